// Round 7
// baseline (1743.904 us; speedup 1.0000x reference)
//
#include <hip/hip_runtime.h>
#include <hip/hip_bf16.h>
#include <math.h>

#define LAYERS 6
#define BBATCH 2
#define TT 512
#define CC 768
#define HH 12
#define MT (BBATCH*TT)      // 1024 tokens
#define FF (4*CC)           // 3072
#define LCH 32
#define NC (TT/LCH)         // 16 chunks
#define BH (BBATCH*HH)      // 24
#define SPAD 65

typedef __hip_bfloat16 bf16;
typedef __bf16 bf16x8 __attribute__((ext_vector_type(8)));
typedef __bf16 bf16x4 __attribute__((ext_vector_type(4)));
typedef float f32x4 __attribute__((ext_vector_type(4)));

__device__ inline bf16 f2b(float f) { return __float2bfloat16(f); }
__device__ inline __bf16 f2bb(float f) {
    __hip_bfloat16 h = __float2bfloat16(f);
    return __builtin_bit_cast(__bf16, h);
}
__device__ inline float bb2f(__bf16 h) {
    return __bfloat162float(__builtin_bit_cast(__hip_bfloat16, h));
}

// ---------------- utility ----------------

__global__ __launch_bounds__(256) void copy_f(float* __restrict__ dst, const float* __restrict__ src) {
    size_t i = (size_t)blockIdx.x * 256 + threadIdx.x;
    dst[i] = src[i];
}

// ---------------- fused layernorm + token-shift-diff, bf16 concat output ----------------

__global__ __launch_bounds__(256) void ln_shift_kernel(const float* __restrict__ x,
                                                       const float* __restrict__ w,
                                                       const float* __restrict__ b,
                                                       bf16* __restrict__ out) {
    int row = blockIdx.x;
    int t = row % TT;
    const float* xr = x + (size_t)row * CC;
    const float* xp = xr - CC;
    int tid = threadIdx.x;
    float c0 = xr[tid], c1 = xr[tid + 256], c2 = xr[tid + 512];
    float p0 = 0.f, p1 = 0.f, p2 = 0.f;
    if (t > 0) { p0 = xp[tid]; p1 = xp[tid + 256]; p2 = xp[tid + 512]; }
    float s  = c0 + c1 + c2, q  = c0 * c0 + c1 * c1 + c2 * c2;
    float sp = p0 + p1 + p2, qp = p0 * p0 + p1 * p1 + p2 * p2;
    for (int m = 1; m < 64; m <<= 1) {
        s += __shfl_xor(s, m); q += __shfl_xor(q, m);
        sp += __shfl_xor(sp, m); qp += __shfl_xor(qp, m);
    }
    __shared__ float rs[4], rq[4], rsp[4], rqp[4];
    int wid = tid >> 6;
    if ((tid & 63) == 0) { rs[wid] = s; rq[wid] = q; rsp[wid] = sp; rqp[wid] = qp; }
    __syncthreads();
    s  = rs[0] + rs[1] + rs[2] + rs[3];   q  = rq[0] + rq[1] + rq[2] + rq[3];
    sp = rsp[0] + rsp[1] + rsp[2] + rsp[3]; qp = rqp[0] + rqp[1] + rqp[2] + rqp[3];
    float meanC = s * (1.f / CC);
    float invC  = rsqrtf(q * (1.f / CC) - meanC * meanC + 1e-5f);
    float meanP = sp * (1.f / CC);
    float invP  = rsqrtf(qp * (1.f / CC) - meanP * meanP + 1e-5f);
    bf16* orow = out + (size_t)row * 1536;
    float cv[3] = {c0, c1, c2};
    float pv[3] = {p0, p1, p2};
#pragma unroll
    for (int j = 0; j < 3; ++j) {
        int cc = tid + j * 256;
        float lnc = (cv[j] - meanC) * invC * w[cc] + b[cc];
        float lnp = (t > 0) ? (pv[j] - meanP) * invP * w[cc] + b[cc] : 0.f;
        orow[cc] = f2b(lnc);
        orow[768 + cc] = f2b(lnp - lnc);
    }
}

// ---------------- weight convert (packed 1D grid) ----------------

struct CEntry { const float* W; const float* mix; bf16* dst; int Ksrc, Nsrc, Npad, Kdst, bstart; };
struct CArgs { CEntry e[14]; };

__global__ __launch_bounds__(256) void convert_weights(CArgs ca) {
    int bid = blockIdx.x;
    int idx = 0;
#pragma unroll
    for (int i = 1; i < 14; ++i) if (bid >= ca.e[i].bstart) idx = i;
    CEntry E = ca.e[idx];
    int t = bid - E.bstart;
    int ntN = E.Npad >> 5;
    int tn = (t % ntN) * 32, tk = (t / ntN) * 32;
    __shared__ float tile[32][33];
    int c = threadIdx.x & 31, r0 = threadIdx.x >> 5;
    int ks = tk;
    const float* mixp = nullptr;
    if (tk >= E.Ksrc) { ks = tk - E.Ksrc; mixp = E.mix; }
#pragma unroll
    for (int i = 0; i < 4; ++i) {
        int r = r0 + i * 8;
        float v = (tn + c < E.Nsrc) ? E.W[(size_t)(ks + r) * E.Nsrc + tn + c] : 0.f;
        if (mixp) v *= mixp[ks + r];
        tile[r][c] = v;
    }
    __syncthreads();
#pragma unroll
    for (int i = 0; i < 4; ++i) {
        int r = r0 + i * 8;
        E.dst[(size_t)(tn + r) * E.Kdst + tk + c] = f2b(tile[c][r]);
    }
}

// ---------------- epilogues ----------------

struct EpiG {
    float* outF; bf16* outH;
    const float* p1; const float* p2;
    int epi, ld, ntrue;
};
struct EpiArgs { EpiG g[7]; int nb[8]; };

__device__ inline void epi_store(const EpiG& E, size_t idx, int lc, float v) {
    switch (E.epi) {
        case 0: E.outF[idx] = v; break;
        case 1: E.outH[idx] = f2b(v); break;
        case 2: E.outH[idx] = f2b(tanhf(v)); break;
        case 3: E.outH[idx] = f2b(1.f / (1.f + expf(-v))); break;
        case 4: { float t = fmaxf(v, 0.f); E.outH[idx] = f2b(t * t); } break;
        case 5: E.outF[idx] += v; break;
        case 6: { float z = E.p1[lc] + v; float nz = -z;
                  float sp = (nz > 20.f) ? nz : log1pf(expf(nz));
                  E.outF[idx] = expf(-expf(-sp - 0.5f)); } break;
        case 7: E.outF[idx] = 1.f / (1.f + expf(-(E.p1[lc] + v))); break;
        case 8: { float vv = E.outF[idx];
                  float s = 1.f / (1.f + expf(-(E.p1[lc] + v)));
                  E.outF[idx] = vv + (E.p2[idx] - vv) * s; } break;
    }
}

// ---------------- bf16 MFMA GEMM with grouped-column epilogue ----------------

template<int BM, int BN>
__global__ __launch_bounds__(256) void gemm_multi(const __bf16* __restrict__ A,
                                                  const __bf16* __restrict__ Bt,
                                                  int K, EpiArgs ea) {
    constexpr int FM = BM / 32, FN = BN / 32;
    constexpr int ABYTES = BM * 64;
    constexpr int TOT = (BM + BN) * 64;
    constexpr int NCHUNK = TOT / 4096;
    __shared__ __align__(16) char smem[2][TOT];
    int tid = threadIdx.x;
    int lane = tid & 63, wid = tid >> 6;
    int bm = blockIdx.y * BM, bn = blockIdx.x * BN;
    int wm = (wid >> 1) * (BM / 2), wn = (wid & 1) * (BN / 2);
    f32x4 acc[FM][FN];
#pragma unroll
    for (int i = 0; i < FM; ++i)
#pragma unroll
        for (int j = 0; j < FN; ++j) acc[i][j] = (f32x4){0.f, 0.f, 0.f, 0.f};

    int nk = K >> 5;
    auto stage = [&](int buf, int k0) {
        char* sb = &smem[buf][0];
#pragma unroll
        for (int c = 0; c < NCHUNK; ++c) {
            int d = c * 4096 + tid * 16;
            int isB = d >= ABYTES;
            int dd = isB ? d - ABYTES : d;
            int row = dd >> 6;
            int u = (dd >> 4) & 3;
            int su = u ^ (row & 3);
            const __bf16* src = isB ? (Bt + (size_t)(bn + row) * K + k0 + su * 8)
                                    : (A  + (size_t)(bm + row) * K + k0 + su * 8);
            char* ldst = sb + c * 4096 + (tid & 192) * 16;
            __builtin_amdgcn_global_load_lds(
                (const __attribute__((address_space(1))) unsigned int*)src,
                (__attribute__((address_space(3))) unsigned int*)ldst, 16, 0, 0);
        }
    };

    stage(0, 0);
    __syncthreads();
    for (int t = 0; t < nk; ++t) {
        if (t + 1 < nk) stage((t + 1) & 1, (t + 1) * 32);
        const char* sA = &smem[t & 1][0];
        const char* sB = &smem[t & 1][ABYTES];
        int u = lane >> 4, r0 = lane & 15;
        bf16x8 af[FM], bfr[FN];
#pragma unroll
        for (int i = 0; i < FM; ++i) {
            int row = wm + i * 16 + r0;
            int su = u ^ (row & 3);
            af[i] = *(const bf16x8*)(sA + row * 64 + su * 16);
        }
#pragma unroll
        for (int j = 0; j < FN; ++j) {
            int row = wn + j * 16 + r0;
            int su = u ^ (row & 3);
            bfr[j] = *(const bf16x8*)(sB + row * 64 + su * 16);
        }
#pragma unroll
        for (int i = 0; i < FM; ++i)
#pragma unroll
            for (int j = 0; j < FN; ++j)
                acc[i][j] = __builtin_amdgcn_mfma_f32_16x16x32_bf16(af[i], bfr[j], acc[i][j], 0, 0, 0);
        __syncthreads();
    }

    int gid = 0;
#pragma unroll 1
    while (bn >= ea.nb[gid + 1]) ++gid;
    EpiG E = ea.g[gid];
    int colBase = ea.nb[gid];
#pragma unroll
    for (int i = 0; i < FM; ++i) {
#pragma unroll
        for (int j = 0; j < FN; ++j) {
#pragma unroll
            for (int q = 0; q < 4; ++q) {
                int gm = bm + wm + i * 16 + (lane >> 4) * 4 + q;
                int lc = bn + wn + j * 16 + (lane & 15) - colBase;
                if (lc < E.ntrue)
                    epi_store(E, (size_t)gm * E.ld + lc, lc, acc[i][j][q]);
            }
        }
    }
}

// ---------------- grouped low-rank GEMM ----------------

struct G2G { const __bf16* A; const __bf16* Bt; float* outF; const float* p1; const float* p2; int K; int epi; };
struct G2Args { G2G g[4]; };

template<int BM, int BN>
__global__ __launch_bounds__(256) void gemm_g2(G2Args ga) {
    G2G G = ga.g[blockIdx.z];
    const __bf16* A = G.A;
    const __bf16* Bt = G.Bt;
    int K = G.K;
    constexpr int FM = BM / 32, FN = BN / 32;
    constexpr int ABYTES = BM * 64;
    constexpr int TOT = (BM + BN) * 64;
    constexpr int NCHUNK = TOT / 4096;
    __shared__ __align__(16) char smem[2][TOT];
    int tid = threadIdx.x;
    int lane = tid & 63, wid = tid >> 6;
    int bm = blockIdx.y * BM, bn = blockIdx.x * BN;
    int wm = (wid >> 1) * (BM / 2), wn = (wid & 1) * (BN / 2);
    f32x4 acc[FM][FN];
#pragma unroll
    for (int i = 0; i < FM; ++i)
#pragma unroll
        for (int j = 0; j < FN; ++j) acc[i][j] = (f32x4){0.f, 0.f, 0.f, 0.f};

    int nk = K >> 5;
    auto stage = [&](int buf, int k0) {
        char* sb = &smem[buf][0];
#pragma unroll
        for (int c = 0; c < NCHUNK; ++c) {
            int d = c * 4096 + tid * 16;
            int isB = d >= ABYTES;
            int dd = isB ? d - ABYTES : d;
            int row = dd >> 6;
            int u = (dd >> 4) & 3;
            int su = u ^ (row & 3);
            const __bf16* src = isB ? (Bt + (size_t)(bn + row) * K + k0 + su * 8)
                                    : (A  + (size_t)(bm + row) * K + k0 + su * 8);
            char* ldst = sb + c * 4096 + (tid & 192) * 16;
            __builtin_amdgcn_global_load_lds(
                (const __attribute__((address_space(1))) unsigned int*)src,
                (__attribute__((address_space(3))) unsigned int*)ldst, 16, 0, 0);
        }
    };

    stage(0, 0);
    __syncthreads();
    for (int t = 0; t < nk; ++t) {
        if (t + 1 < nk) stage((t + 1) & 1, (t + 1) * 32);
        const char* sA = &smem[t & 1][0];
        const char* sB = &smem[t & 1][ABYTES];
        int u = lane >> 4, r0 = lane & 15;
        bf16x8 af[FM], bfr[FN];
#pragma unroll
        for (int i = 0; i < FM; ++i) {
            int row = wm + i * 16 + r0;
            int su = u ^ (row & 3);
            af[i] = *(const bf16x8*)(sA + row * 64 + su * 16);
        }
#pragma unroll
        for (int j = 0; j < FN; ++j) {
            int row = wn + j * 16 + r0;
            int su = u ^ (row & 3);
            bfr[j] = *(const bf16x8*)(sB + row * 64 + su * 16);
        }
#pragma unroll
        for (int i = 0; i < FM; ++i)
#pragma unroll
            for (int j = 0; j < FN; ++j)
                acc[i][j] = __builtin_amdgcn_mfma_f32_16x16x32_bf16(af[i], bfr[j], acc[i][j], 0, 0, 0);
        __syncthreads();
    }

    EpiG E;
    E.outF = G.outF; E.outH = nullptr; E.p1 = G.p1; E.p2 = G.p2;
    E.epi = G.epi; E.ld = 768; E.ntrue = 768;
#pragma unroll
    for (int i = 0; i < FM; ++i) {
#pragma unroll
        for (int j = 0; j < FN; ++j) {
#pragma unroll
            for (int q = 0; q < 4; ++q) {
                int gm = bm + wm + i * 16 + (lane >> 4) * 4 + q;
                int lc = bn + wn + j * 16 + (lane & 15);
                epi_store(E, (size_t)gm * 768 + lc, lc, acc[i][j][q]);
            }
        }
    }
}

// ---------------- chunked WKV7, phase A (register-tiled; M out as transposed bf16 pair) ----------------

__global__ __launch_bounds__(256) void chunkA_kernel(
    const float* __restrict__ r, const float* __restrict__ wd,
    const float* __restrict__ kraw, const float* __restrict__ av_,
    const float* __restrict__ v,
    const float* __restrict__ kkw, const float* __restrict__ kaw,
    float* __restrict__ kupd,
    float* __restrict__ yintra, float* __restrict__ zrO,
    __bf16* __restrict__ mtHi, __bf16* __restrict__ mtLo,
    float* __restrict__ zcO) {
    int c = blockIdx.x, bh = blockIdx.y;
    int b = bh / HH, h = bh % HH;
    __shared__ float Di[LCH][SPAD];
    __shared__ float Ah[LCH][SPAD];
    __shared__ float Bh[LCH][SPAD];
    __shared__ float Kh[LCH][SPAD];
    __shared__ float Rh[LCH][SPAD];
    __shared__ float Vt[LCH][SPAD];
    __shared__ float Qm[LCH][SPAD];
    __shared__ float Gba[LCH][LCH], Gka[LCH][LCH], Grb[LCH][LCH], Grk[LCH][LCH];
    int tid = threadIdx.x;
    int n = tid & 63, tq = tid >> 6;
    size_t base = ((size_t)(b * TT + c * LCH)) * CC + h * 64 + n;
    int cvec = h * 64 + n;
    float kkwv = kkw[cvec], kawv = kaw[cvec];
#pragma unroll
    for (int e = 0; e < 8; ++e) {
        int t = tq * 8 + e;
        size_t off = base + (size_t)t * CC;
        float kr = kraw[off];
        float aval = av_[off];
        float kk0 = kr * kkwv;
        float ss = kk0 * kk0;
        for (int m = 1; m < 64; m <<= 1) ss += __shfl_xor(ss, m);
        float rinv = 1.f / fmaxf(sqrtf(ss), 1e-12f);
        float kkv = kk0 * rinv;
        float ku = kr * (1.f + (aval - 1.f) * kawv);
        kupd[off] = ku;
        Di[t][n] = wd[off];
        Ah[t][n] = -kkv;
        Bh[t][n] = kkv * aval;
        Kh[t][n] = ku;
        Rh[t][n] = r[off];
        Vt[t][n] = v[off];
    }
    __syncthreads();
    if (tid < 64) {
        float d = 1.f;
        for (int t = 0; t < LCH; ++t) { d *= Di[t][tid]; Di[t][tid] = d; }
    }
    __syncthreads();
#pragma unroll
    for (int e = 0; e < 8; ++e) {
        int t = tq * 8 + e;
        float di = Di[t][n];
        float dp = (t == 0) ? 1.f : Di[t - 1][n];
        float inv = 1.f / di;
        Ah[t][n] *= dp;
        Bh[t][n] *= inv;
        Kh[t][n] *= inv;
        Rh[t][n] *= di;
    }
    __syncthreads();
    // ---- G phase: 2x2 (t,s) tiles ----
    {
        int tp = tid >> 4, sp = tid & 15;
        int t0 = 2 * tp, s0 = 2 * sp;
        float gba00 = 0.f, gba01 = 0.f, gba10 = 0.f, gba11 = 0.f;
        float gka00 = 0.f, gka01 = 0.f, gka10 = 0.f, gka11 = 0.f;
        float grb00 = 0.f, grb01 = 0.f, grb10 = 0.f, grb11 = 0.f;
        float grk00 = 0.f, grk01 = 0.f, grk10 = 0.f, grk11 = 0.f;
#pragma unroll 4
        for (int j = 0; j < 64; ++j) {
            float a0 = Ah[t0][j], a1 = Ah[t0 + 1][j];
            float r0 = Rh[t0][j], r1 = Rh[t0 + 1][j];
            float b0 = Bh[s0][j], b1 = Bh[s0 + 1][j];
            float k0 = Kh[s0][j], k1 = Kh[s0 + 1][j];
            gba00 = fmaf(a0, b0, gba00); gba01 = fmaf(a0, b1, gba01);
            gba10 = fmaf(a1, b0, gba10); gba11 = fmaf(a1, b1, gba11);
            gka00 = fmaf(a0, k0, gka00); gka01 = fmaf(a0, k1, gka01);
            gka10 = fmaf(a1, k0, gka10); gka11 = fmaf(a1, k1, gka11);
            grb00 = fmaf(r0, b0, grb00); grb01 = fmaf(r0, b1, grb01);
            grb10 = fmaf(r1, b0, grb10); grb11 = fmaf(r1, b1, grb11);
            grk00 = fmaf(r0, k0, grk00); grk01 = fmaf(r0, k1, grk01);
            grk10 = fmaf(r1, k0, grk10); grk11 = fmaf(r1, k1, grk11);
        }
#pragma unroll
        for (int dt = 0; dt < 2; ++dt) {
            int t = t0 + dt;
#pragma unroll
            for (int ds = 0; ds < 2; ++ds) {
                int s = s0 + ds;
                float vba = dt ? (ds ? gba11 : gba10) : (ds ? gba01 : gba00);
                float vka = dt ? (ds ? gka11 : gka10) : (ds ? gka01 : gka00);
                float vrb = dt ? (ds ? grb11 : grb10) : (ds ? grb01 : grb00);
                float vrk = dt ? (ds ? grk11 : grk10) : (ds ? grk01 : grk00);
                Gba[t][s] = (s < t)  ? vba : 0.f;
                Gka[t][s] = (s < t)  ? vka : 0.f;
                Grb[t][s] = (s <= t) ? vrb : 0.f;
                Grk[t][s] = (s <= t) ? vrk : 0.f;
            }
        }
    }
    __syncthreads();
    // ---- Qm = Gka V (s-outer) ----
    {
        float acc[8];
#pragma unroll
        for (int e = 0; e < 8; ++e) acc[e] = 0.f;
        for (int s = 0; s < LCH; ++s) {
            float vs = Vt[s][n];
#pragma unroll
            for (int e = 0; e < 8; ++e)
                acc[e] = fmaf(Gka[tq * 8 + e][s], vs, acc[e]);
        }
#pragma unroll
        for (int e = 0; e < 8; ++e) Qm[tq * 8 + e][n] = acc[e];
    }
    __syncthreads();
    // ---- forward substitution ----
    if (tq == 0) {
        for (int t = 1; t < LCH; ++t) {
            float acc = Ah[t][n];
            for (int s = 0; s < t; ++s) acc = fmaf(Gba[t][s], Ah[s][n], acc);
            Ah[t][n] = acc;
        }
    } else if (tq == 1) {
        for (int t = 1; t < LCH; ++t) {
            float acc = Qm[t][n];
            for (int s = 0; s < t; ++s) acc = fmaf(Gba[t][s], Qm[s][n], acc);
            Qm[t][n] = acc;
        }
    }
    __syncthreads();
    size_t obase = ((size_t)(bh * NC + c)) * LCH * 64;
    // ---- yintra / zr (s-outer) ----
    {
        float accY[8], accZ[8];
#pragma unroll
        for (int e = 0; e < 8; ++e) { accY[e] = 0.f; accZ[e] = Rh[tq * 8 + e][n]; }
        for (int s = 0; s < LCH; ++s) {
            float vs = Vt[s][n], qs = Qm[s][n], us = Ah[s][n];
#pragma unroll
            for (int e = 0; e < 8; ++e) {
                int t = tq * 8 + e;
                float grk_ = Grk[t][s], grb_ = Grb[t][s];
                accY[e] = fmaf(grk_, vs, fmaf(grb_, qs, accY[e]));
                accZ[e] = fmaf(grb_, us, accZ[e]);
            }
        }
#pragma unroll
        for (int e = 0; e < 8; ++e) {
            int t = tq * 8 + e;
            yintra[obase + t * 64 + n] = accY[e];
            zrO[obase + t * 64 + n] = accZ[e];
        }
    }
    // ---- M / Zc (4x4 tiles, s-outer); M stored transposed as bf16 hi/lo pair ----
    {
        int pi = tid >> 4, ni = tid & 15;
        float accM[4][4], accZc[4][4];
#pragma unroll
        for (int dp = 0; dp < 4; ++dp)
#pragma unroll
            for (int dn = 0; dn < 4; ++dn) { accM[dp][dn] = 0.f; accZc[dp][dn] = 0.f; }
        for (int s = 0; s < LCH; ++s) {
            float aa[4], vv[4], qq[4], bb[4], kk[4];
#pragma unroll
            for (int d = 0; d < 4; ++d) {
                aa[d] = Ah[s][4 * pi + d];
                vv[d] = Vt[s][4 * pi + d];
                qq[d] = Qm[s][4 * pi + d];
                bb[d] = Bh[s][4 * ni + d];
                kk[d] = Kh[s][4 * ni + d];
            }
#pragma unroll
            for (int dp = 0; dp < 4; ++dp)
#pragma unroll
                for (int dn = 0; dn < 4; ++dn) {
                    accM[dp][dn]  = fmaf(aa[dp], bb[dn], accM[dp][dn]);
                    accZc[dp][dn] = fmaf(vv[dp], kk[dn], fmaf(qq[dp], bb[dn], accZc[dp][dn]));
                }
        }
        size_t mbase = ((size_t)(bh * NC + c)) * 4096;
        float dl[4];
#pragma unroll
        for (int dn = 0; dn < 4; ++dn) dl[dn] = Di[LCH - 1][4 * ni + dn];
        // Zc fp32, row-major [p][n]
#pragma unroll
        for (int dp = 0; dp < 4; ++dp) {
            int p = 4 * pi + dp;
            f32x4 z4;
#pragma unroll
            for (int dn = 0; dn < 4; ++dn) z4[dn] = dl[dn] * accZc[dp][dn];
            *(f32x4*)(zcO + mbase + p * 64 + 4 * ni) = z4;
        }
        // M transposed [n][p], bf16 hi/lo split
#pragma unroll
        for (int dn = 0; dn < 4; ++dn) {
            int nn = 4 * ni + dn;
            float dlv = dl[dn];
            bf16x4 h4, l4;
#pragma unroll
            for (int dp = 0; dp < 4; ++dp) {
                int p = 4 * pi + dp;
                float mm = (accM[dp][dn] + ((p == nn) ? 1.f : 0.f)) * dlv;
                __bf16 hb = f2bb(mm);
                h4[dp] = hb;
                l4[dp] = f2bb(mm - bb2f(hb));
            }
            *(bf16x4*)(mtHi + mbase + (size_t)nn * 64 + 4 * pi) = h4;
            *(bf16x4*)(mtLo + mbase + (size_t)nn * 64 + 4 * pi) = l4;
        }
    }
}

// ---------------- phase B1: sequential state chain via split-precision MFMA ----------------
// 256 threads = 4 waves; wave w owns row-tile w (16 rows), col-tiles ct=0..3.
// S fp32 in LDS [64][68]; per chunk: split S->hi/lo bf16 fragments, 3 MFMA products
// against register-double-buffered Mt_hi/Mt_lo; acc init = Zc fragment.

__global__ __launch_bounds__(256) void chunkB1_kernel(
    const float* __restrict__ zc,
    const __bf16* __restrict__ mtHi,
    const __bf16* __restrict__ mtLo,
    float* __restrict__ schk) {
    int bh = blockIdx.x;
    int tid = threadIdx.x;
    int lane = tid & 63, w = tid >> 6;
    int r0 = lane & 15, u = lane >> 4;
    __shared__ __align__(16) float S[64][68];
    for (int i = tid; i < 64 * 68; i += 256) (&S[0][0])[i] = 0.f;
    const float* zbase = zc + (size_t)bh * NC * 4096;
    const __bf16* hbase = mtHi + (size_t)bh * NC * 4096;
    const __bf16* lbase = mtLo + (size_t)bh * NC * 4096;
    float* sbase = schk + (size_t)bh * NC * 4096;
    int arow = w * 16 + r0;

    bf16x8 mh[2][4][2], ml[2][4][2];
    f32x4 zf[2][4];
    // preload chunk 0 M-fragments and Zc-fragments
#pragma unroll
    for (int ct = 0; ct < 4; ++ct) {
#pragma unroll
        for (int ks = 0; ks < 2; ++ks) {
            size_t mo = (size_t)(ct * 16 + r0) * 64 + ks * 32 + u * 8;
            mh[0][ct][ks] = *(const bf16x8*)(hbase + mo);
            ml[0][ct][ks] = *(const bf16x8*)(lbase + mo);
        }
#pragma unroll
        for (int q = 0; q < 4; ++q)
            zf[0][ct][q] = zbase[(size_t)(w * 16 + u * 4 + q) * 64 + ct * 16 + r0];
    }
    __syncthreads();
#pragma unroll 1
    for (int c = 0; c < NC - 1; ++c) {
        int cb = c & 1;
        if (c + 1 < NC - 1) {
            const __bf16* hn = hbase + (size_t)(c + 1) * 4096;
            const __bf16* ln = lbase + (size_t)(c + 1) * 4096;
            const float* zn = zbase + (size_t)(c + 1) * 4096;
#pragma unroll
            for (int ct = 0; ct < 4; ++ct) {
#pragma unroll
                for (int ks = 0; ks < 2; ++ks) {
                    size_t mo = (size_t)(ct * 16 + r0) * 64 + ks * 32 + u * 8;
                    mh[cb ^ 1][ct][ks] = *(const bf16x8*)(hn + mo);
                    ml[cb ^ 1][ct][ks] = *(const bf16x8*)(ln + mo);
                }
#pragma unroll
                for (int q = 0; q < 4; ++q)
                    zf[cb ^ 1][ct][q] = zn[(size_t)(w * 16 + u * 4 + q) * 64 + ct * 16 + r0];
            }
        }
        // A fragments: read 8 f32 of S row, split into bf16 hi/lo
        bf16x8 ah[2], al[2];
#pragma unroll
        for (int ks = 0; ks < 2; ++ks) {
            f32x4 s0 = *(const f32x4*)&S[arow][ks * 32 + u * 8];
            f32x4 s1 = *(const f32x4*)&S[arow][ks * 32 + u * 8 + 4];
#pragma unroll
            for (int e = 0; e < 4; ++e) {
                __bf16 h0 = f2bb(s0[e]);
                ah[ks][e] = h0;
                al[ks][e] = f2bb(s0[e] - bb2f(h0));
                __bf16 h1 = f2bb(s1[e]);
                ah[ks][4 + e] = h1;
                al[ks][4 + e] = f2bb(s1[e] - bb2f(h1));
            }
        }
        f32x4 acc[4];
#pragma unroll
        for (int ct = 0; ct < 4; ++ct) {
            acc[ct] = zf[cb][ct];
#pragma unroll
            for (int ks = 0; ks < 2; ++ks) {
                acc[ct] = __builtin_amdgcn_mfma_f32_16x16x32_bf16(ah[ks], mh[cb][ct][ks], acc[ct], 0, 0, 0);
                acc[ct] = __builtin_amdgcn_mfma_f32_16x16x32_bf16(ah[ks], ml[cb][ct][ks], acc[ct], 0, 0, 0);
                acc[ct] = __builtin_amdgcn_mfma_f32_16x16x32_bf16(al[ks], mh[cb][ct][ks], acc[ct], 0, 0, 0);
            }
        }
        __syncthreads();   // all S reads complete
        float* cp = sbase + (size_t)(c + 1) * 4096;
#pragma unroll
        for (int ct = 0; ct < 4; ++ct) {
#pragma unroll
            for (int q = 0; q < 4; ++q) {
                int row = w * 16 + u * 4 + q;
                int col = ct * 16 + r0;
                S[row][col] = acc[ct][q];
                cp[(size_t)row * 64 + col] = acc[ct][q];
            }
        }
        __syncthreads();   // S_new visible before next chunk
    }
}

// ---------------- phase Y (unchanged) ----------------

__global__ __launch_bounds__(256) void chunkY_kernel(
    const float* __restrict__ yintra, const float* __restrict__ zrI,
    const float* __restrict__ schk,
    const float* __restrict__ r, const float* __restrict__ kupd,
    const float* __restrict__ v, const float* __restrict__ g,
    const float* __restrict__ rk, const float* __restrict__ lw,
    const float* __restrict__ lb, bf16* __restrict__ out) {
    int c = blockIdx.x, bh = blockIdx.y;
    int b = bh / HH, h = bh % HH;
    __shared__ float Y[LCH][SPAD];
    __shared__ float Zr[LCH][SPAD];
    __shared__ float Sh[64][SPAD];
    int tid = threadIdx.x;
    int n = tid & 63, tq = tid >> 6;
    size_t obase = ((size_t)(bh * NC + c)) * LCH * 64;
#pragma unroll
    for (int e = 0; e < 8; ++e) {
        int idx = tid + e * 256;
        int row = idx >> 6, col = idx & 63;
        Y[row][col] = yintra[obase + idx];
        Zr[row][col] = zrI[obase + idx];
    }
    if (c > 0) {
        size_t sbase = ((size_t)(bh * NC + c)) * 4096;
#pragma unroll
        for (int e = 0; e < 16; ++e) {
            int idx = tid + e * 256;
            Sh[idx >> 6][idx & 63] = schk[sbase + idx];
        }
    }
    __syncthreads();
    if (c > 0) {
        float acc[8];
#pragma unroll
        for (int e = 0; e < 8; ++e) acc[e] = 0.f;
        for (int p = 0; p < 64; ++p) {
            float sv = Sh[n][p];
#pragma unroll
            for (int e = 0; e < 8; ++e)
                acc[e] = fmaf(Zr[tq * 8 + e][p], sv, acc[e]);
        }
#pragma unroll
        for (int e = 0; e < 8; ++e) Y[tq * 8 + e][n] += acc[e];
    }
    size_t rowbase = ((size_t)(b * TT + c * LCH)) * CC + h * 64 + n;
    float rkv = rk[h * 64 + n];
    float lwv = lw[h * 64 + n], lbv = lb[h * 64 + n];
#pragma unroll
    for (int e = 0; e < 8; ++e) {
        int t = tq * 8 + e;
        size_t off = rowbase + (size_t)t * CC;
        float yv = Y[t][n];
        float rv = r[off], kv = kupd[off], vv = v[off];
        float s1 = yv, s2 = yv * yv, s3 = rv * kv * rkv;
        for (int m = 1; m < 64; m <<= 1) {
            s1 += __shfl_xor(s1, m);
            s2 += __shfl_xor(s2, m);
            s3 += __shfl_xor(s3, m);
        }
        float mean = s1 * (1.f / 64.f);
        float var  = s2 * (1.f / 64.f) - mean * mean;
        float inv  = rsqrtf(var + 64e-5f);
        float val  = (yv - mean) * inv * lwv + lbv + s3 * vv;
        out[off] = f2b(val * g[off]);
    }
}

// ---------------- host ----------------

extern "C" void kernel_launch(void* const* d_in, const int* in_sizes, int n_in,
                              void* d_out, int out_size, void* d_ws, size_t ws_size,
                              hipStream_t stream) {
    (void)in_sizes; (void)n_in; (void)out_size;
    const float* x    = (const float*)d_in[0];
    const float* x_r  = (const float*)d_in[1];
    const float* x_w  = (const float*)d_in[2];
    const float* x_k  = (const float*)d_in[3];
    const float* x_v  = (const float*)d_in[4];
    const float* x_a  = (const float*)d_in[5];
    const float* x_g  = (const float*)d_in[6];
    const float* w0   = (const float*)d_in[7];
    const float* w1   = (const float*)d_in[8];
    const float* w2   = (const float*)d_in[9];
    const float* a0   = (const float*)d_in[10];
    const float* a1   = (const float*)d_in[11];
    const float* a2   = (const float*)d_in[12];
    const float* v0   = (const float*)d_in[13];
    const float* v1   = (const float*)d_in[14];
    const float* v2   = (const float*)d_in[15];
    const float* g1   = (const float*)d_in[16];
    const float* g2   = (const float*)d_in[17];
    const float* k_k  = (const float*)d_in[18];
    const float* k_a  = (const float*)d_in[19];
    const float* r_k  = (const float*)d_in[20];
    const float* W_r  = (const float*)d_in[21];
    const float* W_k  = (const float*)d_in[22];
    const float* W_v  = (const float*)d_in[23];
    const float* W_o  = (const float*)d_in[24];
    const float* ln_x_w = (const float*)d_in[25];
    const float* ln_x_b = (const float*)d_in[26];
    const float* ln1_w  = (const float*)d_in[27];
    const float* ln1_b  = (const float*)d_in[28];
    const float* ln2_w  = (const float*)d_in[29];
    const float* ln2_b  = (const float*)d_in[30];
    const float* c_x_k  = (const float*)d_in[31];
    const float* W_ck   = (const float*)d_in[32];
    const float* W_cv   = (const float*)d_in[33];

    const size_t MC = (size_t)MT * CC;
    char* wsb = (char*)d_ws;
    size_t woff = 0;
    auto alloc = [&](size_t bytes) -> void* {
        void* p = wsb + woff;
        woff += (bytes + 255) & ~(size_t)255;
        return p;
    };
    bf16* Bcat  = (bf16*)alloc((size_t)2624 * 1536 * 2);
    bf16* Bck   = (bf16*)alloc((size_t)3072 * 1536 * 2);
    bf16* w2t   = (bf16*)alloc((size_t)768 * 64 * 2);
    bf16* a2t   = (bf16*)alloc((size_t)768 * 64 * 2);
    bf16* v2t   = (bf16*)alloc((size_t)768 * 32 * 2);
    bf16* g2t   = (bf16*)alloc((size_t)768 * 128 * 2);
    bf16* Wo_t  = (bf16*)alloc((size_t)768 * 768 * 2);
    bf16* Wcv_t = (bf16*)alloc((size_t)768 * 3072 * 2);
    bf16* A1    = (bf16*)alloc((size_t)MT * 1536 * 2);
    float* rbuf  = (float*)alloc(MC * 4);
    float* kraw  = (float*)alloc(MC * 4);
    float* kupd  = (float*)alloc(MC * 4);
    float* vbuf  = (float*)alloc(MC * 4);
    float* vfirst= (float*)alloc(MC * 4);
    float* abuf  = (float*)alloc(MC * 4);
    float* dbuf  = (float*)alloc(MC * 4);
    float* gbuf  = (float*)alloc(MC * 4);
    bf16* w1o   = (bf16*)alloc((size_t)MT * 64 * 2);
    bf16* a1o   = (bf16*)alloc((size_t)MT * 64 * 2);
    bf16* v1o   = (bf16*)alloc((size_t)MT * 32 * 2);
    bf16* g1o   = (bf16*)alloc((size_t)MT * 128 * 2);
    bf16* hbuf  = (bf16*)alloc((size_t)MT * FF * 2);
    bf16* ghout = (bf16*)alloc(MC * 2);
    float* yintraW = (float*)alloc((size_t)BH * NC * LCH * 64 * 4);
    float* zrW     = (float*)alloc((size_t)BH * NC * LCH * 64 * 4);
    __bf16* mtHiW  = (__bf16*)alloc((size_t)BH * NC * 4096 * 2);
    __bf16* mtLoW  = (__bf16*)alloc((size_t)BH * NC * 4096 * 2);
    float* zcW     = (float*)alloc((size_t)BH * NC * 4096 * 4);
    float* schkW   = (float*)alloc((size_t)BH * NC * 4096 * 4);
    if (woff > ws_size) return;

    float* xcur = (float*)d_out;
    copy_f<<<MC / 256, 256, 0, stream>>>(xcur, x);

    for (int l = 0; l < LAYERS; ++l) {
        size_t oC = (size_t)l * CC;
        float* vptr = (l == 0) ? vfirst : vbuf;

        CArgs ca;
        ca.e[0]  = {W_r  + (size_t)l * 589824, x_r + oC, Bcat,               768, 768, 768, 1536, 0};
        ca.e[1]  = {W_k  + (size_t)l * 589824, x_k + oC, Bcat + (size_t)768  * 1536, 768, 768, 768, 1536, 0};
        ca.e[2]  = {W_v  + (size_t)l * 589824, x_v + oC, Bcat + (size_t)1536 * 1536, 768, 768, 768, 1536, 0};
        ca.e[3]  = {w1   + (size_t)l * 49152,  x_w + oC, Bcat + (size_t)2304 * 1536, 768, 64, 64, 1536, 0};
        ca.e[4]  = {a1   + (size_t)l * 49152,  x_a + oC, Bcat + (size_t)2368 * 1536, 768, 64, 64, 1536, 0};
        ca.e[5]  = {g1   + (size_t)l * 98304,  x_g + oC, Bcat + (size_t)2432 * 1536, 768, 128, 128, 1536, 0};
        ca.e[6]  = {v1   + (size_t)l * 24576,  x_v + oC, Bcat + (size_t)2560 * 1536, 768, 32, 64, 1536, 0};
        ca.e[7]  = {W_ck + (size_t)l * 2359296, c_x_k + oC, Bck, 768, 3072, 3072, 1536, 0};
        ca.e[8]  = {w2   + (size_t)l * 49152,  nullptr, w2t,   64, 768, 768, 64, 0};
        ca.e[9]  = {a2   + (size_t)l * 49152,  nullptr, a2t,   64, 768, 768, 64, 0};
        ca.e[10] = {v2   + (size_t)l * 24576,  nullptr, v2t,   32, 768, 768, 32, 0};
        ca.e[11] = {g2   + (size_t)l * 98304,  nullptr, g2t,  128, 768, 768, 128, 0};
        ca.e[12] = {W_o  + (size_t)l * 589824, nullptr, Wo_t, 768, 768, 768, 768, 0};
        ca.e[13] = {W_cv + (size_t)l * 2359296, nullptr, Wcv_t, 3072, 768, 768, 3072, 0};
        int btot = 0;
        for (int i = 0; i < 14; ++i) {
            ca.e[i].bstart = btot;
            btot += (ca.e[i].Npad >> 5) * (ca.e[i].Kdst >> 5);
        }
        convert_weights<<<btot, 256, 0, stream>>>(ca);

        // ---- time mix ----
        ln_shift_kernel<<<MT, 256, 0, stream>>>(xcur, ln1_w + oC, ln1_b + oC, A1);

        EpiArgs e1;
        e1.g[0] = {rbuf,  nullptr, nullptr, nullptr, 0, 768, 768};
        e1.g[1] = {kraw,  nullptr, nullptr, nullptr, 0, 768, 768};
        e1.g[2] = {vptr,  nullptr, nullptr, nullptr, 0, 768, 768};
        e1.g[3] = {nullptr, w1o, nullptr, nullptr, 2, 64, 64};
        e1.g[4] = {nullptr, a1o, nullptr, nullptr, 1, 64, 64};
        e1.g[5] = {nullptr, g1o, nullptr, nullptr, 3, 128, 128};
        e1.g[6] = {nullptr, v1o, nullptr, nullptr, 1, 32, 32};
        int nb1[8] = {0, 768, 1536, 2304, 2368, 2432, 2560, 2624};
        for (int i = 0; i < 8; ++i) e1.nb[i] = nb1[i];
        gemm_multi<128, 64><<<dim3(41, 8), 256, 0, stream>>>((const __bf16*)A1, (const __bf16*)Bcat, 1536, e1);

        G2Args g2a;
        g2a.g[0] = {(const __bf16*)w1o, (const __bf16*)w2t, dbuf, w0 + oC, nullptr, 64, 6};
        g2a.g[1] = {(const __bf16*)a1o, (const __bf16*)a2t, abuf, a0 + oC, nullptr, 64, 7};
        g2a.g[2] = {(const __bf16*)g1o, (const __bf16*)g2t, gbuf, nullptr, nullptr, 128, 0};
        g2a.g[3] = {(const __bf16*)v1o, (const __bf16*)v2t, vbuf, v0 + oC, vfirst, 32, 8};
        gemm_g2<128, 64><<<dim3(12, 8, (l == 0) ? 3 : 4), 256, 0, stream>>>(g2a);

        // ---- chunked scan ----
        chunkA_kernel<<<dim3(NC, BH), 256, 0, stream>>>(rbuf, dbuf, kraw, abuf, vptr,
                                                        k_k + oC, k_a + oC, kupd,
                                                        yintraW, zrW, mtHiW, mtLoW, zcW);
        chunkB1_kernel<<<BH, 256, 0, stream>>>(zcW, mtHiW, mtLoW, schkW);
        chunkY_kernel<<<dim3(NC, BH), 256, 0, stream>>>(yintraW, zrW, schkW,
                                                        rbuf, kupd, vptr, gbuf,
                                                        r_k + (size_t)l * 768,
                                                        ln_x_w + oC, ln_x_b + oC, ghout);

        EpiArgs eo;
        eo.g[0] = {xcur, nullptr, nullptr, nullptr, 5, 768, 768};
        eo.nb[0] = 0; for (int i = 1; i < 8; ++i) eo.nb[i] = 1 << 30;
        eo.nb[1] = 768;
        gemm_multi<64, 64><<<dim3(12, 16), 256, 0, stream>>>((const __bf16*)ghout, (const __bf16*)Wo_t, 768, eo);

        // ---- channel mix ----
        ln_shift_kernel<<<MT, 256, 0, stream>>>(xcur, ln2_w + oC, ln2_b + oC, A1);

        EpiArgs ec;
        ec.g[0] = {nullptr, hbuf, nullptr, nullptr, 4, 3072, 3072};
        ec.nb[0] = 0; for (int i = 1; i < 8; ++i) ec.nb[i] = 1 << 30;
        ec.nb[1] = 3072;
        gemm_multi<128, 64><<<dim3(48, 8), 256, 0, stream>>>((const __bf16*)A1, (const __bf16*)Bck, 1536, ec);

        EpiArgs ev;
        ev.g[0] = {xcur, nullptr, nullptr, nullptr, 5, 768, 768};
        ev.nb[0] = 0; for (int i = 1; i < 8; ++i) ev.nb[i] = 1 << 30;
        ev.nb[1] = 768;
        gemm_multi<64, 64><<<dim3(12, 16), 256, 0, stream>>>((const __bf16*)hbuf, (const __bf16*)Wcv_t, 3072, ev);
    }
}

// Round 8
// 1482.802 us; speedup vs baseline: 1.1761x; 1.1761x over previous
//
#include <hip/hip_runtime.h>
#include <hip/hip_bf16.h>
#include <math.h>

#define LAYERS 6
#define BBATCH 2
#define TT 512
#define CC 768
#define HH 12
#define MT (BBATCH*TT)      // 1024 tokens
#define FF (4*CC)           // 3072
#define LCH 32
#define NC (TT/LCH)         // 16 chunks
#define BH (BBATCH*HH)      // 24
#define SPAD 65

typedef __hip_bfloat16 bf16;
typedef __bf16 bf16x8 __attribute__((ext_vector_type(8)));
typedef __bf16 bf16x4 __attribute__((ext_vector_type(4)));
typedef float f32x4 __attribute__((ext_vector_type(4)));

__device__ inline bf16 f2b(float f) { return __float2bfloat16(f); }
__device__ inline __bf16 f2bb(float f) {
    __hip_bfloat16 h = __float2bfloat16(f);
    return __builtin_bit_cast(__bf16, h);
}
__device__ inline float bb2f(__bf16 h) {
    return __bfloat162float(__builtin_bit_cast(__hip_bfloat16, h));
}

// ---------------- utility ----------------

__global__ __launch_bounds__(256) void copy_f(float* __restrict__ dst, const float* __restrict__ src) {
    size_t i = (size_t)blockIdx.x * 256 + threadIdx.x;
    dst[i] = src[i];
}

// ---------------- fused layernorm + token-shift-diff, bf16 concat output ----------------

__global__ __launch_bounds__(256) void ln_shift_kernel(const float* __restrict__ x,
                                                       const float* __restrict__ w,
                                                       const float* __restrict__ b,
                                                       bf16* __restrict__ out) {
    int row = blockIdx.x;
    int t = row % TT;
    const float* xr = x + (size_t)row * CC;
    const float* xp = xr - CC;
    int tid = threadIdx.x;
    float c0 = xr[tid], c1 = xr[tid + 256], c2 = xr[tid + 512];
    float p0 = 0.f, p1 = 0.f, p2 = 0.f;
    if (t > 0) { p0 = xp[tid]; p1 = xp[tid + 256]; p2 = xp[tid + 512]; }
    float s  = c0 + c1 + c2, q  = c0 * c0 + c1 * c1 + c2 * c2;
    float sp = p0 + p1 + p2, qp = p0 * p0 + p1 * p1 + p2 * p2;
    for (int m = 1; m < 64; m <<= 1) {
        s += __shfl_xor(s, m); q += __shfl_xor(q, m);
        sp += __shfl_xor(sp, m); qp += __shfl_xor(qp, m);
    }
    __shared__ float rs[4], rq[4], rsp[4], rqp[4];
    int wid = tid >> 6;
    if ((tid & 63) == 0) { rs[wid] = s; rq[wid] = q; rsp[wid] = sp; rqp[wid] = qp; }
    __syncthreads();
    s  = rs[0] + rs[1] + rs[2] + rs[3];   q  = rq[0] + rq[1] + rq[2] + rq[3];
    sp = rsp[0] + rsp[1] + rsp[2] + rsp[3]; qp = rqp[0] + rqp[1] + rqp[2] + rqp[3];
    float meanC = s * (1.f / CC);
    float invC  = rsqrtf(q * (1.f / CC) - meanC * meanC + 1e-5f);
    float meanP = sp * (1.f / CC);
    float invP  = rsqrtf(qp * (1.f / CC) - meanP * meanP + 1e-5f);
    bf16* orow = out + (size_t)row * 1536;
    float cv[3] = {c0, c1, c2};
    float pv[3] = {p0, p1, p2};
#pragma unroll
    for (int j = 0; j < 3; ++j) {
        int cc = tid + j * 256;
        float lnc = (cv[j] - meanC) * invC * w[cc] + b[cc];
        float lnp = (t > 0) ? (pv[j] - meanP) * invP * w[cc] + b[cc] : 0.f;
        orow[cc] = f2b(lnc);
        orow[768 + cc] = f2b(lnp - lnc);
    }
}

// ---------------- weight convert (packed 1D grid) ----------------

struct CEntry { const float* W; const float* mix; bf16* dst; int Ksrc, Nsrc, Npad, Kdst, bstart; };
struct CArgs { CEntry e[14]; };

__global__ __launch_bounds__(256) void convert_weights(CArgs ca) {
    int bid = blockIdx.x;
    int idx = 0;
#pragma unroll
    for (int i = 1; i < 14; ++i) if (bid >= ca.e[i].bstart) idx = i;
    CEntry E = ca.e[idx];
    int t = bid - E.bstart;
    int ntN = E.Npad >> 5;
    int tn = (t % ntN) * 32, tk = (t / ntN) * 32;
    __shared__ float tile[32][33];
    int c = threadIdx.x & 31, r0 = threadIdx.x >> 5;
    int ks = tk;
    const float* mixp = nullptr;
    if (tk >= E.Ksrc) { ks = tk - E.Ksrc; mixp = E.mix; }
#pragma unroll
    for (int i = 0; i < 4; ++i) {
        int r = r0 + i * 8;
        float v = (tn + c < E.Nsrc) ? E.W[(size_t)(ks + r) * E.Nsrc + tn + c] : 0.f;
        if (mixp) v *= mixp[ks + r];
        tile[r][c] = v;
    }
    __syncthreads();
#pragma unroll
    for (int i = 0; i < 4; ++i) {
        int r = r0 + i * 8;
        E.dst[(size_t)(tn + r) * E.Kdst + tk + c] = f2b(tile[c][r]);
    }
}

// ---------------- epilogues ----------------

struct EpiG {
    float* outF; bf16* outH;
    const float* p1; const float* p2;
    int epi, ld, ntrue;
};
struct EpiArgs { EpiG g[7]; int nb[8]; };

__device__ inline void epi_store(const EpiG& E, size_t idx, int lc, float v) {
    switch (E.epi) {
        case 0: E.outF[idx] = v; break;
        case 1: E.outH[idx] = f2b(v); break;
        case 2: E.outH[idx] = f2b(tanhf(v)); break;
        case 3: E.outH[idx] = f2b(1.f / (1.f + expf(-v))); break;
        case 4: { float t = fmaxf(v, 0.f); E.outH[idx] = f2b(t * t); } break;
        case 5: E.outF[idx] += v; break;
        case 6: { float z = E.p1[lc] + v; float nz = -z;
                  float sp = (nz > 20.f) ? nz : log1pf(expf(nz));
                  E.outF[idx] = expf(-expf(-sp - 0.5f)); } break;
        case 7: E.outF[idx] = 1.f / (1.f + expf(-(E.p1[lc] + v))); break;
        case 8: { float vv = E.outF[idx];
                  float s = 1.f / (1.f + expf(-(E.p1[lc] + v)));
                  E.outF[idx] = vv + (E.p2[idx] - vv) * s; } break;
    }
}

// ---------------- bf16 MFMA GEMM with grouped-column epilogue ----------------

template<int BM, int BN>
__global__ __launch_bounds__(256) void gemm_multi(const __bf16* __restrict__ A,
                                                  const __bf16* __restrict__ Bt,
                                                  int K, EpiArgs ea) {
    constexpr int FM = BM / 32, FN = BN / 32;
    constexpr int ABYTES = BM * 64;
    constexpr int TOT = (BM + BN) * 64;
    constexpr int NCHUNK = TOT / 4096;
    __shared__ __align__(16) char smem[2][TOT];
    int tid = threadIdx.x;
    int lane = tid & 63, wid = tid >> 6;
    int bm = blockIdx.y * BM, bn = blockIdx.x * BN;
    int wm = (wid >> 1) * (BM / 2), wn = (wid & 1) * (BN / 2);
    f32x4 acc[FM][FN];
#pragma unroll
    for (int i = 0; i < FM; ++i)
#pragma unroll
        for (int j = 0; j < FN; ++j) acc[i][j] = (f32x4){0.f, 0.f, 0.f, 0.f};

    int nk = K >> 5;
    auto stage = [&](int buf, int k0) {
        char* sb = &smem[buf][0];
#pragma unroll
        for (int c = 0; c < NCHUNK; ++c) {
            int d = c * 4096 + tid * 16;
            int isB = d >= ABYTES;
            int dd = isB ? d - ABYTES : d;
            int row = dd >> 6;
            int u = (dd >> 4) & 3;
            int su = u ^ (row & 3);
            const __bf16* src = isB ? (Bt + (size_t)(bn + row) * K + k0 + su * 8)
                                    : (A  + (size_t)(bm + row) * K + k0 + su * 8);
            char* ldst = sb + c * 4096 + (tid & 192) * 16;
            __builtin_amdgcn_global_load_lds(
                (const __attribute__((address_space(1))) unsigned int*)src,
                (__attribute__((address_space(3))) unsigned int*)ldst, 16, 0, 0);
        }
    };

    stage(0, 0);
    __syncthreads();
    for (int t = 0; t < nk; ++t) {
        if (t + 1 < nk) stage((t + 1) & 1, (t + 1) * 32);
        const char* sA = &smem[t & 1][0];
        const char* sB = &smem[t & 1][ABYTES];
        int u = lane >> 4, r0 = lane & 15;
        bf16x8 af[FM], bfr[FN];
#pragma unroll
        for (int i = 0; i < FM; ++i) {
            int row = wm + i * 16 + r0;
            int su = u ^ (row & 3);
            af[i] = *(const bf16x8*)(sA + row * 64 + su * 16);
        }
#pragma unroll
        for (int j = 0; j < FN; ++j) {
            int row = wn + j * 16 + r0;
            int su = u ^ (row & 3);
            bfr[j] = *(const bf16x8*)(sB + row * 64 + su * 16);
        }
#pragma unroll
        for (int i = 0; i < FM; ++i)
#pragma unroll
            for (int j = 0; j < FN; ++j)
                acc[i][j] = __builtin_amdgcn_mfma_f32_16x16x32_bf16(af[i], bfr[j], acc[i][j], 0, 0, 0);
        __syncthreads();
    }

    int gid = 0;
#pragma unroll 1
    while (bn >= ea.nb[gid + 1]) ++gid;
    EpiG E = ea.g[gid];
    int colBase = ea.nb[gid];
#pragma unroll
    for (int i = 0; i < FM; ++i) {
#pragma unroll
        for (int j = 0; j < FN; ++j) {
#pragma unroll
            for (int q = 0; q < 4; ++q) {
                int gm = bm + wm + i * 16 + (lane >> 4) * 4 + q;
                int lc = bn + wn + j * 16 + (lane & 15) - colBase;
                if (lc < E.ntrue)
                    epi_store(E, (size_t)gm * E.ld + lc, lc, acc[i][j][q]);
            }
        }
    }
}

// ---------------- grouped low-rank GEMM ----------------

struct G2G { const __bf16* A; const __bf16* Bt; float* outF; const float* p1; const float* p2; int K; int epi; };
struct G2Args { G2G g[4]; };

template<int BM, int BN>
__global__ __launch_bounds__(256) void gemm_g2(G2Args ga) {
    G2G G = ga.g[blockIdx.z];
    const __bf16* A = G.A;
    const __bf16* Bt = G.Bt;
    int K = G.K;
    constexpr int FM = BM / 32, FN = BN / 32;
    constexpr int ABYTES = BM * 64;
    constexpr int TOT = (BM + BN) * 64;
    constexpr int NCHUNK = TOT / 4096;
    __shared__ __align__(16) char smem[2][TOT];
    int tid = threadIdx.x;
    int lane = tid & 63, wid = tid >> 6;
    int bm = blockIdx.y * BM, bn = blockIdx.x * BN;
    int wm = (wid >> 1) * (BM / 2), wn = (wid & 1) * (BN / 2);
    f32x4 acc[FM][FN];
#pragma unroll
    for (int i = 0; i < FM; ++i)
#pragma unroll
        for (int j = 0; j < FN; ++j) acc[i][j] = (f32x4){0.f, 0.f, 0.f, 0.f};

    int nk = K >> 5;
    auto stage = [&](int buf, int k0) {
        char* sb = &smem[buf][0];
#pragma unroll
        for (int c = 0; c < NCHUNK; ++c) {
            int d = c * 4096 + tid * 16;
            int isB = d >= ABYTES;
            int dd = isB ? d - ABYTES : d;
            int row = dd >> 6;
            int u = (dd >> 4) & 3;
            int su = u ^ (row & 3);
            const __bf16* src = isB ? (Bt + (size_t)(bn + row) * K + k0 + su * 8)
                                    : (A  + (size_t)(bm + row) * K + k0 + su * 8);
            char* ldst = sb + c * 4096 + (tid & 192) * 16;
            __builtin_amdgcn_global_load_lds(
                (const __attribute__((address_space(1))) unsigned int*)src,
                (__attribute__((address_space(3))) unsigned int*)ldst, 16, 0, 0);
        }
    };

    stage(0, 0);
    __syncthreads();
    for (int t = 0; t < nk; ++t) {
        if (t + 1 < nk) stage((t + 1) & 1, (t + 1) * 32);
        const char* sA = &smem[t & 1][0];
        const char* sB = &smem[t & 1][ABYTES];
        int u = lane >> 4, r0 = lane & 15;
        bf16x8 af[FM], bfr[FN];
#pragma unroll
        for (int i = 0; i < FM; ++i) {
            int row = wm + i * 16 + r0;
            int su = u ^ (row & 3);
            af[i] = *(const bf16x8*)(sA + row * 64 + su * 16);
        }
#pragma unroll
        for (int j = 0; j < FN; ++j) {
            int row = wn + j * 16 + r0;
            int su = u ^ (row & 3);
            bfr[j] = *(const bf16x8*)(sB + row * 64 + su * 16);
        }
#pragma unroll
        for (int i = 0; i < FM; ++i)
#pragma unroll
            for (int j = 0; j < FN; ++j)
                acc[i][j] = __builtin_amdgcn_mfma_f32_16x16x32_bf16(af[i], bfr[j], acc[i][j], 0, 0, 0);
        __syncthreads();
    }

    EpiG E;
    E.outF = G.outF; E.outH = nullptr; E.p1 = G.p1; E.p2 = G.p2;
    E.epi = G.epi; E.ld = 768; E.ntrue = 768;
#pragma unroll
    for (int i = 0; i < FM; ++i) {
#pragma unroll
        for (int j = 0; j < FN; ++j) {
#pragma unroll
            for (int q = 0; q < 4; ++q) {
                int gm = bm + wm + i * 16 + (lane >> 4) * 4 + q;
                int lc = bn + wn + j * 16 + (lane & 15);
                epi_store(E, (size_t)gm * 768 + lc, lc, acc[i][j][q]);
            }
        }
    }
}

// ---------------- chunked WKV7, phase A (register-tiled; M out as transposed bf16 pair) ----------------

__global__ __launch_bounds__(256) void chunkA_kernel(
    const float* __restrict__ r, const float* __restrict__ wd,
    const float* __restrict__ kraw, const float* __restrict__ av_,
    const float* __restrict__ v,
    const float* __restrict__ kkw, const float* __restrict__ kaw,
    float* __restrict__ kupd,
    float* __restrict__ yintra, float* __restrict__ zrO,
    __bf16* __restrict__ mtHi, __bf16* __restrict__ mtLo,
    float* __restrict__ zcO) {
    int c = blockIdx.x, bh = blockIdx.y;
    int b = bh / HH, h = bh % HH;
    __shared__ float Di[LCH][SPAD];
    __shared__ float Ah[LCH][SPAD];
    __shared__ float Bh[LCH][SPAD];
    __shared__ float Kh[LCH][SPAD];
    __shared__ float Rh[LCH][SPAD];
    __shared__ float Vt[LCH][SPAD];
    __shared__ float Qm[LCH][SPAD];
    __shared__ float Gba[LCH][LCH], Gka[LCH][LCH], Grb[LCH][LCH], Grk[LCH][LCH];
    int tid = threadIdx.x;
    int n = tid & 63, tq = tid >> 6;
    size_t base = ((size_t)(b * TT + c * LCH)) * CC + h * 64 + n;
    int cvec = h * 64 + n;
    float kkwv = kkw[cvec], kawv = kaw[cvec];
#pragma unroll
    for (int e = 0; e < 8; ++e) {
        int t = tq * 8 + e;
        size_t off = base + (size_t)t * CC;
        float kr = kraw[off];
        float aval = av_[off];
        float kk0 = kr * kkwv;
        float ss = kk0 * kk0;
        for (int m = 1; m < 64; m <<= 1) ss += __shfl_xor(ss, m);
        float rinv = 1.f / fmaxf(sqrtf(ss), 1e-12f);
        float kkv = kk0 * rinv;
        float ku = kr * (1.f + (aval - 1.f) * kawv);
        kupd[off] = ku;
        Di[t][n] = wd[off];
        Ah[t][n] = -kkv;
        Bh[t][n] = kkv * aval;
        Kh[t][n] = ku;
        Rh[t][n] = r[off];
        Vt[t][n] = v[off];
    }
    __syncthreads();
    if (tid < 64) {
        float d = 1.f;
        for (int t = 0; t < LCH; ++t) { d *= Di[t][tid]; Di[t][tid] = d; }
    }
    __syncthreads();
#pragma unroll
    for (int e = 0; e < 8; ++e) {
        int t = tq * 8 + e;
        float di = Di[t][n];
        float dp = (t == 0) ? 1.f : Di[t - 1][n];
        float inv = 1.f / di;
        Ah[t][n] *= dp;
        Bh[t][n] *= inv;
        Kh[t][n] *= inv;
        Rh[t][n] *= di;
    }
    __syncthreads();
    // ---- G phase: 2x2 (t,s) tiles ----
    {
        int tp = tid >> 4, sp = tid & 15;
        int t0 = 2 * tp, s0 = 2 * sp;
        float gba00 = 0.f, gba01 = 0.f, gba10 = 0.f, gba11 = 0.f;
        float gka00 = 0.f, gka01 = 0.f, gka10 = 0.f, gka11 = 0.f;
        float grb00 = 0.f, grb01 = 0.f, grb10 = 0.f, grb11 = 0.f;
        float grk00 = 0.f, grk01 = 0.f, grk10 = 0.f, grk11 = 0.f;
#pragma unroll 4
        for (int j = 0; j < 64; ++j) {
            float a0 = Ah[t0][j], a1 = Ah[t0 + 1][j];
            float r0 = Rh[t0][j], r1 = Rh[t0 + 1][j];
            float b0 = Bh[s0][j], b1 = Bh[s0 + 1][j];
            float k0 = Kh[s0][j], k1 = Kh[s0 + 1][j];
            gba00 = fmaf(a0, b0, gba00); gba01 = fmaf(a0, b1, gba01);
            gba10 = fmaf(a1, b0, gba10); gba11 = fmaf(a1, b1, gba11);
            gka00 = fmaf(a0, k0, gka00); gka01 = fmaf(a0, k1, gka01);
            gka10 = fmaf(a1, k0, gka10); gka11 = fmaf(a1, k1, gka11);
            grb00 = fmaf(r0, b0, grb00); grb01 = fmaf(r0, b1, grb01);
            grb10 = fmaf(r1, b0, grb10); grb11 = fmaf(r1, b1, grb11);
            grk00 = fmaf(r0, k0, grk00); grk01 = fmaf(r0, k1, grk01);
            grk10 = fmaf(r1, k0, grk10); grk11 = fmaf(r1, k1, grk11);
        }
#pragma unroll
        for (int dt = 0; dt < 2; ++dt) {
            int t = t0 + dt;
#pragma unroll
            for (int ds = 0; ds < 2; ++ds) {
                int s = s0 + ds;
                float vba = dt ? (ds ? gba11 : gba10) : (ds ? gba01 : gba00);
                float vka = dt ? (ds ? gka11 : gka10) : (ds ? gka01 : gka00);
                float vrb = dt ? (ds ? grb11 : grb10) : (ds ? grb01 : grb00);
                float vrk = dt ? (ds ? grk11 : grk10) : (ds ? grk01 : grk00);
                Gba[t][s] = (s < t)  ? vba : 0.f;
                Gka[t][s] = (s < t)  ? vka : 0.f;
                Grb[t][s] = (s <= t) ? vrb : 0.f;
                Grk[t][s] = (s <= t) ? vrk : 0.f;
            }
        }
    }
    __syncthreads();
    // ---- Qm = Gka V (s-outer) ----
    {
        float acc[8];
#pragma unroll
        for (int e = 0; e < 8; ++e) acc[e] = 0.f;
        for (int s = 0; s < LCH; ++s) {
            float vs = Vt[s][n];
#pragma unroll
            for (int e = 0; e < 8; ++e)
                acc[e] = fmaf(Gka[tq * 8 + e][s], vs, acc[e]);
        }
#pragma unroll
        for (int e = 0; e < 8; ++e) Qm[tq * 8 + e][n] = acc[e];
    }
    __syncthreads();
    // ---- forward substitution ----
    if (tq == 0) {
        for (int t = 1; t < LCH; ++t) {
            float acc = Ah[t][n];
            for (int s = 0; s < t; ++s) acc = fmaf(Gba[t][s], Ah[s][n], acc);
            Ah[t][n] = acc;
        }
    } else if (tq == 1) {
        for (int t = 1; t < LCH; ++t) {
            float acc = Qm[t][n];
            for (int s = 0; s < t; ++s) acc = fmaf(Gba[t][s], Qm[s][n], acc);
            Qm[t][n] = acc;
        }
    }
    __syncthreads();
    size_t obase = ((size_t)(bh * NC + c)) * LCH * 64;
    // ---- yintra / zr (s-outer) ----
    {
        float accY[8], accZ[8];
#pragma unroll
        for (int e = 0; e < 8; ++e) { accY[e] = 0.f; accZ[e] = Rh[tq * 8 + e][n]; }
        for (int s = 0; s < LCH; ++s) {
            float vs = Vt[s][n], qs = Qm[s][n], us = Ah[s][n];
#pragma unroll
            for (int e = 0; e < 8; ++e) {
                int t = tq * 8 + e;
                float grk_ = Grk[t][s], grb_ = Grb[t][s];
                accY[e] = fmaf(grk_, vs, fmaf(grb_, qs, accY[e]));
                accZ[e] = fmaf(grb_, us, accZ[e]);
            }
        }
#pragma unroll
        for (int e = 0; e < 8; ++e) {
            int t = tq * 8 + e;
            yintra[obase + t * 64 + n] = accY[e];
            zrO[obase + t * 64 + n] = accZ[e];
        }
    }
    // ---- M / Zc (4x4 tiles, s-outer); M stored transposed as bf16 hi/lo pair ----
    {
        int pi = tid >> 4, ni = tid & 15;
        float accM[4][4], accZc[4][4];
#pragma unroll
        for (int dp = 0; dp < 4; ++dp)
#pragma unroll
            for (int dn = 0; dn < 4; ++dn) { accM[dp][dn] = 0.f; accZc[dp][dn] = 0.f; }
        for (int s = 0; s < LCH; ++s) {
            float aa[4], vv[4], qq[4], bb[4], kk[4];
#pragma unroll
            for (int d = 0; d < 4; ++d) {
                aa[d] = Ah[s][4 * pi + d];
                vv[d] = Vt[s][4 * pi + d];
                qq[d] = Qm[s][4 * pi + d];
                bb[d] = Bh[s][4 * ni + d];
                kk[d] = Kh[s][4 * ni + d];
            }
#pragma unroll
            for (int dp = 0; dp < 4; ++dp)
#pragma unroll
                for (int dn = 0; dn < 4; ++dn) {
                    accM[dp][dn]  = fmaf(aa[dp], bb[dn], accM[dp][dn]);
                    accZc[dp][dn] = fmaf(vv[dp], kk[dn], fmaf(qq[dp], bb[dn], accZc[dp][dn]));
                }
        }
        size_t mbase = ((size_t)(bh * NC + c)) * 4096;
        float dl[4];
#pragma unroll
        for (int dn = 0; dn < 4; ++dn) dl[dn] = Di[LCH - 1][4 * ni + dn];
        // Zc fp32, row-major [p][n]
#pragma unroll
        for (int dp = 0; dp < 4; ++dp) {
            int p = 4 * pi + dp;
            f32x4 z4;
#pragma unroll
            for (int dn = 0; dn < 4; ++dn) z4[dn] = dl[dn] * accZc[dp][dn];
            *(f32x4*)(zcO + mbase + p * 64 + 4 * ni) = z4;
        }
        // M transposed [n][p], bf16 hi/lo split
#pragma unroll
        for (int dn = 0; dn < 4; ++dn) {
            int nn = 4 * ni + dn;
            float dlv = dl[dn];
            bf16x4 h4, l4;
#pragma unroll
            for (int dp = 0; dp < 4; ++dp) {
                int p = 4 * pi + dp;
                float mm = (accM[dp][dn] + ((p == nn) ? 1.f : 0.f)) * dlv;
                __bf16 hb = f2bb(mm);
                h4[dp] = hb;
                l4[dp] = f2bb(mm - bb2f(hb));
            }
            *(bf16x4*)(mtHi + mbase + (size_t)nn * 64 + 4 * pi) = h4;
            *(bf16x4*)(mtLo + mbase + (size_t)nn * 64 + 4 * pi) = l4;
        }
    }
}

// ---------------- phase B1: sequential state chain via split-precision MFMA ----------------
// FULLY UNROLLED chunk loop so the double-buffer index cb is compile-time
// (rule #20: runtime-indexed ext_vector arrays spill to scratch — r7 failure).

__global__ __launch_bounds__(256) void chunkB1_kernel(
    const float* __restrict__ zc,
    const __bf16* __restrict__ mtHi,
    const __bf16* __restrict__ mtLo,
    float* __restrict__ schk) {
    int bh = blockIdx.x;
    int tid = threadIdx.x;
    int lane = tid & 63, w = tid >> 6;
    int r0 = lane & 15, u = lane >> 4;
    __shared__ __align__(16) float S[64][68];
    for (int i = tid; i < 64 * 68; i += 256) (&S[0][0])[i] = 0.f;
    const float* zbase = zc + (size_t)bh * NC * 4096;
    const __bf16* hbase = mtHi + (size_t)bh * NC * 4096;
    const __bf16* lbase = mtLo + (size_t)bh * NC * 4096;
    float* sbase = schk + (size_t)bh * NC * 4096;
    int arow = w * 16 + r0;

    bf16x8 mh[2][4][2], ml[2][4][2];
    f32x4 zf[2][4];
    // preload chunk 0 fragments into buffer 0
#pragma unroll
    for (int ct = 0; ct < 4; ++ct) {
#pragma unroll
        for (int ks = 0; ks < 2; ++ks) {
            size_t mo = (size_t)(ct * 16 + r0) * 64 + ks * 32 + u * 8;
            mh[0][ct][ks] = *(const bf16x8*)(hbase + mo);
            ml[0][ct][ks] = *(const bf16x8*)(lbase + mo);
        }
#pragma unroll
        for (int q = 0; q < 4; ++q)
            zf[0][ct][q] = zbase[(size_t)(w * 16 + u * 4 + q) * 64 + ct * 16 + r0];
    }
    __syncthreads();
#pragma unroll
    for (int c = 0; c < NC - 1; ++c) {
        constexpr int dummy = 0; (void)dummy;
        const int cb = c & 1;          // compile-time after full unroll
        if (c + 1 < NC - 1) {
            const __bf16* hn = hbase + (size_t)(c + 1) * 4096;
            const __bf16* ln = lbase + (size_t)(c + 1) * 4096;
            const float* zn = zbase + (size_t)(c + 1) * 4096;
#pragma unroll
            for (int ct = 0; ct < 4; ++ct) {
#pragma unroll
                for (int ks = 0; ks < 2; ++ks) {
                    size_t mo = (size_t)(ct * 16 + r0) * 64 + ks * 32 + u * 8;
                    mh[cb ^ 1][ct][ks] = *(const bf16x8*)(hn + mo);
                    ml[cb ^ 1][ct][ks] = *(const bf16x8*)(ln + mo);
                }
#pragma unroll
                for (int q = 0; q < 4; ++q)
                    zf[cb ^ 1][ct][q] = zn[(size_t)(w * 16 + u * 4 + q) * 64 + ct * 16 + r0];
            }
        }
        // A fragments: read 8 f32 of S row, split into bf16 hi/lo
        bf16x8 ah[2], al[2];
#pragma unroll
        for (int ks = 0; ks < 2; ++ks) {
            f32x4 s0 = *(const f32x4*)&S[arow][ks * 32 + u * 8];
            f32x4 s1 = *(const f32x4*)&S[arow][ks * 32 + u * 8 + 4];
#pragma unroll
            for (int e = 0; e < 4; ++e) {
                __bf16 h0 = f2bb(s0[e]);
                ah[ks][e] = h0;
                al[ks][e] = f2bb(s0[e] - bb2f(h0));
                __bf16 h1 = f2bb(s1[e]);
                ah[ks][4 + e] = h1;
                al[ks][4 + e] = f2bb(s1[e] - bb2f(h1));
            }
        }
        f32x4 acc[4];
#pragma unroll
        for (int ct = 0; ct < 4; ++ct) {
            acc[ct] = zf[cb][ct];
#pragma unroll
            for (int ks = 0; ks < 2; ++ks) {
                acc[ct] = __builtin_amdgcn_mfma_f32_16x16x32_bf16(ah[ks], mh[cb][ct][ks], acc[ct], 0, 0, 0);
                acc[ct] = __builtin_amdgcn_mfma_f32_16x16x32_bf16(ah[ks], ml[cb][ct][ks], acc[ct], 0, 0, 0);
                acc[ct] = __builtin_amdgcn_mfma_f32_16x16x32_bf16(al[ks], mh[cb][ct][ks], acc[ct], 0, 0, 0);
            }
        }
        __syncthreads();   // all S reads complete
        float* cp = sbase + (size_t)(c + 1) * 4096;
#pragma unroll
        for (int ct = 0; ct < 4; ++ct) {
#pragma unroll
            for (int q = 0; q < 4; ++q) {
                int row = w * 16 + u * 4 + q;
                int col = ct * 16 + r0;
                S[row][col] = acc[ct][q];
                cp[(size_t)row * 64 + col] = acc[ct][q];
            }
        }
        __syncthreads();   // S_new visible before next chunk
    }
}

// ---------------- phase Y (unchanged) ----------------

__global__ __launch_bounds__(256) void chunkY_kernel(
    const float* __restrict__ yintra, const float* __restrict__ zrI,
    const float* __restrict__ schk,
    const float* __restrict__ r, const float* __restrict__ kupd,
    const float* __restrict__ v, const float* __restrict__ g,
    const float* __restrict__ rk, const float* __restrict__ lw,
    const float* __restrict__ lb, bf16* __restrict__ out) {
    int c = blockIdx.x, bh = blockIdx.y;
    int b = bh / HH, h = bh % HH;
    __shared__ float Y[LCH][SPAD];
    __shared__ float Zr[LCH][SPAD];
    __shared__ float Sh[64][SPAD];
    int tid = threadIdx.x;
    int n = tid & 63, tq = tid >> 6;
    size_t obase = ((size_t)(bh * NC + c)) * LCH * 64;
#pragma unroll
    for (int e = 0; e < 8; ++e) {
        int idx = tid + e * 256;
        int row = idx >> 6, col = idx & 63;
        Y[row][col] = yintra[obase + idx];
        Zr[row][col] = zrI[obase + idx];
    }
    if (c > 0) {
        size_t sbase = ((size_t)(bh * NC + c)) * 4096;
#pragma unroll
        for (int e = 0; e < 16; ++e) {
            int idx = tid + e * 256;
            Sh[idx >> 6][idx & 63] = schk[sbase + idx];
        }
    }
    __syncthreads();
    if (c > 0) {
        float acc[8];
#pragma unroll
        for (int e = 0; e < 8; ++e) acc[e] = 0.f;
        for (int p = 0; p < 64; ++p) {
            float sv = Sh[n][p];
#pragma unroll
            for (int e = 0; e < 8; ++e)
                acc[e] = fmaf(Zr[tq * 8 + e][p], sv, acc[e]);
        }
#pragma unroll
        for (int e = 0; e < 8; ++e) Y[tq * 8 + e][n] += acc[e];
    }
    size_t rowbase = ((size_t)(b * TT + c * LCH)) * CC + h * 64 + n;
    float rkv = rk[h * 64 + n];
    float lwv = lw[h * 64 + n], lbv = lb[h * 64 + n];
#pragma unroll
    for (int e = 0; e < 8; ++e) {
        int t = tq * 8 + e;
        size_t off = rowbase + (size_t)t * CC;
        float yv = Y[t][n];
        float rv = r[off], kv = kupd[off], vv = v[off];
        float s1 = yv, s2 = yv * yv, s3 = rv * kv * rkv;
        for (int m = 1; m < 64; m <<= 1) {
            s1 += __shfl_xor(s1, m);
            s2 += __shfl_xor(s2, m);
            s3 += __shfl_xor(s3, m);
        }
        float mean = s1 * (1.f / 64.f);
        float var  = s2 * (1.f / 64.f) - mean * mean;
        float inv  = rsqrtf(var + 64e-5f);
        float val  = (yv - mean) * inv * lwv + lbv + s3 * vv;
        out[off] = f2b(val * g[off]);
    }
}

// ---------------- host ----------------

extern "C" void kernel_launch(void* const* d_in, const int* in_sizes, int n_in,
                              void* d_out, int out_size, void* d_ws, size_t ws_size,
                              hipStream_t stream) {
    (void)in_sizes; (void)n_in; (void)out_size;
    const float* x    = (const float*)d_in[0];
    const float* x_r  = (const float*)d_in[1];
    const float* x_w  = (const float*)d_in[2];
    const float* x_k  = (const float*)d_in[3];
    const float* x_v  = (const float*)d_in[4];
    const float* x_a  = (const float*)d_in[5];
    const float* x_g  = (const float*)d_in[6];
    const float* w0   = (const float*)d_in[7];
    const float* w1   = (const float*)d_in[8];
    const float* w2   = (const float*)d_in[9];
    const float* a0   = (const float*)d_in[10];
    const float* a1   = (const float*)d_in[11];
    const float* a2   = (const float*)d_in[12];
    const float* v0   = (const float*)d_in[13];
    const float* v1   = (const float*)d_in[14];
    const float* v2   = (const float*)d_in[15];
    const float* g1   = (const float*)d_in[16];
    const float* g2   = (const float*)d_in[17];
    const float* k_k  = (const float*)d_in[18];
    const float* k_a  = (const float*)d_in[19];
    const float* r_k  = (const float*)d_in[20];
    const float* W_r  = (const float*)d_in[21];
    const float* W_k  = (const float*)d_in[22];
    const float* W_v  = (const float*)d_in[23];
    const float* W_o  = (const float*)d_in[24];
    const float* ln_x_w = (const float*)d_in[25];
    const float* ln_x_b = (const float*)d_in[26];
    const float* ln1_w  = (const float*)d_in[27];
    const float* ln1_b  = (const float*)d_in[28];
    const float* ln2_w  = (const float*)d_in[29];
    const float* ln2_b  = (const float*)d_in[30];
    const float* c_x_k  = (const float*)d_in[31];
    const float* W_ck   = (const float*)d_in[32];
    const float* W_cv   = (const float*)d_in[33];

    const size_t MC = (size_t)MT * CC;
    char* wsb = (char*)d_ws;
    size_t woff = 0;
    auto alloc = [&](size_t bytes) -> void* {
        void* p = wsb + woff;
        woff += (bytes + 255) & ~(size_t)255;
        return p;
    };
    bf16* Bcat  = (bf16*)alloc((size_t)2624 * 1536 * 2);
    bf16* Bck   = (bf16*)alloc((size_t)3072 * 1536 * 2);
    bf16* w2t   = (bf16*)alloc((size_t)768 * 64 * 2);
    bf16* a2t   = (bf16*)alloc((size_t)768 * 64 * 2);
    bf16* v2t   = (bf16*)alloc((size_t)768 * 32 * 2);
    bf16* g2t   = (bf16*)alloc((size_t)768 * 128 * 2);
    bf16* Wo_t  = (bf16*)alloc((size_t)768 * 768 * 2);
    bf16* Wcv_t = (bf16*)alloc((size_t)768 * 3072 * 2);
    bf16* A1    = (bf16*)alloc((size_t)MT * 1536 * 2);
    float* rbuf  = (float*)alloc(MC * 4);
    float* kraw  = (float*)alloc(MC * 4);
    float* kupd  = (float*)alloc(MC * 4);
    float* vbuf  = (float*)alloc(MC * 4);
    float* vfirst= (float*)alloc(MC * 4);
    float* abuf  = (float*)alloc(MC * 4);
    float* dbuf  = (float*)alloc(MC * 4);
    float* gbuf  = (float*)alloc(MC * 4);
    bf16* w1o   = (bf16*)alloc((size_t)MT * 64 * 2);
    bf16* a1o   = (bf16*)alloc((size_t)MT * 64 * 2);
    bf16* v1o   = (bf16*)alloc((size_t)MT * 32 * 2);
    bf16* g1o   = (bf16*)alloc((size_t)MT * 128 * 2);
    bf16* hbuf  = (bf16*)alloc((size_t)MT * FF * 2);
    bf16* ghout = (bf16*)alloc(MC * 2);
    float* yintraW = (float*)alloc((size_t)BH * NC * LCH * 64 * 4);
    float* zrW     = (float*)alloc((size_t)BH * NC * LCH * 64 * 4);
    __bf16* mtHiW  = (__bf16*)alloc((size_t)BH * NC * 4096 * 2);
    __bf16* mtLoW  = (__bf16*)alloc((size_t)BH * NC * 4096 * 2);
    float* zcW     = (float*)alloc((size_t)BH * NC * 4096 * 4);
    float* schkW   = (float*)alloc((size_t)BH * NC * 4096 * 4);
    if (woff > ws_size) return;

    float* xcur = (float*)d_out;
    copy_f<<<MC / 256, 256, 0, stream>>>(xcur, x);

    for (int l = 0; l < LAYERS; ++l) {
        size_t oC = (size_t)l * CC;
        float* vptr = (l == 0) ? vfirst : vbuf;

        CArgs ca;
        ca.e[0]  = {W_r  + (size_t)l * 589824, x_r + oC, Bcat,               768, 768, 768, 1536, 0};
        ca.e[1]  = {W_k  + (size_t)l * 589824, x_k + oC, Bcat + (size_t)768  * 1536, 768, 768, 768, 1536, 0};
        ca.e[2]  = {W_v  + (size_t)l * 589824, x_v + oC, Bcat + (size_t)1536 * 1536, 768, 768, 768, 1536, 0};
        ca.e[3]  = {w1   + (size_t)l * 49152,  x_w + oC, Bcat + (size_t)2304 * 1536, 768, 64, 64, 1536, 0};
        ca.e[4]  = {a1   + (size_t)l * 49152,  x_a + oC, Bcat + (size_t)2368 * 1536, 768, 64, 64, 1536, 0};
        ca.e[5]  = {g1   + (size_t)l * 98304,  x_g + oC, Bcat + (size_t)2432 * 1536, 768, 128, 128, 1536, 0};
        ca.e[6]  = {v1   + (size_t)l * 24576,  x_v + oC, Bcat + (size_t)2560 * 1536, 768, 32, 64, 1536, 0};
        ca.e[7]  = {W_ck + (size_t)l * 2359296, c_x_k + oC, Bck, 768, 3072, 3072, 1536, 0};
        ca.e[8]  = {w2   + (size_t)l * 49152,  nullptr, w2t,   64, 768, 768, 64, 0};
        ca.e[9]  = {a2   + (size_t)l * 49152,  nullptr, a2t,   64, 768, 768, 64, 0};
        ca.e[10] = {v2   + (size_t)l * 24576,  nullptr, v2t,   32, 768, 768, 32, 0};
        ca.e[11] = {g2   + (size_t)l * 98304,  nullptr, g2t,  128, 768, 768, 128, 0};
        ca.e[12] = {W_o  + (size_t)l * 589824, nullptr, Wo_t, 768, 768, 768, 768, 0};
        ca.e[13] = {W_cv + (size_t)l * 2359296, nullptr, Wcv_t, 3072, 768, 768, 3072, 0};
        int btot = 0;
        for (int i = 0; i < 14; ++i) {
            ca.e[i].bstart = btot;
            btot += (ca.e[i].Npad >> 5) * (ca.e[i].Kdst >> 5);
        }
        convert_weights<<<btot, 256, 0, stream>>>(ca);

        // ---- time mix ----
        ln_shift_kernel<<<MT, 256, 0, stream>>>(xcur, ln1_w + oC, ln1_b + oC, A1);

        EpiArgs e1;
        e1.g[0] = {rbuf,  nullptr, nullptr, nullptr, 0, 768, 768};
        e1.g[1] = {kraw,  nullptr, nullptr, nullptr, 0, 768, 768};
        e1.g[2] = {vptr,  nullptr, nullptr, nullptr, 0, 768, 768};
        e1.g[3] = {nullptr, w1o, nullptr, nullptr, 2, 64, 64};
        e1.g[4] = {nullptr, a1o, nullptr, nullptr, 1, 64, 64};
        e1.g[5] = {nullptr, g1o, nullptr, nullptr, 3, 128, 128};
        e1.g[6] = {nullptr, v1o, nullptr, nullptr, 1, 32, 32};
        int nb1[8] = {0, 768, 1536, 2304, 2368, 2432, 2560, 2624};
        for (int i = 0; i < 8; ++i) e1.nb[i] = nb1[i];
        gemm_multi<128, 64><<<dim3(41, 8), 256, 0, stream>>>((const __bf16*)A1, (const __bf16*)Bcat, 1536, e1);

        G2Args g2a;
        g2a.g[0] = {(const __bf16*)w1o, (const __bf16*)w2t, dbuf, w0 + oC, nullptr, 64, 6};
        g2a.g[1] = {(const __bf16*)a1o, (const __bf16*)a2t, abuf, a0 + oC, nullptr, 64, 7};
        g2a.g[2] = {(const __bf16*)g1o, (const __bf16*)g2t, gbuf, nullptr, nullptr, 128, 0};
        g2a.g[3] = {(const __bf16*)v1o, (const __bf16*)v2t, vbuf, v0 + oC, vfirst, 32, 8};
        gemm_g2<128, 64><<<dim3(12, 8, (l == 0) ? 3 : 4), 256, 0, stream>>>(g2a);

        // ---- chunked scan ----
        chunkA_kernel<<<dim3(NC, BH), 256, 0, stream>>>(rbuf, dbuf, kraw, abuf, vptr,
                                                        k_k + oC, k_a + oC, kupd,
                                                        yintraW, zrW, mtHiW, mtLoW, zcW);
        chunkB1_kernel<<<BH, 256, 0, stream>>>(zcW, mtHiW, mtLoW, schkW);
        chunkY_kernel<<<dim3(NC, BH), 256, 0, stream>>>(yintraW, zrW, schkW,
                                                        rbuf, kupd, vptr, gbuf,
                                                        r_k + (size_t)l * 768,
                                                        ln_x_w + oC, ln_x_b + oC, ghout);

        EpiArgs eo;
        eo.g[0] = {xcur, nullptr, nullptr, nullptr, 5, 768, 768};
        eo.nb[0] = 0; for (int i = 1; i < 8; ++i) eo.nb[i] = 1 << 30;
        eo.nb[1] = 768;
        gemm_multi<64, 64><<<dim3(12, 16), 256, 0, stream>>>((const __bf16*)ghout, (const __bf16*)Wo_t, 768, eo);

        // ---- channel mix ----
        ln_shift_kernel<<<MT, 256, 0, stream>>>(xcur, ln2_w + oC, ln2_b + oC, A1);

        EpiArgs ec;
        ec.g[0] = {nullptr, hbuf, nullptr, nullptr, 4, 3072, 3072};
        ec.nb[0] = 0; for (int i = 1; i < 8; ++i) ec.nb[i] = 1 << 30;
        ec.nb[1] = 3072;
        gemm_multi<128, 64><<<dim3(48, 8), 256, 0, stream>>>((const __bf16*)A1, (const __bf16*)Bck, 1536, ec);

        EpiArgs ev;
        ev.g[0] = {xcur, nullptr, nullptr, nullptr, 5, 768, 768};
        ev.nb[0] = 0; for (int i = 1; i < 8; ++i) ev.nb[i] = 1 << 30;
        ev.nb[1] = 768;
        gemm_multi<64, 64><<<dim3(12, 16), 256, 0, stream>>>((const __bf16*)hbuf, (const __bf16*)Wcv_t, 3072, ev);
    }
}

// Round 9
// 1409.677 us; speedup vs baseline: 1.2371x; 1.0519x over previous
//
#include <hip/hip_runtime.h>
#include <hip/hip_bf16.h>
#include <math.h>

#define LAYERS 6
#define BBATCH 2
#define TT 512
#define CC 768
#define HH 12
#define MT (BBATCH*TT)      // 1024 tokens
#define FF (4*CC)           // 3072
#define LCH 32
#define NC (TT/LCH)         // 16 chunks
#define BH (BBATCH*HH)      // 24
#define SPAD 65

typedef __hip_bfloat16 bf16;
typedef __bf16 bf16x8 __attribute__((ext_vector_type(8)));
typedef __bf16 bf16x4 __attribute__((ext_vector_type(4)));
typedef float f32x4 __attribute__((ext_vector_type(4)));

__device__ inline bf16 f2b(float f) { return __float2bfloat16(f); }
__device__ inline __bf16 f2bb(float f) {
    __hip_bfloat16 h = __float2bfloat16(f);
    return __builtin_bit_cast(__bf16, h);
}
__device__ inline float bb2f(__bf16 h) {
    return __bfloat162float(__builtin_bit_cast(__hip_bfloat16, h));
}

// ---------------- utility ----------------

__global__ __launch_bounds__(256) void copy_f(float* __restrict__ dst, const float* __restrict__ src) {
    size_t i = (size_t)blockIdx.x * 256 + threadIdx.x;
    dst[i] = src[i];
}

// ---------------- fused layernorm + token-shift-diff, bf16 concat output ----------------

__global__ __launch_bounds__(256) void ln_shift_kernel(const float* __restrict__ x,
                                                       const float* __restrict__ w,
                                                       const float* __restrict__ b,
                                                       bf16* __restrict__ out) {
    int row = blockIdx.x;
    int t = row % TT;
    const float* xr = x + (size_t)row * CC;
    const float* xp = xr - CC;
    int tid = threadIdx.x;
    float c0 = xr[tid], c1 = xr[tid + 256], c2 = xr[tid + 512];
    float p0 = 0.f, p1 = 0.f, p2 = 0.f;
    if (t > 0) { p0 = xp[tid]; p1 = xp[tid + 256]; p2 = xp[tid + 512]; }
    float s  = c0 + c1 + c2, q  = c0 * c0 + c1 * c1 + c2 * c2;
    float sp = p0 + p1 + p2, qp = p0 * p0 + p1 * p1 + p2 * p2;
    for (int m = 1; m < 64; m <<= 1) {
        s += __shfl_xor(s, m); q += __shfl_xor(q, m);
        sp += __shfl_xor(sp, m); qp += __shfl_xor(qp, m);
    }
    __shared__ float rs[4], rq[4], rsp[4], rqp[4];
    int wid = tid >> 6;
    if ((tid & 63) == 0) { rs[wid] = s; rq[wid] = q; rsp[wid] = sp; rqp[wid] = qp; }
    __syncthreads();
    s  = rs[0] + rs[1] + rs[2] + rs[3];   q  = rq[0] + rq[1] + rq[2] + rq[3];
    sp = rsp[0] + rsp[1] + rsp[2] + rsp[3]; qp = rqp[0] + rqp[1] + rqp[2] + rqp[3];
    float meanC = s * (1.f / CC);
    float invC  = rsqrtf(q * (1.f / CC) - meanC * meanC + 1e-5f);
    float meanP = sp * (1.f / CC);
    float invP  = rsqrtf(qp * (1.f / CC) - meanP * meanP + 1e-5f);
    bf16* orow = out + (size_t)row * 1536;
    float cv[3] = {c0, c1, c2};
    float pv[3] = {p0, p1, p2};
#pragma unroll
    for (int j = 0; j < 3; ++j) {
        int cc = tid + j * 256;
        float lnc = (cv[j] - meanC) * invC * w[cc] + b[cc];
        float lnp = (t > 0) ? (pv[j] - meanP) * invP * w[cc] + b[cc] : 0.f;
        orow[cc] = f2b(lnc);
        orow[768 + cc] = f2b(lnp - lnc);
    }
}

// ---------------- weight convert (packed 1D grid) ----------------

struct CEntry { const float* W; const float* mix; bf16* dst; int Ksrc, Nsrc, Npad, Kdst, bstart; };
struct CArgs { CEntry e[14]; };

__global__ __launch_bounds__(256) void convert_weights(CArgs ca) {
    int bid = blockIdx.x;
    int idx = 0;
#pragma unroll
    for (int i = 1; i < 14; ++i) if (bid >= ca.e[i].bstart) idx = i;
    CEntry E = ca.e[idx];
    int t = bid - E.bstart;
    int ntN = E.Npad >> 5;
    int tn = (t % ntN) * 32, tk = (t / ntN) * 32;
    __shared__ float tile[32][33];
    int c = threadIdx.x & 31, r0 = threadIdx.x >> 5;
    int ks = tk;
    const float* mixp = nullptr;
    if (tk >= E.Ksrc) { ks = tk - E.Ksrc; mixp = E.mix; }
#pragma unroll
    for (int i = 0; i < 4; ++i) {
        int r = r0 + i * 8;
        float v = (tn + c < E.Nsrc) ? E.W[(size_t)(ks + r) * E.Nsrc + tn + c] : 0.f;
        if (mixp) v *= mixp[ks + r];
        tile[r][c] = v;
    }
    __syncthreads();
#pragma unroll
    for (int i = 0; i < 4; ++i) {
        int r = r0 + i * 8;
        E.dst[(size_t)(tn + r) * E.Kdst + tk + c] = f2b(tile[c][r]);
    }
}

// ---------------- epilogues ----------------

struct EpiG {
    float* outF; bf16* outH;
    const float* p1; const float* p2;
    int epi, ld, ntrue;
};
struct EpiArgs { EpiG g[7]; int nb[8]; };

__device__ inline void epi_store(const EpiG& E, size_t idx, int lc, float v) {
    switch (E.epi) {
        case 0: E.outF[idx] = v; break;
        case 1: E.outH[idx] = f2b(v); break;
        case 2: E.outH[idx] = f2b(tanhf(v)); break;
        case 3: E.outH[idx] = f2b(1.f / (1.f + expf(-v))); break;
        case 4: { float t = fmaxf(v, 0.f); E.outH[idx] = f2b(t * t); } break;
        case 5: E.outF[idx] += v; break;
        case 6: { float z = E.p1[lc] + v; float nz = -z;
                  float sp = (nz > 20.f) ? nz : log1pf(expf(nz));
                  E.outF[idx] = expf(-expf(-sp - 0.5f)); } break;
        case 7: E.outF[idx] = 1.f / (1.f + expf(-(E.p1[lc] + v))); break;
        case 8: { float vv = E.outF[idx];
                  float s = 1.f / (1.f + expf(-(E.p1[lc] + v)));
                  E.outF[idx] = vv + (E.p2[idx] - vv) * s; } break;
    }
}

// ---------------- bf16 MFMA GEMM, BK=64, XCD-swizzled, grouped-column epilogue ----------------
// LDS rows of 128B (64 bf16); 16B slot swizzle: slot_lds = slot_global ^ (row & 7)
// (per 16-lane phase banks = 4*(slot^(r&7)) -> 2-way = free).

template<int BM, int BN>
__global__ __launch_bounds__(256) void gemm_multi(const __bf16* __restrict__ A,
                                                  const __bf16* __restrict__ Bt,
                                                  int K, EpiArgs ea) {
    constexpr int FM = BM / 32, FN = BN / 32;
    constexpr int ABYTES = BM * 128;
    constexpr int TOT = (BM + BN) * 128;
    constexpr int NCHUNK = TOT / 4096;
    __shared__ __align__(16) char smem[2][TOT];
    int tid = threadIdx.x;
    int lane = tid & 63, wid = tid >> 6;
    // bijective XCD-chunked remap (m204): contiguous tile ranges per XCD
    int nwg = gridDim.x * gridDim.y;
    int orig = blockIdx.y * gridDim.x + blockIdx.x;
    int qq = nwg >> 3, rr = nwg & 7, xc = orig & 7, oo = orig >> 3;
    int swz = (xc < rr ? xc * (qq + 1) : rr * (qq + 1) + (xc - rr) * qq) + oo;
    int bn = (swz % gridDim.x) * BN, bm = (swz / gridDim.x) * BM;
    int wm = (wid >> 1) * (BM / 2), wn = (wid & 1) * (BN / 2);
    f32x4 acc[FM][FN];
#pragma unroll
    for (int i = 0; i < FM; ++i)
#pragma unroll
        for (int j = 0; j < FN; ++j) acc[i][j] = (f32x4){0.f, 0.f, 0.f, 0.f};

    int nk = K >> 6;
    auto stage = [&](int buf, int k0) {
        char* sb = &smem[buf][0];
#pragma unroll
        for (int c = 0; c < NCHUNK; ++c) {
            int d = c * 4096 + tid * 16;
            int isB = d >= ABYTES;
            int dd = isB ? d - ABYTES : d;
            int row = dd >> 7;
            int slot = (dd >> 4) & 7;
            int su = slot ^ (row & 7);
            const __bf16* src = isB ? (Bt + (size_t)(bn + row) * K + k0 + su * 8)
                                    : (A  + (size_t)(bm + row) * K + k0 + su * 8);
            char* ldst = sb + c * 4096 + (tid & 192) * 16;
            __builtin_amdgcn_global_load_lds(
                (const __attribute__((address_space(1))) unsigned int*)src,
                (__attribute__((address_space(3))) unsigned int*)ldst, 16, 0, 0);
        }
    };

    stage(0, 0);
    __syncthreads();
    for (int t = 0; t < nk; ++t) {
        if (t + 1 < nk) stage((t + 1) & 1, (t + 1) * 64);
        const char* sA = &smem[t & 1][0];
        const char* sB = &smem[t & 1][ABYTES];
        int u = lane >> 4, r0 = lane & 15;
        bf16x8 af[2][FM], bfr[2][FN];
#pragma unroll
        for (int ks = 0; ks < 2; ++ks) {
#pragma unroll
            for (int i = 0; i < FM; ++i) {
                int row = wm + i * 16 + r0;
                int slot = (ks * 4 + u) ^ (row & 7);
                af[ks][i] = *(const bf16x8*)(sA + row * 128 + slot * 16);
            }
#pragma unroll
            for (int j = 0; j < FN; ++j) {
                int row = wn + j * 16 + r0;
                int slot = (ks * 4 + u) ^ (row & 7);
                bfr[ks][j] = *(const bf16x8*)(sB + row * 128 + slot * 16);
            }
        }
#pragma unroll
        for (int ks = 0; ks < 2; ++ks)
#pragma unroll
            for (int i = 0; i < FM; ++i)
#pragma unroll
                for (int j = 0; j < FN; ++j)
                    acc[i][j] = __builtin_amdgcn_mfma_f32_16x16x32_bf16(af[ks][i], bfr[ks][j], acc[i][j], 0, 0, 0);
        __syncthreads();
    }

    int gid = 0;
#pragma unroll 1
    while (bn >= ea.nb[gid + 1]) ++gid;
    EpiG E = ea.g[gid];
    int colBase = ea.nb[gid];
#pragma unroll
    for (int i = 0; i < FM; ++i) {
#pragma unroll
        for (int j = 0; j < FN; ++j) {
#pragma unroll
            for (int q = 0; q < 4; ++q) {
                int gm = bm + wm + i * 16 + (lane >> 4) * 4 + q;
                int lc = bn + wn + j * 16 + (lane & 15) - colBase;
                if (lc < E.ntrue)
                    epi_store(E, (size_t)gm * E.ld + lc, lc, acc[i][j][q]);
            }
        }
    }
}

// ---------------- grouped low-rank GEMM (BK=32; fixed 2-way swizzle) ----------------

struct G2G { const __bf16* A; const __bf16* Bt; float* outF; const float* p1; const float* p2; int K; int epi; };
struct G2Args { G2G g[4]; };

template<int BM, int BN>
__global__ __launch_bounds__(256) void gemm_g2(G2Args ga) {
    G2G G = ga.g[blockIdx.z];
    const __bf16* A = G.A;
    const __bf16* Bt = G.Bt;
    int K = G.K;
    constexpr int FM = BM / 32, FN = BN / 32;
    constexpr int ABYTES = BM * 64;
    constexpr int TOT = (BM + BN) * 64;
    constexpr int NCHUNK = TOT / 4096;
    __shared__ __align__(16) char smem[2][TOT];
    int tid = threadIdx.x;
    int lane = tid & 63, wid = tid >> 6;
    int bm = blockIdx.y * BM, bn = blockIdx.x * BN;
    int wm = (wid >> 1) * (BM / 2), wn = (wid & 1) * (BN / 2);
    f32x4 acc[FM][FN];
#pragma unroll
    for (int i = 0; i < FM; ++i)
#pragma unroll
        for (int j = 0; j < FN; ++j) acc[i][j] = (f32x4){0.f, 0.f, 0.f, 0.f};

    int nk = K >> 5;
    auto stage = [&](int buf, int k0) {
        char* sb = &smem[buf][0];
#pragma unroll
        for (int c = 0; c < NCHUNK; ++c) {
            int d = c * 4096 + tid * 16;
            int isB = d >= ABYTES;
            int dd = isB ? d - ABYTES : d;
            int row = dd >> 6;
            int u = (dd >> 4) & 3;
            int su = u ^ ((row >> 1) & 3);
            const __bf16* src = isB ? (Bt + (size_t)(bn + row) * K + k0 + su * 8)
                                    : (A  + (size_t)(bm + row) * K + k0 + su * 8);
            char* ldst = sb + c * 4096 + (tid & 192) * 16;
            __builtin_amdgcn_global_load_lds(
                (const __attribute__((address_space(1))) unsigned int*)src,
                (__attribute__((address_space(3))) unsigned int*)ldst, 16, 0, 0);
        }
    };

    stage(0, 0);
    __syncthreads();
    for (int t = 0; t < nk; ++t) {
        if (t + 1 < nk) stage((t + 1) & 1, (t + 1) * 32);
        const char* sA = &smem[t & 1][0];
        const char* sB = &smem[t & 1][ABYTES];
        int u = lane >> 4, r0 = lane & 15;
        bf16x8 af[FM], bfr[FN];
#pragma unroll
        for (int i = 0; i < FM; ++i) {
            int row = wm + i * 16 + r0;
            int su = u ^ ((row >> 1) & 3);
            af[i] = *(const bf16x8*)(sA + row * 64 + su * 16);
        }
#pragma unroll
        for (int j = 0; j < FN; ++j) {
            int row = wn + j * 16 + r0;
            int su = u ^ ((row >> 1) & 3);
            bfr[j] = *(const bf16x8*)(sB + row * 64 + su * 16);
        }
#pragma unroll
        for (int i = 0; i < FM; ++i)
#pragma unroll
            for (int j = 0; j < FN; ++j)
                acc[i][j] = __builtin_amdgcn_mfma_f32_16x16x32_bf16(af[i], bfr[j], acc[i][j], 0, 0, 0);
        __syncthreads();
    }

    EpiG E;
    E.outF = G.outF; E.outH = nullptr; E.p1 = G.p1; E.p2 = G.p2;
    E.epi = G.epi; E.ld = 768; E.ntrue = 768;
#pragma unroll
    for (int i = 0; i < FM; ++i) {
#pragma unroll
        for (int j = 0; j < FN; ++j) {
#pragma unroll
            for (int q = 0; q < 4; ++q) {
                int gm = bm + wm + i * 16 + (lane >> 4) * 4 + q;
                int lc = bn + wn + j * 16 + (lane & 15);
                epi_store(E, (size_t)gm * 768 + lc, lc, acc[i][j][q]);
            }
        }
    }
}

// ---------------- chunked WKV7, phase A (register-tiled; M out as transposed bf16 pair) ----------------

__global__ __launch_bounds__(256) void chunkA_kernel(
    const float* __restrict__ r, const float* __restrict__ wd,
    const float* __restrict__ kraw, const float* __restrict__ av_,
    const float* __restrict__ v,
    const float* __restrict__ kkw, const float* __restrict__ kaw,
    float* __restrict__ kupd,
    float* __restrict__ yintra, float* __restrict__ zrO,
    __bf16* __restrict__ mtHi, __bf16* __restrict__ mtLo,
    float* __restrict__ zcO) {
    int c = blockIdx.x, bh = blockIdx.y;
    int b = bh / HH, h = bh % HH;
    __shared__ float Di[LCH][SPAD];
    __shared__ float Ah[LCH][SPAD];
    __shared__ float Bh[LCH][SPAD];
    __shared__ float Kh[LCH][SPAD];
    __shared__ float Rh[LCH][SPAD];
    __shared__ float Vt[LCH][SPAD];
    __shared__ float Qm[LCH][SPAD];
    __shared__ float Gba[LCH][LCH], Gka[LCH][LCH], Grb[LCH][LCH], Grk[LCH][LCH];
    int tid = threadIdx.x;
    int n = tid & 63, tq = tid >> 6;
    size_t base = ((size_t)(b * TT + c * LCH)) * CC + h * 64 + n;
    int cvec = h * 64 + n;
    float kkwv = kkw[cvec], kawv = kaw[cvec];
#pragma unroll
    for (int e = 0; e < 8; ++e) {
        int t = tq * 8 + e;
        size_t off = base + (size_t)t * CC;
        float kr = kraw[off];
        float aval = av_[off];
        float kk0 = kr * kkwv;
        float ss = kk0 * kk0;
        for (int m = 1; m < 64; m <<= 1) ss += __shfl_xor(ss, m);
        float rinv = 1.f / fmaxf(sqrtf(ss), 1e-12f);
        float kkv = kk0 * rinv;
        float ku = kr * (1.f + (aval - 1.f) * kawv);
        kupd[off] = ku;
        Di[t][n] = wd[off];
        Ah[t][n] = -kkv;
        Bh[t][n] = kkv * aval;
        Kh[t][n] = ku;
        Rh[t][n] = r[off];
        Vt[t][n] = v[off];
    }
    __syncthreads();
    if (tid < 64) {
        float d = 1.f;
        for (int t = 0; t < LCH; ++t) { d *= Di[t][tid]; Di[t][tid] = d; }
    }
    __syncthreads();
#pragma unroll
    for (int e = 0; e < 8; ++e) {
        int t = tq * 8 + e;
        float di = Di[t][n];
        float dp = (t == 0) ? 1.f : Di[t - 1][n];
        float inv = 1.f / di;
        Ah[t][n] *= dp;
        Bh[t][n] *= inv;
        Kh[t][n] *= inv;
        Rh[t][n] *= di;
    }
    __syncthreads();
    // ---- G phase: 2x2 (t,s) tiles ----
    {
        int tp = tid >> 4, sp = tid & 15;
        int t0 = 2 * tp, s0 = 2 * sp;
        float gba00 = 0.f, gba01 = 0.f, gba10 = 0.f, gba11 = 0.f;
        float gka00 = 0.f, gka01 = 0.f, gka10 = 0.f, gka11 = 0.f;
        float grb00 = 0.f, grb01 = 0.f, grb10 = 0.f, grb11 = 0.f;
        float grk00 = 0.f, grk01 = 0.f, grk10 = 0.f, grk11 = 0.f;
#pragma unroll 4
        for (int j = 0; j < 64; ++j) {
            float a0 = Ah[t0][j], a1 = Ah[t0 + 1][j];
            float r0 = Rh[t0][j], r1 = Rh[t0 + 1][j];
            float b0 = Bh[s0][j], b1 = Bh[s0 + 1][j];
            float k0 = Kh[s0][j], k1 = Kh[s0 + 1][j];
            gba00 = fmaf(a0, b0, gba00); gba01 = fmaf(a0, b1, gba01);
            gba10 = fmaf(a1, b0, gba10); gba11 = fmaf(a1, b1, gba11);
            gka00 = fmaf(a0, k0, gka00); gka01 = fmaf(a0, k1, gka01);
            gka10 = fmaf(a1, k0, gka10); gka11 = fmaf(a1, k1, gka11);
            grb00 = fmaf(r0, b0, grb00); grb01 = fmaf(r0, b1, grb01);
            grb10 = fmaf(r1, b0, grb10); grb11 = fmaf(r1, b1, grb11);
            grk00 = fmaf(r0, k0, grk00); grk01 = fmaf(r0, k1, grk01);
            grk10 = fmaf(r1, k0, grk10); grk11 = fmaf(r1, k1, grk11);
        }
#pragma unroll
        for (int dt = 0; dt < 2; ++dt) {
            int t = t0 + dt;
#pragma unroll
            for (int ds = 0; ds < 2; ++ds) {
                int s = s0 + ds;
                float vba = dt ? (ds ? gba11 : gba10) : (ds ? gba01 : gba00);
                float vka = dt ? (ds ? gka11 : gka10) : (ds ? gka01 : gka00);
                float vrb = dt ? (ds ? grb11 : grb10) : (ds ? grb01 : grb00);
                float vrk = dt ? (ds ? grk11 : grk10) : (ds ? grk01 : grk00);
                Gba[t][s] = (s < t)  ? vba : 0.f;
                Gka[t][s] = (s < t)  ? vka : 0.f;
                Grb[t][s] = (s <= t) ? vrb : 0.f;
                Grk[t][s] = (s <= t) ? vrk : 0.f;
            }
        }
    }
    __syncthreads();
    // ---- Qm = Gka V (s-outer) ----
    {
        float acc[8];
#pragma unroll
        for (int e = 0; e < 8; ++e) acc[e] = 0.f;
        for (int s = 0; s < LCH; ++s) {
            float vs = Vt[s][n];
#pragma unroll
            for (int e = 0; e < 8; ++e)
                acc[e] = fmaf(Gka[tq * 8 + e][s], vs, acc[e]);
        }
#pragma unroll
        for (int e = 0; e < 8; ++e) Qm[tq * 8 + e][n] = acc[e];
    }
    __syncthreads();
    // ---- forward substitution ----
    if (tq == 0) {
        for (int t = 1; t < LCH; ++t) {
            float acc = Ah[t][n];
            for (int s = 0; s < t; ++s) acc = fmaf(Gba[t][s], Ah[s][n], acc);
            Ah[t][n] = acc;
        }
    } else if (tq == 1) {
        for (int t = 1; t < LCH; ++t) {
            float acc = Qm[t][n];
            for (int s = 0; s < t; ++s) acc = fmaf(Gba[t][s], Qm[s][n], acc);
            Qm[t][n] = acc;
        }
    }
    __syncthreads();
    size_t obase = ((size_t)(bh * NC + c)) * LCH * 64;
    // ---- yintra / zr (s-outer) ----
    {
        float accY[8], accZ[8];
#pragma unroll
        for (int e = 0; e < 8; ++e) { accY[e] = 0.f; accZ[e] = Rh[tq * 8 + e][n]; }
        for (int s = 0; s < LCH; ++s) {
            float vs = Vt[s][n], qs = Qm[s][n], us = Ah[s][n];
#pragma unroll
            for (int e = 0; e < 8; ++e) {
                int t = tq * 8 + e;
                float grk_ = Grk[t][s], grb_ = Grb[t][s];
                accY[e] = fmaf(grk_, vs, fmaf(grb_, qs, accY[e]));
                accZ[e] = fmaf(grb_, us, accZ[e]);
            }
        }
#pragma unroll
        for (int e = 0; e < 8; ++e) {
            int t = tq * 8 + e;
            yintra[obase + t * 64 + n] = accY[e];
            zrO[obase + t * 64 + n] = accZ[e];
        }
    }
    // ---- M / Zc (4x4 tiles, s-outer); M stored transposed as bf16 hi/lo pair ----
    {
        int pi = tid >> 4, ni = tid & 15;
        float accM[4][4], accZc[4][4];
#pragma unroll
        for (int dp = 0; dp < 4; ++dp)
#pragma unroll
            for (int dn = 0; dn < 4; ++dn) { accM[dp][dn] = 0.f; accZc[dp][dn] = 0.f; }
        for (int s = 0; s < LCH; ++s) {
            float aa[4], vv[4], qq[4], bb[4], kk[4];
#pragma unroll
            for (int d = 0; d < 4; ++d) {
                aa[d] = Ah[s][4 * pi + d];
                vv[d] = Vt[s][4 * pi + d];
                qq[d] = Qm[s][4 * pi + d];
                bb[d] = Bh[s][4 * ni + d];
                kk[d] = Kh[s][4 * ni + d];
            }
#pragma unroll
            for (int dp = 0; dp < 4; ++dp)
#pragma unroll
                for (int dn = 0; dn < 4; ++dn) {
                    accM[dp][dn]  = fmaf(aa[dp], bb[dn], accM[dp][dn]);
                    accZc[dp][dn] = fmaf(vv[dp], kk[dn], fmaf(qq[dp], bb[dn], accZc[dp][dn]));
                }
        }
        size_t mbase = ((size_t)(bh * NC + c)) * 4096;
        float dl[4];
#pragma unroll
        for (int dn = 0; dn < 4; ++dn) dl[dn] = Di[LCH - 1][4 * ni + dn];
        // Zc fp32, row-major [p][n]
#pragma unroll
        for (int dp = 0; dp < 4; ++dp) {
            int p = 4 * pi + dp;
            f32x4 z4;
#pragma unroll
            for (int dn = 0; dn < 4; ++dn) z4[dn] = dl[dn] * accZc[dp][dn];
            *(f32x4*)(zcO + mbase + p * 64 + 4 * ni) = z4;
        }
        // M transposed [n][p], bf16 hi/lo split
#pragma unroll
        for (int dn = 0; dn < 4; ++dn) {
            int nn = 4 * ni + dn;
            float dlv = dl[dn];
            bf16x4 h4, l4;
#pragma unroll
            for (int dp = 0; dp < 4; ++dp) {
                int p = 4 * pi + dp;
                float mm = (accM[dp][dn] + ((p == nn) ? 1.f : 0.f)) * dlv;
                __bf16 hb = f2bb(mm);
                h4[dp] = hb;
                l4[dp] = f2bb(mm - bb2f(hb));
            }
            *(bf16x4*)(mtHi + mbase + (size_t)nn * 64 + 4 * pi) = h4;
            *(bf16x4*)(mtLo + mbase + (size_t)nn * 64 + 4 * pi) = l4;
        }
    }
}

// ---------------- phase B1: sequential state chain via split-precision MFMA ----------------
// FULLY UNROLLED chunk loop so the double-buffer index cb is compile-time (rule #20).

__global__ __launch_bounds__(256) void chunkB1_kernel(
    const float* __restrict__ zc,
    const __bf16* __restrict__ mtHi,
    const __bf16* __restrict__ mtLo,
    float* __restrict__ schk) {
    int bh = blockIdx.x;
    int tid = threadIdx.x;
    int lane = tid & 63, w = tid >> 6;
    int r0 = lane & 15, u = lane >> 4;
    __shared__ __align__(16) float S[64][68];
    for (int i = tid; i < 64 * 68; i += 256) (&S[0][0])[i] = 0.f;
    const float* zbase = zc + (size_t)bh * NC * 4096;
    const __bf16* hbase = mtHi + (size_t)bh * NC * 4096;
    const __bf16* lbase = mtLo + (size_t)bh * NC * 4096;
    float* sbase = schk + (size_t)bh * NC * 4096;
    int arow = w * 16 + r0;

    bf16x8 mh[2][4][2], ml[2][4][2];
    f32x4 zf[2][4];
#pragma unroll
    for (int ct = 0; ct < 4; ++ct) {
#pragma unroll
        for (int ks = 0; ks < 2; ++ks) {
            size_t mo = (size_t)(ct * 16 + r0) * 64 + ks * 32 + u * 8;
            mh[0][ct][ks] = *(const bf16x8*)(hbase + mo);
            ml[0][ct][ks] = *(const bf16x8*)(lbase + mo);
        }
#pragma unroll
        for (int q = 0; q < 4; ++q)
            zf[0][ct][q] = zbase[(size_t)(w * 16 + u * 4 + q) * 64 + ct * 16 + r0];
    }
    __syncthreads();
#pragma unroll
    for (int c = 0; c < NC - 1; ++c) {
        const int cb = c & 1;          // compile-time after full unroll
        if (c + 1 < NC - 1) {
            const __bf16* hn = hbase + (size_t)(c + 1) * 4096;
            const __bf16* ln = lbase + (size_t)(c + 1) * 4096;
            const float* zn = zbase + (size_t)(c + 1) * 4096;
#pragma unroll
            for (int ct = 0; ct < 4; ++ct) {
#pragma unroll
                for (int ks = 0; ks < 2; ++ks) {
                    size_t mo = (size_t)(ct * 16 + r0) * 64 + ks * 32 + u * 8;
                    mh[cb ^ 1][ct][ks] = *(const bf16x8*)(hn + mo);
                    ml[cb ^ 1][ct][ks] = *(const bf16x8*)(ln + mo);
                }
#pragma unroll
                for (int q = 0; q < 4; ++q)
                    zf[cb ^ 1][ct][q] = zn[(size_t)(w * 16 + u * 4 + q) * 64 + ct * 16 + r0];
            }
        }
        bf16x8 ah[2], al[2];
#pragma unroll
        for (int ks = 0; ks < 2; ++ks) {
            f32x4 s0 = *(const f32x4*)&S[arow][ks * 32 + u * 8];
            f32x4 s1 = *(const f32x4*)&S[arow][ks * 32 + u * 8 + 4];
#pragma unroll
            for (int e = 0; e < 4; ++e) {
                __bf16 h0 = f2bb(s0[e]);
                ah[ks][e] = h0;
                al[ks][e] = f2bb(s0[e] - bb2f(h0));
                __bf16 h1 = f2bb(s1[e]);
                ah[ks][4 + e] = h1;
                al[ks][4 + e] = f2bb(s1[e] - bb2f(h1));
            }
        }
        f32x4 acc[4];
#pragma unroll
        for (int ct = 0; ct < 4; ++ct) {
            acc[ct] = zf[cb][ct];
#pragma unroll
            for (int ks = 0; ks < 2; ++ks) {
                acc[ct] = __builtin_amdgcn_mfma_f32_16x16x32_bf16(ah[ks], mh[cb][ct][ks], acc[ct], 0, 0, 0);
                acc[ct] = __builtin_amdgcn_mfma_f32_16x16x32_bf16(ah[ks], ml[cb][ct][ks], acc[ct], 0, 0, 0);
                acc[ct] = __builtin_amdgcn_mfma_f32_16x16x32_bf16(al[ks], mh[cb][ct][ks], acc[ct], 0, 0, 0);
            }
        }
        __syncthreads();   // all S reads complete
        float* cp = sbase + (size_t)(c + 1) * 4096;
#pragma unroll
        for (int ct = 0; ct < 4; ++ct) {
#pragma unroll
            for (int q = 0; q < 4; ++q) {
                int row = w * 16 + u * 4 + q;
                int col = ct * 16 + r0;
                S[row][col] = acc[ct][q];
                cp[(size_t)row * 64 + col] = acc[ct][q];
            }
        }
        __syncthreads();   // S_new visible before next chunk
    }
}

// ---------------- phase Y (unchanged) ----------------

__global__ __launch_bounds__(256) void chunkY_kernel(
    const float* __restrict__ yintra, const float* __restrict__ zrI,
    const float* __restrict__ schk,
    const float* __restrict__ r, const float* __restrict__ kupd,
    const float* __restrict__ v, const float* __restrict__ g,
    const float* __restrict__ rk, const float* __restrict__ lw,
    const float* __restrict__ lb, bf16* __restrict__ out) {
    int c = blockIdx.x, bh = blockIdx.y;
    int b = bh / HH, h = bh % HH;
    __shared__ float Y[LCH][SPAD];
    __shared__ float Zr[LCH][SPAD];
    __shared__ float Sh[64][SPAD];
    int tid = threadIdx.x;
    int n = tid & 63, tq = tid >> 6;
    size_t obase = ((size_t)(bh * NC + c)) * LCH * 64;
#pragma unroll
    for (int e = 0; e < 8; ++e) {
        int idx = tid + e * 256;
        int row = idx >> 6, col = idx & 63;
        Y[row][col] = yintra[obase + idx];
        Zr[row][col] = zrI[obase + idx];
    }
    if (c > 0) {
        size_t sbase = ((size_t)(bh * NC + c)) * 4096;
#pragma unroll
        for (int e = 0; e < 16; ++e) {
            int idx = tid + e * 256;
            Sh[idx >> 6][idx & 63] = schk[sbase + idx];
        }
    }
    __syncthreads();
    if (c > 0) {
        float acc[8];
#pragma unroll
        for (int e = 0; e < 8; ++e) acc[e] = 0.f;
        for (int p = 0; p < 64; ++p) {
            float sv = Sh[n][p];
#pragma unroll
            for (int e = 0; e < 8; ++e)
                acc[e] = fmaf(Zr[tq * 8 + e][p], sv, acc[e]);
        }
#pragma unroll
        for (int e = 0; e < 8; ++e) Y[tq * 8 + e][n] += acc[e];
    }
    size_t rowbase = ((size_t)(b * TT + c * LCH)) * CC + h * 64 + n;
    float rkv = rk[h * 64 + n];
    float lwv = lw[h * 64 + n], lbv = lb[h * 64 + n];
#pragma unroll
    for (int e = 0; e < 8; ++e) {
        int t = tq * 8 + e;
        size_t off = rowbase + (size_t)t * CC;
        float yv = Y[t][n];
        float rv = r[off], kv = kupd[off], vv = v[off];
        float s1 = yv, s2 = yv * yv, s3 = rv * kv * rkv;
        for (int m = 1; m < 64; m <<= 1) {
            s1 += __shfl_xor(s1, m);
            s2 += __shfl_xor(s2, m);
            s3 += __shfl_xor(s3, m);
        }
        float mean = s1 * (1.f / 64.f);
        float var  = s2 * (1.f / 64.f) - mean * mean;
        float inv  = rsqrtf(var + 64e-5f);
        float val  = (yv - mean) * inv * lwv + lbv + s3 * vv;
        out[off] = f2b(val * g[off]);
    }
}

// ---------------- host ----------------

extern "C" void kernel_launch(void* const* d_in, const int* in_sizes, int n_in,
                              void* d_out, int out_size, void* d_ws, size_t ws_size,
                              hipStream_t stream) {
    (void)in_sizes; (void)n_in; (void)out_size;
    const float* x    = (const float*)d_in[0];
    const float* x_r  = (const float*)d_in[1];
    const float* x_w  = (const float*)d_in[2];
    const float* x_k  = (const float*)d_in[3];
    const float* x_v  = (const float*)d_in[4];
    const float* x_a  = (const float*)d_in[5];
    const float* x_g  = (const float*)d_in[6];
    const float* w0   = (const float*)d_in[7];
    const float* w1   = (const float*)d_in[8];
    const float* w2   = (const float*)d_in[9];
    const float* a0   = (const float*)d_in[10];
    const float* a1   = (const float*)d_in[11];
    const float* a2   = (const float*)d_in[12];
    const float* v0   = (const float*)d_in[13];
    const float* v1   = (const float*)d_in[14];
    const float* v2   = (const float*)d_in[15];
    const float* g1   = (const float*)d_in[16];
    const float* g2   = (const float*)d_in[17];
    const float* k_k  = (const float*)d_in[18];
    const float* k_a  = (const float*)d_in[19];
    const float* r_k  = (const float*)d_in[20];
    const float* W_r  = (const float*)d_in[21];
    const float* W_k  = (const float*)d_in[22];
    const float* W_v  = (const float*)d_in[23];
    const float* W_o  = (const float*)d_in[24];
    const float* ln_x_w = (const float*)d_in[25];
    const float* ln_x_b = (const float*)d_in[26];
    const float* ln1_w  = (const float*)d_in[27];
    const float* ln1_b  = (const float*)d_in[28];
    const float* ln2_w  = (const float*)d_in[29];
    const float* ln2_b  = (const float*)d_in[30];
    const float* c_x_k  = (const float*)d_in[31];
    const float* W_ck   = (const float*)d_in[32];
    const float* W_cv   = (const float*)d_in[33];

    const size_t MC = (size_t)MT * CC;
    char* wsb = (char*)d_ws;
    size_t woff = 0;
    auto alloc = [&](size_t bytes) -> void* {
        void* p = wsb + woff;
        woff += (bytes + 255) & ~(size_t)255;
        return p;
    };
    bf16* Bcat  = (bf16*)alloc((size_t)2624 * 1536 * 2);
    bf16* Bck   = (bf16*)alloc((size_t)3072 * 1536 * 2);
    bf16* w2t   = (bf16*)alloc((size_t)768 * 64 * 2);
    bf16* a2t   = (bf16*)alloc((size_t)768 * 64 * 2);
    bf16* v2t   = (bf16*)alloc((size_t)768 * 32 * 2);
    bf16* g2t   = (bf16*)alloc((size_t)768 * 128 * 2);
    bf16* Wo_t  = (bf16*)alloc((size_t)768 * 768 * 2);
    bf16* Wcv_t = (bf16*)alloc((size_t)768 * 3072 * 2);
    bf16* A1    = (bf16*)alloc((size_t)MT * 1536 * 2);
    float* rbuf  = (float*)alloc(MC * 4);
    float* kraw  = (float*)alloc(MC * 4);
    float* kupd  = (float*)alloc(MC * 4);
    float* vbuf  = (float*)alloc(MC * 4);
    float* vfirst= (float*)alloc(MC * 4);
    float* abuf  = (float*)alloc(MC * 4);
    float* dbuf  = (float*)alloc(MC * 4);
    float* gbuf  = (float*)alloc(MC * 4);
    bf16* w1o   = (bf16*)alloc((size_t)MT * 64 * 2);
    bf16* a1o   = (bf16*)alloc((size_t)MT * 64 * 2);
    bf16* v1o   = (bf16*)alloc((size_t)MT * 32 * 2);
    bf16* g1o   = (bf16*)alloc((size_t)MT * 128 * 2);
    bf16* hbuf  = (bf16*)alloc((size_t)MT * FF * 2);
    bf16* ghout = (bf16*)alloc(MC * 2);
    float* yintraW = (float*)alloc((size_t)BH * NC * LCH * 64 * 4);
    float* zrW     = (float*)alloc((size_t)BH * NC * LCH * 64 * 4);
    __bf16* mtHiW  = (__bf16*)alloc((size_t)BH * NC * 4096 * 2);
    __bf16* mtLoW  = (__bf16*)alloc((size_t)BH * NC * 4096 * 2);
    float* zcW     = (float*)alloc((size_t)BH * NC * 4096 * 4);
    float* schkW   = (float*)alloc((size_t)BH * NC * 4096 * 4);
    if (woff > ws_size) return;

    float* xcur = (float*)d_out;
    copy_f<<<MC / 256, 256, 0, stream>>>(xcur, x);

    for (int l = 0; l < LAYERS; ++l) {
        size_t oC = (size_t)l * CC;
        float* vptr = (l == 0) ? vfirst : vbuf;

        CArgs ca;
        ca.e[0]  = {W_r  + (size_t)l * 589824, x_r + oC, Bcat,               768, 768, 768, 1536, 0};
        ca.e[1]  = {W_k  + (size_t)l * 589824, x_k + oC, Bcat + (size_t)768  * 1536, 768, 768, 768, 1536, 0};
        ca.e[2]  = {W_v  + (size_t)l * 589824, x_v + oC, Bcat + (size_t)1536 * 1536, 768, 768, 768, 1536, 0};
        ca.e[3]  = {w1   + (size_t)l * 49152,  x_w + oC, Bcat + (size_t)2304 * 1536, 768, 64, 64, 1536, 0};
        ca.e[4]  = {a1   + (size_t)l * 49152,  x_a + oC, Bcat + (size_t)2368 * 1536, 768, 64, 64, 1536, 0};
        ca.e[5]  = {g1   + (size_t)l * 98304,  x_g + oC, Bcat + (size_t)2432 * 1536, 768, 128, 128, 1536, 0};
        ca.e[6]  = {v1   + (size_t)l * 24576,  x_v + oC, Bcat + (size_t)2560 * 1536, 768, 32, 64, 1536, 0};
        ca.e[7]  = {W_ck + (size_t)l * 2359296, c_x_k + oC, Bck, 768, 3072, 3072, 1536, 0};
        ca.e[8]  = {w2   + (size_t)l * 49152,  nullptr, w2t,   64, 768, 768, 64, 0};
        ca.e[9]  = {a2   + (size_t)l * 49152,  nullptr, a2t,   64, 768, 768, 64, 0};
        ca.e[10] = {v2   + (size_t)l * 24576,  nullptr, v2t,   32, 768, 768, 32, 0};
        ca.e[11] = {g2   + (size_t)l * 98304,  nullptr, g2t,  128, 768, 768, 128, 0};
        ca.e[12] = {W_o  + (size_t)l * 589824, nullptr, Wo_t, 768, 768, 768, 768, 0};
        ca.e[13] = {W_cv + (size_t)l * 2359296, nullptr, Wcv_t, 3072, 768, 768, 3072, 0};
        int btot = 0;
        for (int i = 0; i < 14; ++i) {
            ca.e[i].bstart = btot;
            btot += (ca.e[i].Npad >> 5) * (ca.e[i].Kdst >> 5);
        }
        convert_weights<<<btot, 256, 0, stream>>>(ca);

        // ---- time mix ----
        ln_shift_kernel<<<MT, 256, 0, stream>>>(xcur, ln1_w + oC, ln1_b + oC, A1);

        EpiArgs e1;
        e1.g[0] = {rbuf,  nullptr, nullptr, nullptr, 0, 768, 768};
        e1.g[1] = {kraw,  nullptr, nullptr, nullptr, 0, 768, 768};
        e1.g[2] = {vptr,  nullptr, nullptr, nullptr, 0, 768, 768};
        e1.g[3] = {nullptr, w1o, nullptr, nullptr, 2, 64, 64};
        e1.g[4] = {nullptr, a1o, nullptr, nullptr, 1, 64, 64};
        e1.g[5] = {nullptr, g1o, nullptr, nullptr, 3, 128, 128};
        e1.g[6] = {nullptr, v1o, nullptr, nullptr, 1, 32, 32};
        int nb1[8] = {0, 768, 1536, 2304, 2368, 2432, 2560, 2624};
        for (int i = 0; i < 8; ++i) e1.nb[i] = nb1[i];
        gemm_multi<128, 64><<<dim3(41, 8), 256, 0, stream>>>((const __bf16*)A1, (const __bf16*)Bcat, 1536, e1);

        G2Args g2a;
        g2a.g[0] = {(const __bf16*)w1o, (const __bf16*)w2t, dbuf, w0 + oC, nullptr, 64, 6};
        g2a.g[1] = {(const __bf16*)a1o, (const __bf16*)a2t, abuf, a0 + oC, nullptr, 64, 7};
        g2a.g[2] = {(const __bf16*)g1o, (const __bf16*)g2t, gbuf, nullptr, nullptr, 128, 0};
        g2a.g[3] = {(const __bf16*)v1o, (const __bf16*)v2t, vbuf, v0 + oC, vfirst, 32, 8};
        gemm_g2<128, 64><<<dim3(12, 8, (l == 0) ? 3 : 4), 256, 0, stream>>>(g2a);

        // ---- chunked scan ----
        chunkA_kernel<<<dim3(NC, BH), 256, 0, stream>>>(rbuf, dbuf, kraw, abuf, vptr,
                                                        k_k + oC, k_a + oC, kupd,
                                                        yintraW, zrW, mtHiW, mtLoW, zcW);
        chunkB1_kernel<<<BH, 256, 0, stream>>>(zcW, mtHiW, mtLoW, schkW);
        chunkY_kernel<<<dim3(NC, BH), 256, 0, stream>>>(yintraW, zrW, schkW,
                                                        rbuf, kupd, vptr, gbuf,
                                                        r_k + (size_t)l * 768,
                                                        ln_x_w + oC, ln_x_b + oC, ghout);

        EpiArgs eo;
        eo.g[0] = {xcur, nullptr, nullptr, nullptr, 5, 768, 768};
        eo.nb[0] = 0; for (int i = 1; i < 8; ++i) eo.nb[i] = 1 << 30;
        eo.nb[1] = 768;
        gemm_multi<64, 64><<<dim3(12, 16), 256, 0, stream>>>((const __bf16*)ghout, (const __bf16*)Wo_t, 768, eo);

        // ---- channel mix ----
        ln_shift_kernel<<<MT, 256, 0, stream>>>(xcur, ln2_w + oC, ln2_b + oC, A1);

        EpiArgs ec;
        ec.g[0] = {nullptr, hbuf, nullptr, nullptr, 4, 3072, 3072};
        ec.nb[0] = 0; for (int i = 1; i < 8; ++i) ec.nb[i] = 1 << 30;
        ec.nb[1] = 3072;
        gemm_multi<128, 64><<<dim3(48, 8), 256, 0, stream>>>((const __bf16*)A1, (const __bf16*)Bck, 1536, ec);

        EpiArgs ev;
        ev.g[0] = {xcur, nullptr, nullptr, nullptr, 5, 768, 768};
        ev.nb[0] = 0; for (int i = 1; i < 8; ++i) ev.nb[i] = 1 << 30;
        ev.nb[1] = 768;
        gemm_multi<64, 64><<<dim3(12, 16), 256, 0, stream>>>((const __bf16*)hbuf, (const __bf16*)Wcv_t, 3072, ev);
    }
}

// Round 11
// 1355.664 us; speedup vs baseline: 1.2864x; 1.0398x over previous
//
#include <hip/hip_runtime.h>
#include <hip/hip_bf16.h>
#include <math.h>

#define LAYERS 6
#define BBATCH 2
#define TT 512
#define CC 768
#define HH 12
#define MT (BBATCH*TT)      // 1024 tokens
#define FF (4*CC)           // 3072
#define LCH 32
#define NC (TT/LCH)         // 16 chunks
#define BH (BBATCH*HH)      // 24
#define SPAD 65

typedef __hip_bfloat16 bf16;
typedef __bf16 bf16x8 __attribute__((ext_vector_type(8)));
typedef __bf16 bf16x4 __attribute__((ext_vector_type(4)));
typedef float f32x4 __attribute__((ext_vector_type(4)));

__device__ inline bf16 f2b(float f) { return __float2bfloat16(f); }
__device__ inline __bf16 f2bb(float f) {
    __hip_bfloat16 h = __float2bfloat16(f);
    return __builtin_bit_cast(__bf16, h);
}
__device__ inline float bb2f(__bf16 h) {
    return __bfloat162float(__builtin_bit_cast(__hip_bfloat16, h));
}

// ---------------- utility ----------------

__global__ __launch_bounds__(256) void copy_f(float* __restrict__ dst, const float* __restrict__ src) {
    size_t i = (size_t)blockIdx.x * 256 + threadIdx.x;
    dst[i] = src[i];
}

// ---------------- fused layernorm + token-shift-diff, bf16 concat output ----------------

__global__ __launch_bounds__(256) void ln_shift_kernel(const float* __restrict__ x,
                                                       const float* __restrict__ w,
                                                       const float* __restrict__ b,
                                                       bf16* __restrict__ out) {
    int row = blockIdx.x;
    int t = row % TT;
    const float* xr = x + (size_t)row * CC;
    const float* xp = xr - CC;
    int tid = threadIdx.x;
    float c0 = xr[tid], c1 = xr[tid + 256], c2 = xr[tid + 512];
    float p0 = 0.f, p1 = 0.f, p2 = 0.f;
    if (t > 0) { p0 = xp[tid]; p1 = xp[tid + 256]; p2 = xp[tid + 512]; }
    float s  = c0 + c1 + c2, q  = c0 * c0 + c1 * c1 + c2 * c2;
    float sp = p0 + p1 + p2, qp = p0 * p0 + p1 * p1 + p2 * p2;
    for (int m = 1; m < 64; m <<= 1) {
        s += __shfl_xor(s, m); q += __shfl_xor(q, m);
        sp += __shfl_xor(sp, m); qp += __shfl_xor(qp, m);
    }
    __shared__ float rs[4], rq[4], rsp[4], rqp[4];
    int wid = tid >> 6;
    if ((tid & 63) == 0) { rs[wid] = s; rq[wid] = q; rsp[wid] = sp; rqp[wid] = qp; }
    __syncthreads();
    s  = rs[0] + rs[1] + rs[2] + rs[3];   q  = rq[0] + rq[1] + rq[2] + rq[3];
    sp = rsp[0] + rsp[1] + rsp[2] + rsp[3]; qp = rqp[0] + rqp[1] + rqp[2] + rqp[3];
    float meanC = s * (1.f / CC);
    float invC  = rsqrtf(q * (1.f / CC) - meanC * meanC + 1e-5f);
    float meanP = sp * (1.f / CC);
    float invP  = rsqrtf(qp * (1.f / CC) - meanP * meanP + 1e-5f);
    bf16* orow = out + (size_t)row * 1536;
    float cv[3] = {c0, c1, c2};
    float pv[3] = {p0, p1, p2};
#pragma unroll
    for (int j = 0; j < 3; ++j) {
        int cc = tid + j * 256;
        float lnc = (cv[j] - meanC) * invC * w[cc] + b[cc];
        float lnp = (t > 0) ? (pv[j] - meanP) * invP * w[cc] + b[cc] : 0.f;
        orow[cc] = f2b(lnc);
        orow[768 + cc] = f2b(lnp - lnc);
    }
}

// ---------------- weight convert: ALL LAYERS in one launch (grid.y = layer) ----------------

struct CEntry { const float* W; const float* mix; bf16* dst;
                int Ksrc, Nsrc, Npad, Kdst, bstart, wstr, dstr; };
struct CArgs { CEntry e[14]; };

__global__ __launch_bounds__(256) void convert_weights(CArgs ca) {
    int bid = blockIdx.x;
    int l = blockIdx.y;
    int idx = 0;
#pragma unroll
    for (int i = 1; i < 14; ++i) if (bid >= ca.e[i].bstart) idx = i;
    CEntry E = ca.e[idx];
    const float* Wsrc = E.W + (size_t)l * E.wstr;
    bf16* d = E.dst + (size_t)l * E.dstr;
    int t = bid - E.bstart;
    int ntN = E.Npad >> 5;
    int tn = (t % ntN) * 32, tk = (t / ntN) * 32;
    __shared__ float tile[32][33];
    int c = threadIdx.x & 31, r0 = threadIdx.x >> 5;
    int ks = tk;
    const float* mixp = nullptr;
    if (tk >= E.Ksrc) { ks = tk - E.Ksrc; mixp = E.mix + (size_t)l * CC; }
#pragma unroll
    for (int i = 0; i < 4; ++i) {
        int r = r0 + i * 8;
        float v = (tn + c < E.Nsrc) ? Wsrc[(size_t)(ks + r) * E.Nsrc + tn + c] : 0.f;
        if (mixp) v *= mixp[ks + r];
        tile[r][c] = v;
    }
    __syncthreads();
#pragma unroll
    for (int i = 0; i < 4; ++i) {
        int r = r0 + i * 8;
        d[(size_t)(tn + r) * E.Kdst + tk + c] = f2b(tile[c][r]);
    }
}

// ---------------- epilogues ----------------

struct EpiG {
    float* outF; bf16* outH;
    const float* p1; const float* p2;
    int epi, ld, ntrue;
};
struct EpiArgs { EpiG g[7]; int nb[8]; };

__device__ inline void epi_store(const EpiG& E, size_t idx, int lc, float v) {
    switch (E.epi) {
        case 0: E.outF[idx] = v; break;
        case 1: E.outH[idx] = f2b(v); break;
        case 2: E.outH[idx] = f2b(tanhf(v)); break;
        case 3: E.outH[idx] = f2b(1.f / (1.f + expf(-v))); break;
        case 4: { float t = fmaxf(v, 0.f); E.outH[idx] = f2b(t * t); } break;
        case 5: E.outF[idx] += v; break;
        case 6: { float z = E.p1[lc] + v; float nz = -z;
                  float sp = (nz > 20.f) ? nz : log1pf(expf(nz));
                  E.outF[idx] = expf(-expf(-sp - 0.5f)); } break;
        case 7: E.outF[idx] = 1.f / (1.f + expf(-(E.p1[lc] + v))); break;
        case 8: { float vv = E.outF[idx];
                  float s = 1.f / (1.f + expf(-(E.p1[lc] + v)));
                  E.outF[idx] = vv + (E.p2[idx] - vv) * s; } break;
    }
}

// ---------------- bf16 MFMA GEMM, BK=64, XCD-swizzled, grouped-column epilogue ----------------

template<int BM, int BN>
__global__ __launch_bounds__(256) void gemm_multi(const __bf16* __restrict__ A,
                                                  const __bf16* __restrict__ Bt,
                                                  int K, EpiArgs ea) {
    constexpr int FM = BM / 32, FN = BN / 32;
    constexpr int ABYTES = BM * 128;
    constexpr int TOT = (BM + BN) * 128;
    constexpr int NCHUNK = TOT / 4096;
    __shared__ __align__(16) char smem[2][TOT];
    int tid = threadIdx.x;
    int lane = tid & 63, wid = tid >> 6;
    int nwg = gridDim.x * gridDim.y;
    int orig = blockIdx.y * gridDim.x + blockIdx.x;
    int qq = nwg >> 3, rr = nwg & 7, xc = orig & 7, oo = orig >> 3;
    int swz = (xc < rr ? xc * (qq + 1) : rr * (qq + 1) + (xc - rr) * qq) + oo;
    int bn = (swz % gridDim.x) * BN, bm = (swz / gridDim.x) * BM;
    int wm = (wid >> 1) * (BM / 2), wn = (wid & 1) * (BN / 2);
    f32x4 acc[FM][FN];
#pragma unroll
    for (int i = 0; i < FM; ++i)
#pragma unroll
        for (int j = 0; j < FN; ++j) acc[i][j] = (f32x4){0.f, 0.f, 0.f, 0.f};

    int nk = K >> 6;
    auto stage = [&](int buf, int k0) {
        char* sb = &smem[buf][0];
#pragma unroll
        for (int c = 0; c < NCHUNK; ++c) {
            int d = c * 4096 + tid * 16;
            int isB = d >= ABYTES;
            int dd = isB ? d - ABYTES : d;
            int row = dd >> 7;
            int slot = (dd >> 4) & 7;
            int su = slot ^ (row & 7);
            const __bf16* src = isB ? (Bt + (size_t)(bn + row) * K + k0 + su * 8)
                                    : (A  + (size_t)(bm + row) * K + k0 + su * 8);
            char* ldst = sb + c * 4096 + (tid & 192) * 16;
            __builtin_amdgcn_global_load_lds(
                (const __attribute__((address_space(1))) unsigned int*)src,
                (__attribute__((address_space(3))) unsigned int*)ldst, 16, 0, 0);
        }
    };

    stage(0, 0);
    __syncthreads();
    for (int t = 0; t < nk; ++t) {
        if (t + 1 < nk) stage((t + 1) & 1, (t + 1) * 64);
        const char* sA = &smem[t & 1][0];
        const char* sB = &smem[t & 1][ABYTES];
        int u = lane >> 4, r0 = lane & 15;
        bf16x8 af[2][FM], bfr[2][FN];
#pragma unroll
        for (int ks = 0; ks < 2; ++ks) {
#pragma unroll
            for (int i = 0; i < FM; ++i) {
                int row = wm + i * 16 + r0;
                int slot = (ks * 4 + u) ^ (row & 7);
                af[ks][i] = *(const bf16x8*)(sA + row * 128 + slot * 16);
            }
#pragma unroll
            for (int j = 0; j < FN; ++j) {
                int row = wn + j * 16 + r0;
                int slot = (ks * 4 + u) ^ (row & 7);
                bfr[ks][j] = *(const bf16x8*)(sB + row * 128 + slot * 16);
            }
        }
#pragma unroll
        for (int ks = 0; ks < 2; ++ks)
#pragma unroll
            for (int i = 0; i < FM; ++i)
#pragma unroll
                for (int j = 0; j < FN; ++j)
                    acc[i][j] = __builtin_amdgcn_mfma_f32_16x16x32_bf16(af[ks][i], bfr[ks][j], acc[i][j], 0, 0, 0);
        __syncthreads();
    }

    int gid = 0;
#pragma unroll 1
    while (bn >= ea.nb[gid + 1]) ++gid;
    EpiG E = ea.g[gid];
    int colBase = ea.nb[gid];
#pragma unroll
    for (int i = 0; i < FM; ++i) {
#pragma unroll
        for (int j = 0; j < FN; ++j) {
#pragma unroll
            for (int q = 0; q < 4; ++q) {
                int gm = bm + wm + i * 16 + (lane >> 4) * 4 + q;
                int lc = bn + wn + j * 16 + (lane & 15) - colBase;
                if (lc < E.ntrue)
                    epi_store(E, (size_t)gm * E.ld + lc, lc, acc[i][j][q]);
            }
        }
    }
}

// ---------------- grouped low-rank GEMM (BK=32; 2-way swizzle) ----------------

struct G2G { const __bf16* A; const __bf16* Bt; float* outF; const float* p1; const float* p2; int K; int epi; };
struct G2Args { G2G g[4]; };

template<int BM, int BN>
__global__ __launch_bounds__(256) void gemm_g2(G2Args ga) {
    G2G G = ga.g[blockIdx.z];
    const __bf16* A = G.A;
    const __bf16* Bt = G.Bt;
    int K = G.K;
    constexpr int FM = BM / 32, FN = BN / 32;
    constexpr int ABYTES = BM * 64;
    constexpr int TOT = (BM + BN) * 64;
    constexpr int NCHUNK = TOT / 4096;
    __shared__ __align__(16) char smem[2][TOT];
    int tid = threadIdx.x;
    int lane = tid & 63, wid = tid >> 6;
    int bm = blockIdx.y * BM, bn = blockIdx.x * BN;
    int wm = (wid >> 1) * (BM / 2), wn = (wid & 1) * (BN / 2);
    f32x4 acc[FM][FN];
#pragma unroll
    for (int i = 0; i < FM; ++i)
#pragma unroll
        for (int j = 0; j < FN; ++j) acc[i][j] = (f32x4){0.f, 0.f, 0.f, 0.f};

    int nk = K >> 5;
    auto stage = [&](int buf, int k0) {
        char* sb = &smem[buf][0];
#pragma unroll
        for (int c = 0; c < NCHUNK; ++c) {
            int d = c * 4096 + tid * 16;
            int isB = d >= ABYTES;
            int dd = isB ? d - ABYTES : d;
            int row = dd >> 6;
            int u = (dd >> 4) & 3;
            int su = u ^ ((row >> 1) & 3);
            const __bf16* src = isB ? (Bt + (size_t)(bn + row) * K + k0 + su * 8)
                                    : (A  + (size_t)(bm + row) * K + k0 + su * 8);
            char* ldst = sb + c * 4096 + (tid & 192) * 16;
            __builtin_amdgcn_global_load_lds(
                (const __attribute__((address_space(1))) unsigned int*)src,
                (__attribute__((address_space(3))) unsigned int*)ldst, 16, 0, 0);
        }
    };

    stage(0, 0);
    __syncthreads();
    for (int t = 0; t < nk; ++t) {
        if (t + 1 < nk) stage((t + 1) & 1, (t + 1) * 32);
        const char* sA = &smem[t & 1][0];
        const char* sB = &smem[t & 1][ABYTES];
        int u = lane >> 4, r0 = lane & 15;
        bf16x8 af[FM], bfr[FN];
#pragma unroll
        for (int i = 0; i < FM; ++i) {
            int row = wm + i * 16 + r0;
            int su = u ^ ((row >> 1) & 3);
            af[i] = *(const bf16x8*)(sA + row * 64 + su * 16);
        }
#pragma unroll
        for (int j = 0; j < FN; ++j) {
            int row = wn + j * 16 + r0;
            int su = u ^ ((row >> 1) & 3);
            bfr[j] = *(const bf16x8*)(sB + row * 64 + su * 16);
        }
#pragma unroll
        for (int i = 0; i < FM; ++i)
#pragma unroll
            for (int j = 0; j < FN; ++j)
                acc[i][j] = __builtin_amdgcn_mfma_f32_16x16x32_bf16(af[i], bfr[j], acc[i][j], 0, 0, 0);
        __syncthreads();
    }

    EpiG E;
    E.outF = G.outF; E.outH = nullptr; E.p1 = G.p1; E.p2 = G.p2;
    E.epi = G.epi; E.ld = 768; E.ntrue = 768;
#pragma unroll
    for (int i = 0; i < FM; ++i) {
#pragma unroll
        for (int j = 0; j < FN; ++j) {
#pragma unroll
            for (int q = 0; q < 4; ++q) {
                int gm = bm + wm + i * 16 + (lane >> 4) * 4 + q;
                int lc = bn + wn + j * 16 + (lane & 15);
                epi_store(E, (size_t)gm * 768 + lc, lc, acc[i][j][q]);
            }
        }
    }
}

// ---------------- chunked WKV7, phase A (register-tiled; M out as transposed bf16 pair) ----------------

__global__ __launch_bounds__(256) void chunkA_kernel(
    const float* __restrict__ r, const float* __restrict__ wd,
    const float* __restrict__ kraw, const float* __restrict__ av_,
    const float* __restrict__ v,
    const float* __restrict__ kkw, const float* __restrict__ kaw,
    float* __restrict__ kupd,
    float* __restrict__ yintra, float* __restrict__ zrO,
    __bf16* __restrict__ mtHi, __bf16* __restrict__ mtLo,
    float* __restrict__ zcO) {
    int c = blockIdx.x, bh = blockIdx.y;
    int b = bh / HH, h = bh % HH;
    __shared__ float Di[LCH][SPAD];
    __shared__ float Ah[LCH][SPAD];
    __shared__ float Bh[LCH][SPAD];
    __shared__ float Kh[LCH][SPAD];
    __shared__ float Rh[LCH][SPAD];
    __shared__ float Vt[LCH][SPAD];
    __shared__ float Qm[LCH][SPAD];
    __shared__ float Gba[LCH][LCH], Gka[LCH][LCH], Grb[LCH][LCH], Grk[LCH][LCH];
    int tid = threadIdx.x;
    int n = tid & 63, tq = tid >> 6;
    size_t base = ((size_t)(b * TT + c * LCH)) * CC + h * 64 + n;
    int cvec = h * 64 + n;
    float kkwv = kkw[cvec], kawv = kaw[cvec];
#pragma unroll
    for (int e = 0; e < 8; ++e) {
        int t = tq * 8 + e;
        size_t off = base + (size_t)t * CC;
        float kr = kraw[off];
        float aval = av_[off];
        float kk0 = kr * kkwv;
        float ss = kk0 * kk0;
        for (int m = 1; m < 64; m <<= 1) ss += __shfl_xor(ss, m);
        float rinv = 1.f / fmaxf(sqrtf(ss), 1e-12f);
        float kkv = kk0 * rinv;
        float ku = kr * (1.f + (aval - 1.f) * kawv);
        kupd[off] = ku;
        Di[t][n] = wd[off];
        Ah[t][n] = -kkv;
        Bh[t][n] = kkv * aval;
        Kh[t][n] = ku;
        Rh[t][n] = r[off];
        Vt[t][n] = v[off];
    }
    __syncthreads();
    if (tid < 64) {
        float d = 1.f;
        for (int t = 0; t < LCH; ++t) { d *= Di[t][tid]; Di[t][tid] = d; }
    }
    __syncthreads();
#pragma unroll
    for (int e = 0; e < 8; ++e) {
        int t = tq * 8 + e;
        float di = Di[t][n];
        float dp = (t == 0) ? 1.f : Di[t - 1][n];
        float inv = 1.f / di;
        Ah[t][n] *= dp;
        Bh[t][n] *= inv;
        Kh[t][n] *= inv;
        Rh[t][n] *= di;
    }
    __syncthreads();
    // ---- G phase: 2x2 (t,s) tiles ----
    {
        int tp = tid >> 4, sp = tid & 15;
        int t0 = 2 * tp, s0 = 2 * sp;
        float gba00 = 0.f, gba01 = 0.f, gba10 = 0.f, gba11 = 0.f;
        float gka00 = 0.f, gka01 = 0.f, gka10 = 0.f, gka11 = 0.f;
        float grb00 = 0.f, grb01 = 0.f, grb10 = 0.f, grb11 = 0.f;
        float grk00 = 0.f, grk01 = 0.f, grk10 = 0.f, grk11 = 0.f;
#pragma unroll 4
        for (int j = 0; j < 64; ++j) {
            float a0 = Ah[t0][j], a1 = Ah[t0 + 1][j];
            float r0 = Rh[t0][j], r1 = Rh[t0 + 1][j];
            float b0 = Bh[s0][j], b1 = Bh[s0 + 1][j];
            float k0 = Kh[s0][j], k1 = Kh[s0 + 1][j];
            gba00 = fmaf(a0, b0, gba00); gba01 = fmaf(a0, b1, gba01);
            gba10 = fmaf(a1, b0, gba10); gba11 = fmaf(a1, b1, gba11);
            gka00 = fmaf(a0, k0, gka00); gka01 = fmaf(a0, k1, gka01);
            gka10 = fmaf(a1, k0, gka10); gka11 = fmaf(a1, k1, gka11);
            grb00 = fmaf(r0, b0, grb00); grb01 = fmaf(r0, b1, grb01);
            grb10 = fmaf(r1, b0, grb10); grb11 = fmaf(r1, b1, grb11);
            grk00 = fmaf(r0, k0, grk00); grk01 = fmaf(r0, k1, grk01);
            grk10 = fmaf(r1, k0, grk10); grk11 = fmaf(r1, k1, grk11);
        }
#pragma unroll
        for (int dt = 0; dt < 2; ++dt) {
            int t = t0 + dt;
#pragma unroll
            for (int ds = 0; ds < 2; ++ds) {
                int s = s0 + ds;
                float vba = dt ? (ds ? gba11 : gba10) : (ds ? gba01 : gba00);
                float vka = dt ? (ds ? gka11 : gka10) : (ds ? gka01 : gka00);
                float vrb = dt ? (ds ? grb11 : grb10) : (ds ? grb01 : grb00);
                float vrk = dt ? (ds ? grk11 : grk10) : (ds ? grk01 : grk00);
                Gba[t][s] = (s < t)  ? vba : 0.f;
                Gka[t][s] = (s < t)  ? vka : 0.f;
                Grb[t][s] = (s <= t) ? vrb : 0.f;
                Grk[t][s] = (s <= t) ? vrk : 0.f;
            }
        }
    }
    __syncthreads();
    // ---- Qm = Gka V (s-outer) ----
    {
        float acc[8];
#pragma unroll
        for (int e = 0; e < 8; ++e) acc[e] = 0.f;
        for (int s = 0; s < LCH; ++s) {
            float vs = Vt[s][n];
#pragma unroll
            for (int e = 0; e < 8; ++e)
                acc[e] = fmaf(Gka[tq * 8 + e][s], vs, acc[e]);
        }
#pragma unroll
        for (int e = 0; e < 8; ++e) Qm[tq * 8 + e][n] = acc[e];
    }
    __syncthreads();
    // ---- forward substitution ----
    if (tq == 0) {
        for (int t = 1; t < LCH; ++t) {
            float acc = Ah[t][n];
            for (int s = 0; s < t; ++s) acc = fmaf(Gba[t][s], Ah[s][n], acc);
            Ah[t][n] = acc;
        }
    } else if (tq == 1) {
        for (int t = 1; t < LCH; ++t) {
            float acc = Qm[t][n];
            for (int s = 0; s < t; ++s) acc = fmaf(Gba[t][s], Qm[s][n], acc);
            Qm[t][n] = acc;
        }
    }
    __syncthreads();
    size_t obase = ((size_t)(bh * NC + c)) * LCH * 64;
    // ---- yintra / zr (s-outer) ----
    {
        float accY[8], accZ[8];
#pragma unroll
        for (int e = 0; e < 8; ++e) { accY[e] = 0.f; accZ[e] = Rh[tq * 8 + e][n]; }
        for (int s = 0; s < LCH; ++s) {
            float vs = Vt[s][n], qs = Qm[s][n], us = Ah[s][n];
#pragma unroll
            for (int e = 0; e < 8; ++e) {
                int t = tq * 8 + e;
                float grk_ = Grk[t][s], grb_ = Grb[t][s];
                accY[e] = fmaf(grk_, vs, fmaf(grb_, qs, accY[e]));
                accZ[e] = fmaf(grb_, us, accZ[e]);
            }
        }
#pragma unroll
        for (int e = 0; e < 8; ++e) {
            int t = tq * 8 + e;
            yintra[obase + t * 64 + n] = accY[e];
            zrO[obase + t * 64 + n] = accZ[e];
        }
    }
    // ---- M / Zc (4x4 tiles, s-outer); M stored transposed as bf16 hi/lo pair ----
    {
        int pi = tid >> 4, ni = tid & 15;
        float accM[4][4], accZc[4][4];
#pragma unroll
        for (int dp = 0; dp < 4; ++dp)
#pragma unroll
            for (int dn = 0; dn < 4; ++dn) { accM[dp][dn] = 0.f; accZc[dp][dn] = 0.f; }
        for (int s = 0; s < LCH; ++s) {
            float aa[4], vv[4], qq[4], bb[4], kk[4];
#pragma unroll
            for (int d = 0; d < 4; ++d) {
                aa[d] = Ah[s][4 * pi + d];
                vv[d] = Vt[s][4 * pi + d];
                qq[d] = Qm[s][4 * pi + d];
                bb[d] = Bh[s][4 * ni + d];
                kk[d] = Kh[s][4 * ni + d];
            }
#pragma unroll
            for (int dp = 0; dp < 4; ++dp)
#pragma unroll
                for (int dn = 0; dn < 4; ++dn) {
                    accM[dp][dn]  = fmaf(aa[dp], bb[dn], accM[dp][dn]);
                    accZc[dp][dn] = fmaf(vv[dp], kk[dn], fmaf(qq[dp], bb[dn], accZc[dp][dn]));
                }
        }
        size_t mbase = ((size_t)(bh * NC + c)) * 4096;
        float dl[4];
#pragma unroll
        for (int dn = 0; dn < 4; ++dn) dl[dn] = Di[LCH - 1][4 * ni + dn];
#pragma unroll
        for (int dp = 0; dp < 4; ++dp) {
            int p = 4 * pi + dp;
            f32x4 z4;
#pragma unroll
            for (int dn = 0; dn < 4; ++dn) z4[dn] = dl[dn] * accZc[dp][dn];
            *(f32x4*)(zcO + mbase + p * 64 + 4 * ni) = z4;
        }
#pragma unroll
        for (int dn = 0; dn < 4; ++dn) {
            int nn = 4 * ni + dn;
            float dlv = dl[dn];
            bf16x4 h4, l4;
#pragma unroll
            for (int dp = 0; dp < 4; ++dp) {
                int p = 4 * pi + dp;
                float mm = (accM[dp][dn] + ((p == nn) ? 1.f : 0.f)) * dlv;
                __bf16 hb = f2bb(mm);
                h4[dp] = hb;
                l4[dp] = f2bb(mm - bb2f(hb));
            }
            *(bf16x4*)(mtHi + mbase + (size_t)nn * 64 + 4 * pi) = h4;
            *(bf16x4*)(mtLo + mbase + (size_t)nn * 64 + 4 * pi) = l4;
        }
    }
}

// ---------------- phase B1: sequential state chain via split-precision MFMA ----------------
// FULLY UNROLLED chunk loop so the double-buffer index cb is compile-time (rule #20).

__global__ __launch_bounds__(256) void chunkB1_kernel(
    const float* __restrict__ zc,
    const __bf16* __restrict__ mtHi,
    const __bf16* __restrict__ mtLo,
    float* __restrict__ schk) {
    int bh = blockIdx.x;
    int tid = threadIdx.x;
    int lane = tid & 63, w = tid >> 6;
    int r0 = lane & 15, u = lane >> 4;
    __shared__ __align__(16) float S[64][68];
    for (int i = tid; i < 64 * 68; i += 256) (&S[0][0])[i] = 0.f;
    const float* zbase = zc + (size_t)bh * NC * 4096;
    const __bf16* hbase = mtHi + (size_t)bh * NC * 4096;
    const __bf16* lbase = mtLo + (size_t)bh * NC * 4096;
    float* sbase = schk + (size_t)bh * NC * 4096;
    int arow = w * 16 + r0;

    bf16x8 mh[2][4][2], ml[2][4][2];
    f32x4 zf[2][4];
#pragma unroll
    for (int ct = 0; ct < 4; ++ct) {
#pragma unroll
        for (int ks = 0; ks < 2; ++ks) {
            size_t mo = (size_t)(ct * 16 + r0) * 64 + ks * 32 + u * 8;
            mh[0][ct][ks] = *(const bf16x8*)(hbase + mo);
            ml[0][ct][ks] = *(const bf16x8*)(lbase + mo);
        }
#pragma unroll
        for (int q = 0; q < 4; ++q)
            zf[0][ct][q] = zbase[(size_t)(w * 16 + u * 4 + q) * 64 + ct * 16 + r0];
    }
    __syncthreads();
#pragma unroll
    for (int c = 0; c < NC - 1; ++c) {
        const int cb = c & 1;          // compile-time after full unroll
        if (c + 1 < NC - 1) {
            const __bf16* hn = hbase + (size_t)(c + 1) * 4096;
            const __bf16* ln = lbase + (size_t)(c + 1) * 4096;
            const float* zn = zbase + (size_t)(c + 1) * 4096;
#pragma unroll
            for (int ct = 0; ct < 4; ++ct) {
#pragma unroll
                for (int ks = 0; ks < 2; ++ks) {
                    size_t mo = (size_t)(ct * 16 + r0) * 64 + ks * 32 + u * 8;
                    mh[cb ^ 1][ct][ks] = *(const bf16x8*)(hn + mo);
                    ml[cb ^ 1][ct][ks] = *(const bf16x8*)(ln + mo);
                }
#pragma unroll
                for (int q = 0; q < 4; ++q)
                    zf[cb ^ 1][ct][q] = zn[(size_t)(w * 16 + u * 4 + q) * 64 + ct * 16 + r0];
            }
        }
        bf16x8 ah[2], al[2];
#pragma unroll
        for (int ks = 0; ks < 2; ++ks) {
            f32x4 s0 = *(const f32x4*)&S[arow][ks * 32 + u * 8];
            f32x4 s1 = *(const f32x4*)&S[arow][ks * 32 + u * 8 + 4];
#pragma unroll
            for (int e = 0; e < 4; ++e) {
                __bf16 h0 = f2bb(s0[e]);
                ah[ks][e] = h0;
                al[ks][e] = f2bb(s0[e] - bb2f(h0));
                __bf16 h1 = f2bb(s1[e]);
                ah[ks][4 + e] = h1;
                al[ks][4 + e] = f2bb(s1[e] - bb2f(h1));
            }
        }
        f32x4 acc[4];
#pragma unroll
        for (int ct = 0; ct < 4; ++ct) {
            acc[ct] = zf[cb][ct];
#pragma unroll
            for (int ks = 0; ks < 2; ++ks) {
                acc[ct] = __builtin_amdgcn_mfma_f32_16x16x32_bf16(ah[ks], mh[cb][ct][ks], acc[ct], 0, 0, 0);
                acc[ct] = __builtin_amdgcn_mfma_f32_16x16x32_bf16(ah[ks], ml[cb][ct][ks], acc[ct], 0, 0, 0);
                acc[ct] = __builtin_amdgcn_mfma_f32_16x16x32_bf16(al[ks], mh[cb][ct][ks], acc[ct], 0, 0, 0);
            }
        }
        __syncthreads();   // all S reads complete
        float* cp = sbase + (size_t)(c + 1) * 4096;
#pragma unroll
        for (int ct = 0; ct < 4; ++ct) {
#pragma unroll
            for (int q = 0; q < 4; ++q) {
                int row = w * 16 + u * 4 + q;
                int col = ct * 16 + r0;
                S[row][col] = acc[ct][q];
                cp[(size_t)row * 64 + col] = acc[ct][q];
            }
        }
        __syncthreads();   // S_new visible before next chunk
    }
}

// ---------------- phase Y (unchanged) ----------------

__global__ __launch_bounds__(256) void chunkY_kernel(
    const float* __restrict__ yintra, const float* __restrict__ zrI,
    const float* __restrict__ schk,
    const float* __restrict__ r, const float* __restrict__ kupd,
    const float* __restrict__ v, const float* __restrict__ g,
    const float* __restrict__ rk, const float* __restrict__ lw,
    const float* __restrict__ lb, bf16* __restrict__ out) {
    int c = blockIdx.x, bh = blockIdx.y;
    int b = bh / HH, h = bh % HH;
    __shared__ float Y[LCH][SPAD];
    __shared__ float Zr[LCH][SPAD];
    __shared__ float Sh[64][SPAD];
    int tid = threadIdx.x;
    int n = tid & 63, tq = tid >> 6;
    size_t obase = ((size_t)(bh * NC + c)) * LCH * 64;
#pragma unroll
    for (int e = 0; e < 8; ++e) {
        int idx = tid + e * 256;
        int row = idx >> 6, col = idx & 63;
        Y[row][col] = yintra[obase + idx];
        Zr[row][col] = zrI[obase + idx];
    }
    if (c > 0) {
        size_t sbase = ((size_t)(bh * NC + c)) * 4096;
#pragma unroll
        for (int e = 0; e < 16; ++e) {
            int idx = tid + e * 256;
            Sh[idx >> 6][idx & 63] = schk[sbase + idx];
        }
    }
    __syncthreads();
    if (c > 0) {
        float acc[8];
#pragma unroll
        for (int e = 0; e < 8; ++e) acc[e] = 0.f;
        for (int p = 0; p < 64; ++p) {
            float sv = Sh[n][p];
#pragma unroll
            for (int e = 0; e < 8; ++e)
                acc[e] = fmaf(Zr[tq * 8 + e][p], sv, acc[e]);
        }
#pragma unroll
        for (int e = 0; e < 8; ++e) Y[tq * 8 + e][n] += acc[e];
    }
    size_t rowbase = ((size_t)(b * TT + c * LCH)) * CC + h * 64 + n;
    float rkv = rk[h * 64 + n];
    float lwv = lw[h * 64 + n], lbv = lb[h * 64 + n];
#pragma unroll
    for (int e = 0; e < 8; ++e) {
        int t = tq * 8 + e;
        size_t off = rowbase + (size_t)t * CC;
        float yv = Y[t][n];
        float rv = r[off], kv = kupd[off], vv = v[off];
        float s1 = yv, s2 = yv * yv, s3 = rv * kv * rkv;
        for (int m = 1; m < 64; m <<= 1) {
            s1 += __shfl_xor(s1, m);
            s2 += __shfl_xor(s2, m);
            s3 += __shfl_xor(s3, m);
        }
        float mean = s1 * (1.f / 64.f);
        float var  = s2 * (1.f / 64.f) - mean * mean;
        float inv  = rsqrtf(var + 64e-5f);
        float val  = (yv - mean) * inv * lwv + lbv + s3 * vv;
        out[off] = f2b(val * g[off]);
    }
}

// ---------------- host ----------------

extern "C" void kernel_launch(void* const* d_in, const int* in_sizes, int n_in,
                              void* d_out, int out_size, void* d_ws, size_t ws_size,
                              hipStream_t stream) {
    (void)in_sizes; (void)n_in; (void)out_size;
    const float* x    = (const float*)d_in[0];
    const float* x_r  = (const float*)d_in[1];
    const float* x_w  = (const float*)d_in[2];
    const float* x_k  = (const float*)d_in[3];
    const float* x_v  = (const float*)d_in[4];
    const float* x_a  = (const float*)d_in[5];
    const float* x_g  = (const float*)d_in[6];
    const float* w0   = (const float*)d_in[7];
    const float* w1   = (const float*)d_in[8];
    const float* w2   = (const float*)d_in[9];
    const float* a0   = (const float*)d_in[10];
    const float* a1   = (const float*)d_in[11];
    const float* a2   = (const float*)d_in[12];
    const float* v0   = (const float*)d_in[13];
    const float* v1   = (const float*)d_in[14];
    const float* v2   = (const float*)d_in[15];
    const float* g1   = (const float*)d_in[16];
    const float* g2   = (const float*)d_in[17];
    const float* k_k  = (const float*)d_in[18];
    const float* k_a  = (const float*)d_in[19];
    const float* r_k  = (const float*)d_in[20];
    const float* W_r  = (const float*)d_in[21];
    const float* W_k  = (const float*)d_in[22];
    const float* W_v  = (const float*)d_in[23];
    const float* W_o  = (const float*)d_in[24];
    const float* ln_x_w = (const float*)d_in[25];
    const float* ln_x_b = (const float*)d_in[26];
    const float* ln1_w  = (const float*)d_in[27];
    const float* ln1_b  = (const float*)d_in[28];
    const float* ln2_w  = (const float*)d_in[29];
    const float* ln2_b  = (const float*)d_in[30];
    const float* c_x_k  = (const float*)d_in[31];
    const float* W_ck   = (const float*)d_in[32];
    const float* W_cv   = (const float*)d_in[33];

    const size_t MC = (size_t)MT * CC;
    char* wsb = (char*)d_ws;
    size_t woff = 0;
    auto alloc = [&](size_t bytes) -> void* {
        void* p = wsb + woff;
        woff += (bytes + 255) & ~(size_t)255;
        return p;
    };
    // 6-layer bf16 weight arenas (converted once per call, before the layer loop)
    const size_t S_Bcat = (size_t)2624 * 1536;
    const size_t S_Bck  = (size_t)3072 * 1536;
    const size_t S_w2t  = (size_t)768 * 64;
    const size_t S_a2t  = (size_t)768 * 64;
    const size_t S_v2t  = (size_t)768 * 32;
    const size_t S_g2t  = (size_t)768 * 128;
    const size_t S_Wo   = (size_t)768 * 768;
    const size_t S_Wcv  = (size_t)768 * 3072;
    bf16* BcatA = (bf16*)alloc(S_Bcat * LAYERS * 2);
    bf16* BckA  = (bf16*)alloc(S_Bck  * LAYERS * 2);
    bf16* w2tA  = (bf16*)alloc(S_w2t  * LAYERS * 2);
    bf16* a2tA  = (bf16*)alloc(S_a2t  * LAYERS * 2);
    bf16* v2tA  = (bf16*)alloc(S_v2t  * LAYERS * 2);
    bf16* g2tA  = (bf16*)alloc(S_g2t  * LAYERS * 2);
    bf16* WoA   = (bf16*)alloc(S_Wo   * LAYERS * 2);
    bf16* WcvA  = (bf16*)alloc(S_Wcv  * LAYERS * 2);
    bf16* A1    = (bf16*)alloc((size_t)MT * 1536 * 2);
    float* rbuf  = (float*)alloc(MC * 4);
    float* kraw  = (float*)alloc(MC * 4);
    float* kupd  = (float*)alloc(MC * 4);
    float* vbuf  = (float*)alloc(MC * 4);
    float* vfirst= (float*)alloc(MC * 4);
    float* abuf  = (float*)alloc(MC * 4);
    float* dbuf  = (float*)alloc(MC * 4);
    float* gbuf  = (float*)alloc(MC * 4);
    bf16* w1o   = (bf16*)alloc((size_t)MT * 64 * 2);
    bf16* a1o   = (bf16*)alloc((size_t)MT * 64 * 2);
    bf16* v1o   = (bf16*)alloc((size_t)MT * 32 * 2);
    bf16* g1o   = (bf16*)alloc((size_t)MT * 128 * 2);
    bf16* hbuf  = (bf16*)alloc((size_t)MT * FF * 2);
    bf16* ghout = (bf16*)alloc(MC * 2);
    float* yintraW = (float*)alloc((size_t)BH * NC * LCH * 64 * 4);
    float* zrW     = (float*)alloc((size_t)BH * NC * LCH * 64 * 4);
    __bf16* mtHiW  = (__bf16*)alloc((size_t)BH * NC * 4096 * 2);
    __bf16* mtLoW  = (__bf16*)alloc((size_t)BH * NC * 4096 * 2);
    float* zcW     = (float*)alloc((size_t)BH * NC * 4096 * 4);
    float* schkW   = (float*)alloc((size_t)BH * NC * 4096 * 4);
    if (woff > ws_size) return;

    float* xcur = (float*)d_out;
    copy_f<<<MC / 256, 256, 0, stream>>>(xcur, x);

    // ---- convert ALL layers' weights in one launch ----
    CArgs ca;
    ca.e[0]  = {W_r,  x_r,  BcatA,                    768, 768, 768, 1536, 0, 589824, (int)S_Bcat};
    ca.e[1]  = {W_k,  x_k,  BcatA + (size_t)768  * 1536, 768, 768, 768, 1536, 0, 589824, (int)S_Bcat};
    ca.e[2]  = {W_v,  x_v,  BcatA + (size_t)1536 * 1536, 768, 768, 768, 1536, 0, 589824, (int)S_Bcat};
    ca.e[3]  = {w1,   x_w,  BcatA + (size_t)2304 * 1536, 768, 64, 64, 1536, 0, 49152, (int)S_Bcat};
    ca.e[4]  = {a1,   x_a,  BcatA + (size_t)2368 * 1536, 768, 64, 64, 1536, 0, 49152, (int)S_Bcat};
    ca.e[5]  = {g1,   x_g,  BcatA + (size_t)2432 * 1536, 768, 128, 128, 1536, 0, 98304, (int)S_Bcat};
    ca.e[6]  = {v1,   x_v,  BcatA + (size_t)2560 * 1536, 768, 32, 64, 1536, 0, 24576, (int)S_Bcat};
    ca.e[7]  = {W_ck, c_x_k, BckA, 768, 3072, 3072, 1536, 0, 2359296, (int)S_Bck};
    ca.e[8]  = {w2,   nullptr, w2tA,   64, 768, 768, 64, 0, 49152, (int)S_w2t};
    ca.e[9]  = {a2,   nullptr, a2tA,   64, 768, 768, 64, 0, 49152, (int)S_a2t};
    ca.e[10] = {v2,   nullptr, v2tA,   32, 768, 768, 32, 0, 24576, (int)S_v2t};
    ca.e[11] = {g2,   nullptr, g2tA,  128, 768, 768, 128, 0, 98304, (int)S_g2t};
    ca.e[12] = {W_o,  nullptr, WoA,  768, 768, 768, 768, 0, 589824, (int)S_Wo};
    ca.e[13] = {W_cv, nullptr, WcvA, 3072, 768, 768, 3072, 0, 2359296, (int)S_Wcv};
    int btot = 0;
    for (int i = 0; i < 14; ++i) {
        ca.e[i].bstart = btot;
        btot += (ca.e[i].Npad >> 5) * (ca.e[i].Kdst >> 5);
    }
    convert_weights<<<dim3(btot, LAYERS), 256, 0, stream>>>(ca);

    for (int l = 0; l < LAYERS; ++l) {
        size_t oC = (size_t)l * CC;
        float* vptr = (l == 0) ? vfirst : vbuf;
        const __bf16* Bcat  = (const __bf16*)(BcatA + (size_t)l * S_Bcat);
        const __bf16* Bck   = (const __bf16*)(BckA  + (size_t)l * S_Bck);
        const __bf16* w2t   = (const __bf16*)(w2tA  + (size_t)l * S_w2t);
        const __bf16* a2t   = (const __bf16*)(a2tA  + (size_t)l * S_a2t);
        const __bf16* v2t   = (const __bf16*)(v2tA  + (size_t)l * S_v2t);
        const __bf16* g2t   = (const __bf16*)(g2tA  + (size_t)l * S_g2t);
        const __bf16* Wo_t  = (const __bf16*)(WoA   + (size_t)l * S_Wo);
        const __bf16* Wcv_t = (const __bf16*)(WcvA  + (size_t)l * S_Wcv);

        // ---- time mix ----
        ln_shift_kernel<<<MT, 256, 0, stream>>>(xcur, ln1_w + oC, ln1_b + oC, A1);

        EpiArgs e1;
        e1.g[0] = {rbuf,  nullptr, nullptr, nullptr, 0, 768, 768};
        e1.g[1] = {kraw,  nullptr, nullptr, nullptr, 0, 768, 768};
        e1.g[2] = {vptr,  nullptr, nullptr, nullptr, 0, 768, 768};
        e1.g[3] = {nullptr, w1o, nullptr, nullptr, 2, 64, 64};
        e1.g[4] = {nullptr, a1o, nullptr, nullptr, 1, 64, 64};
        e1.g[5] = {nullptr, g1o, nullptr, nullptr, 3, 128, 128};
        e1.g[6] = {nullptr, v1o, nullptr, nullptr, 1, 32, 32};
        int nb1[8] = {0, 768, 1536, 2304, 2368, 2432, 2560, 2624};
        for (int i = 0; i < 8; ++i) e1.nb[i] = nb1[i];
        gemm_multi<64, 64><<<dim3(41, 16), 256, 0, stream>>>((const __bf16*)A1, Bcat, 1536, e1);

        G2Args g2a;
        g2a.g[0] = {(const __bf16*)w1o, w2t, dbuf, w0 + oC, nullptr, 64, 6};
        g2a.g[1] = {(const __bf16*)a1o, a2t, abuf, a0 + oC, nullptr, 64, 7};
        g2a.g[2] = {(const __bf16*)g1o, g2t, gbuf, nullptr, nullptr, 128, 0};
        g2a.g[3] = {(const __bf16*)v1o, v2t, vbuf, v0 + oC, vfirst, 32, 8};
        gemm_g2<128, 64><<<dim3(12, 8, (l == 0) ? 3 : 4), 256, 0, stream>>>(g2a);

        // ---- chunked scan ----
        chunkA_kernel<<<dim3(NC, BH), 256, 0, stream>>>(rbuf, dbuf, kraw, abuf, vptr,
                                                        k_k + oC, k_a + oC, kupd,
                                                        yintraW, zrW, mtHiW, mtLoW, zcW);
        chunkB1_kernel<<<BH, 256, 0, stream>>>(zcW, mtHiW, mtLoW, schkW);
        chunkY_kernel<<<dim3(NC, BH), 256, 0, stream>>>(yintraW, zrW, schkW,
                                                        rbuf, kupd, vptr, gbuf,
                                                        r_k + (size_t)l * 768,
                                                        ln_x_w + oC, ln_x_b + oC, ghout);

        EpiArgs eo;
        eo.g[0] = {xcur, nullptr, nullptr, nullptr, 5, 768, 768};
        eo.nb[0] = 0; for (int i = 1; i < 8; ++i) eo.nb[i] = 1 << 30;
        eo.nb[1] = 768;
        gemm_multi<64, 64><<<dim3(12, 16), 256, 0, stream>>>((const __bf16*)ghout, Wo_t, 768, eo);

        // ---- channel mix ----
        ln_shift_kernel<<<MT, 256, 0, stream>>>(xcur, ln2_w + oC, ln2_b + oC, A1);

        EpiArgs ec;
        ec.g[0] = {nullptr, hbuf, nullptr, nullptr, 4, 3072, 3072};
        ec.nb[0] = 0; for (int i = 1; i < 8; ++i) ec.nb[i] = 1 << 30;
        ec.nb[1] = 3072;
        gemm_multi<64, 64><<<dim3(48, 16), 256, 0, stream>>>((const __bf16*)A1, Bck, 1536, ec);

        EpiArgs ev;
        ev.g[0] = {xcur, nullptr, nullptr, nullptr, 5, 768, 768};
        ev.nb[0] = 0; for (int i = 1; i < 8; ++i) ev.nb[i] = 1 << 30;
        ev.nb[1] = 768;
        gemm_multi<64, 64><<<dim3(12, 16), 256, 0, stream>>>((const __bf16*)hbuf, Wcv_t, 3072, ev);
    }
}

// Round 12
// 1351.503 us; speedup vs baseline: 1.2903x; 1.0031x over previous
//
#include <hip/hip_runtime.h>
#include <hip/hip_bf16.h>
#include <math.h>

#define LAYERS 6
#define BBATCH 2
#define TT 512
#define CC 768
#define HH 12
#define MT (BBATCH*TT)      // 1024 tokens
#define FF (4*CC)           // 3072
#define LCH 32
#define NC (TT/LCH)         // 16 chunks
#define BH (BBATCH*HH)      // 24
#define SPAD 65

typedef __hip_bfloat16 bf16;
typedef __bf16 bf16x8 __attribute__((ext_vector_type(8)));
typedef __bf16 bf16x4 __attribute__((ext_vector_type(4)));
typedef float f32x4 __attribute__((ext_vector_type(4)));

__device__ inline bf16 f2b(float f) { return __float2bfloat16(f); }
__device__ inline __bf16 f2bb(float f) {
    __hip_bfloat16 h = __float2bfloat16(f);
    return __builtin_bit_cast(__bf16, h);
}
__device__ inline float bb2f(__bf16 h) {
    return __bfloat162float(__builtin_bit_cast(__hip_bfloat16, h));
}

// ---------------- utility ----------------

__global__ __launch_bounds__(256) void copy_f(float* __restrict__ dst, const float* __restrict__ src) {
    size_t i = (size_t)blockIdx.x * 256 + threadIdx.x;
    dst[i] = src[i];
}

// ---------------- fused layernorm + token-shift-diff, bf16 concat output ----------------

__global__ __launch_bounds__(256) void ln_shift_kernel(const float* __restrict__ x,
                                                       const float* __restrict__ w,
                                                       const float* __restrict__ b,
                                                       bf16* __restrict__ out) {
    int row = blockIdx.x;
    int t = row % TT;
    const float* xr = x + (size_t)row * CC;
    const float* xp = xr - CC;
    int tid = threadIdx.x;
    float c0 = xr[tid], c1 = xr[tid + 256], c2 = xr[tid + 512];
    float p0 = 0.f, p1 = 0.f, p2 = 0.f;
    if (t > 0) { p0 = xp[tid]; p1 = xp[tid + 256]; p2 = xp[tid + 512]; }
    float s  = c0 + c1 + c2, q  = c0 * c0 + c1 * c1 + c2 * c2;
    float sp = p0 + p1 + p2, qp = p0 * p0 + p1 * p1 + p2 * p2;
    for (int m = 1; m < 64; m <<= 1) {
        s += __shfl_xor(s, m); q += __shfl_xor(q, m);
        sp += __shfl_xor(sp, m); qp += __shfl_xor(qp, m);
    }
    __shared__ float rs[4], rq[4], rsp[4], rqp[4];
    int wid = tid >> 6;
    if ((tid & 63) == 0) { rs[wid] = s; rq[wid] = q; rsp[wid] = sp; rqp[wid] = qp; }
    __syncthreads();
    s  = rs[0] + rs[1] + rs[2] + rs[3];   q  = rq[0] + rq[1] + rq[2] + rq[3];
    sp = rsp[0] + rsp[1] + rsp[2] + rsp[3]; qp = rqp[0] + rqp[1] + rqp[2] + rqp[3];
    float meanC = s * (1.f / CC);
    float invC  = rsqrtf(q * (1.f / CC) - meanC * meanC + 1e-5f);
    float meanP = sp * (1.f / CC);
    float invP  = rsqrtf(qp * (1.f / CC) - meanP * meanP + 1e-5f);
    bf16* orow = out + (size_t)row * 1536;
    float cv[3] = {c0, c1, c2};
    float pv[3] = {p0, p1, p2};
#pragma unroll
    for (int j = 0; j < 3; ++j) {
        int cc = tid + j * 256;
        float lnc = (cv[j] - meanC) * invC * w[cc] + b[cc];
        float lnp = (t > 0) ? (pv[j] - meanP) * invP * w[cc] + b[cc] : 0.f;
        orow[cc] = f2b(lnc);
        orow[768 + cc] = f2b(lnp - lnc);
    }
}

// ---------------- weight convert: ALL LAYERS, vectorized 64k x 32n tiles ----------------
// load f32 coalesced (128B rows); write one bf16x8 (16B) per thread, 128B per n-row.
// Plain entries with Kdst > Ksrc get zero rows (used to pad v2t to K=64).

struct CEntry { const float* W; const float* mix; bf16* dst;
                int Ksrc, Nsrc, Npad, Kdst, bstart, wstr, dstr; };
struct CArgs { CEntry e[14]; };

__global__ __launch_bounds__(256) void convert_weights(CArgs ca) {
    int bid = blockIdx.x;
    int l = blockIdx.y;
    int idx = 0;
#pragma unroll
    for (int i = 1; i < 14; ++i) if (bid >= ca.e[i].bstart) idx = i;
    CEntry E = ca.e[idx];
    const float* Wsrc = E.W + (size_t)l * E.wstr;
    bf16* d = E.dst + (size_t)l * E.dstr;
    int t = bid - E.bstart;
    int ntN = E.Npad >> 5;
    int tn = (t % ntN) * 32;
    int tk = (t / ntN) * 64;
    __shared__ float tile[64][33];
    int tid = threadIdx.x;
    const float* mixl = E.mix ? (E.mix + (size_t)l * CC) : nullptr;
#pragma unroll
    for (int i = 0; i < 8; ++i) {
        int id2 = tid + i * 256;
        int k = id2 >> 5, n = id2 & 31;
        int kk = tk + k;
        float v = 0.f;
        if (mixl) {
            int ks = (kk < E.Ksrc) ? kk : kk - E.Ksrc;
            if (tn + n < E.Nsrc) v = Wsrc[(size_t)ks * E.Nsrc + tn + n];
            if (kk >= E.Ksrc) v *= mixl[ks];
        } else {
            if (kk < E.Ksrc && tn + n < E.Nsrc) v = Wsrc[(size_t)kk * E.Nsrc + tn + n];
        }
        tile[k][n] = v;
    }
    __syncthreads();
    int n2 = tid >> 3, slot = tid & 7;
    bf16x8 h8;
#pragma unroll
    for (int e = 0; e < 8; ++e) h8[e] = f2bb(tile[slot * 8 + e][n2]);
    *(bf16x8*)((__bf16*)d + (size_t)(tn + n2) * E.Kdst + tk + slot * 8) = h8;
}

// ---------------- epilogues ----------------

struct EpiG {
    float* outF; bf16* outH;
    const float* p1; const float* p2;
    int epi, ld, ntrue;
};
struct EpiArgs { EpiG g[7]; int nb[8]; };

__device__ inline void epi_store(const EpiG& E, size_t idx, int lc, float v) {
    switch (E.epi) {
        case 0: E.outF[idx] = v; break;
        case 1: E.outH[idx] = f2b(v); break;
        case 2: E.outH[idx] = f2b(tanhf(v)); break;
        case 3: E.outH[idx] = f2b(1.f / (1.f + expf(-v))); break;
        case 4: { float t = fmaxf(v, 0.f); E.outH[idx] = f2b(t * t); } break;
        case 5: E.outF[idx] += v; break;
        case 6: { float z = E.p1[lc] + v; float nz = -z;
                  float sp = (nz > 20.f) ? nz : log1pf(expf(nz));
                  E.outF[idx] = expf(-expf(-sp - 0.5f)); } break;
        case 7: E.outF[idx] = 1.f / (1.f + expf(-(E.p1[lc] + v))); break;
        case 8: { float vv = E.outF[idx];
                  float s = 1.f / (1.f + expf(-(E.p1[lc] + v)));
                  E.outF[idx] = vv + (E.p2[idx] - vv) * s; } break;
    }
}

// ---------------- bf16 MFMA GEMM, BK=64, XCD-swizzled, grouped-column epilogue ----------------

template<int BM, int BN>
__global__ __launch_bounds__(256) void gemm_multi(const __bf16* __restrict__ A,
                                                  const __bf16* __restrict__ Bt,
                                                  int K, EpiArgs ea) {
    constexpr int FM = BM / 32, FN = BN / 32;
    constexpr int ABYTES = BM * 128;
    constexpr int TOT = (BM + BN) * 128;
    constexpr int NCHUNK = TOT / 4096;
    __shared__ __align__(16) char smem[2][TOT];
    int tid = threadIdx.x;
    int lane = tid & 63, wid = tid >> 6;
    int nwg = gridDim.x * gridDim.y;
    int orig = blockIdx.y * gridDim.x + blockIdx.x;
    int qq = nwg >> 3, rr = nwg & 7, xc = orig & 7, oo = orig >> 3;
    int swz = (xc < rr ? xc * (qq + 1) : rr * (qq + 1) + (xc - rr) * qq) + oo;
    int bn = (swz % gridDim.x) * BN, bm = (swz / gridDim.x) * BM;
    int wm = (wid >> 1) * (BM / 2), wn = (wid & 1) * (BN / 2);
    f32x4 acc[FM][FN];
#pragma unroll
    for (int i = 0; i < FM; ++i)
#pragma unroll
        for (int j = 0; j < FN; ++j) acc[i][j] = (f32x4){0.f, 0.f, 0.f, 0.f};

    int nk = K >> 6;
    auto stage = [&](int buf, int k0) {
        char* sb = &smem[buf][0];
#pragma unroll
        for (int c = 0; c < NCHUNK; ++c) {
            int d = c * 4096 + tid * 16;
            int isB = d >= ABYTES;
            int dd = isB ? d - ABYTES : d;
            int row = dd >> 7;
            int slot = (dd >> 4) & 7;
            int su = slot ^ (row & 7);
            const __bf16* src = isB ? (Bt + (size_t)(bn + row) * K + k0 + su * 8)
                                    : (A  + (size_t)(bm + row) * K + k0 + su * 8);
            char* ldst = sb + c * 4096 + (tid & 192) * 16;
            __builtin_amdgcn_global_load_lds(
                (const __attribute__((address_space(1))) unsigned int*)src,
                (__attribute__((address_space(3))) unsigned int*)ldst, 16, 0, 0);
        }
    };

    stage(0, 0);
    __syncthreads();
    for (int t = 0; t < nk; ++t) {
        if (t + 1 < nk) stage((t + 1) & 1, (t + 1) * 64);
        const char* sA = &smem[t & 1][0];
        const char* sB = &smem[t & 1][ABYTES];
        int u = lane >> 4, r0 = lane & 15;
        bf16x8 af[2][FM], bfr[2][FN];
#pragma unroll
        for (int ks = 0; ks < 2; ++ks) {
#pragma unroll
            for (int i = 0; i < FM; ++i) {
                int row = wm + i * 16 + r0;
                int slot = (ks * 4 + u) ^ (row & 7);
                af[ks][i] = *(const bf16x8*)(sA + row * 128 + slot * 16);
            }
#pragma unroll
            for (int j = 0; j < FN; ++j) {
                int row = wn + j * 16 + r0;
                int slot = (ks * 4 + u) ^ (row & 7);
                bfr[ks][j] = *(const bf16x8*)(sB + row * 128 + slot * 16);
            }
        }
#pragma unroll
        for (int ks = 0; ks < 2; ++ks)
#pragma unroll
            for (int i = 0; i < FM; ++i)
#pragma unroll
                for (int j = 0; j < FN; ++j)
                    acc[i][j] = __builtin_amdgcn_mfma_f32_16x16x32_bf16(af[ks][i], bfr[ks][j], acc[i][j], 0, 0, 0);
        __syncthreads();
    }

    int gid = 0;
#pragma unroll 1
    while (bn >= ea.nb[gid + 1]) ++gid;
    EpiG E = ea.g[gid];
    int colBase = ea.nb[gid];
#pragma unroll
    for (int i = 0; i < FM; ++i) {
#pragma unroll
        for (int j = 0; j < FN; ++j) {
#pragma unroll
            for (int q = 0; q < 4; ++q) {
                int gm = bm + wm + i * 16 + (lane >> 4) * 4 + q;
                int lc = bn + wn + j * 16 + (lane & 15) - colBase;
                if (lc < E.ntrue)
                    epi_store(E, (size_t)gm * E.ld + lc, lc, acc[i][j][q]);
            }
        }
    }
}

// ---------------- grouped low-rank GEMM (BK=32; 2-way swizzle) ----------------

struct G2G { const __bf16* A; const __bf16* Bt; float* outF; const float* p1; const float* p2; int K; int epi; };
struct G2Args { G2G g[4]; };

template<int BM, int BN>
__global__ __launch_bounds__(256) void gemm_g2(G2Args ga) {
    G2G G = ga.g[blockIdx.z];
    const __bf16* A = G.A;
    const __bf16* Bt = G.Bt;
    int K = G.K;
    constexpr int FM = BM / 32, FN = BN / 32;
    constexpr int ABYTES = BM * 64;
    constexpr int TOT = (BM + BN) * 64;
    constexpr int NCHUNK = TOT / 4096;
    __shared__ __align__(16) char smem[2][TOT];
    int tid = threadIdx.x;
    int lane = tid & 63, wid = tid >> 6;
    int bm = blockIdx.y * BM, bn = blockIdx.x * BN;
    int wm = (wid >> 1) * (BM / 2), wn = (wid & 1) * (BN / 2);
    f32x4 acc[FM][FN];
#pragma unroll
    for (int i = 0; i < FM; ++i)
#pragma unroll
        for (int j = 0; j < FN; ++j) acc[i][j] = (f32x4){0.f, 0.f, 0.f, 0.f};

    int nk = K >> 5;
    auto stage = [&](int buf, int k0) {
        char* sb = &smem[buf][0];
#pragma unroll
        for (int c = 0; c < NCHUNK; ++c) {
            int d = c * 4096 + tid * 16;
            int isB = d >= ABYTES;
            int dd = isB ? d - ABYTES : d;
            int row = dd >> 6;
            int u = (dd >> 4) & 3;
            int su = u ^ ((row >> 1) & 3);
            const __bf16* src = isB ? (Bt + (size_t)(bn + row) * K + k0 + su * 8)
                                    : (A  + (size_t)(bm + row) * K + k0 + su * 8);
            char* ldst = sb + c * 4096 + (tid & 192) * 16;
            __builtin_amdgcn_global_load_lds(
                (const __attribute__((address_space(1))) unsigned int*)src,
                (__attribute__((address_space(3))) unsigned int*)ldst, 16, 0, 0);
        }
    };

    stage(0, 0);
    __syncthreads();
    for (int t = 0; t < nk; ++t) {
        if (t + 1 < nk) stage((t + 1) & 1, (t + 1) * 32);
        const char* sA = &smem[t & 1][0];
        const char* sB = &smem[t & 1][ABYTES];
        int u = lane >> 4, r0 = lane & 15;
        bf16x8 af[FM], bfr[FN];
#pragma unroll
        for (int i = 0; i < FM; ++i) {
            int row = wm + i * 16 + r0;
            int su = u ^ ((row >> 1) & 3);
            af[i] = *(const bf16x8*)(sA + row * 64 + su * 16);
        }
#pragma unroll
        for (int j = 0; j < FN; ++j) {
            int row = wn + j * 16 + r0;
            int su = u ^ ((row >> 1) & 3);
            bfr[j] = *(const bf16x8*)(sB + row * 64 + su * 16);
        }
#pragma unroll
        for (int i = 0; i < FM; ++i)
#pragma unroll
            for (int j = 0; j < FN; ++j)
                acc[i][j] = __builtin_amdgcn_mfma_f32_16x16x32_bf16(af[i], bfr[j], acc[i][j], 0, 0, 0);
        __syncthreads();
    }

    EpiG E;
    E.outF = G.outF; E.outH = nullptr; E.p1 = G.p1; E.p2 = G.p2;
    E.epi = G.epi; E.ld = 768; E.ntrue = 768;
#pragma unroll
    for (int i = 0; i < FM; ++i) {
#pragma unroll
        for (int j = 0; j < FN; ++j) {
#pragma unroll
            for (int q = 0; q < 4; ++q) {
                int gm = bm + wm + i * 16 + (lane >> 4) * 4 + q;
                int lc = bn + wn + j * 16 + (lane & 15);
                epi_store(E, (size_t)gm * 768 + lc, lc, acc[i][j][q]);
            }
        }
    }
}

// ---------------- chunked WKV7, phase A (register-tiled; M out as transposed bf16 pair) ----------------

__global__ __launch_bounds__(256) void chunkA_kernel(
    const float* __restrict__ r, const float* __restrict__ wd,
    const float* __restrict__ kraw, const float* __restrict__ av_,
    const float* __restrict__ v,
    const float* __restrict__ kkw, const float* __restrict__ kaw,
    float* __restrict__ kupd,
    float* __restrict__ yintra, float* __restrict__ zrO,
    __bf16* __restrict__ mtHi, __bf16* __restrict__ mtLo,
    float* __restrict__ zcO) {
    int c = blockIdx.x, bh = blockIdx.y;
    int b = bh / HH, h = bh % HH;
    __shared__ float Di[LCH][SPAD];
    __shared__ float Ah[LCH][SPAD];
    __shared__ float Bh[LCH][SPAD];
    __shared__ float Kh[LCH][SPAD];
    __shared__ float Rh[LCH][SPAD];
    __shared__ float Vt[LCH][SPAD];
    __shared__ float Qm[LCH][SPAD];
    __shared__ float Gba[LCH][LCH], Gka[LCH][LCH], Grb[LCH][LCH], Grk[LCH][LCH];
    int tid = threadIdx.x;
    int n = tid & 63, tq = tid >> 6;
    size_t base = ((size_t)(b * TT + c * LCH)) * CC + h * 64 + n;
    int cvec = h * 64 + n;
    float kkwv = kkw[cvec], kawv = kaw[cvec];
#pragma unroll
    for (int e = 0; e < 8; ++e) {
        int t = tq * 8 + e;
        size_t off = base + (size_t)t * CC;
        float kr = kraw[off];
        float aval = av_[off];
        float kk0 = kr * kkwv;
        float ss = kk0 * kk0;
        for (int m = 1; m < 64; m <<= 1) ss += __shfl_xor(ss, m);
        float rinv = 1.f / fmaxf(sqrtf(ss), 1e-12f);
        float kkv = kk0 * rinv;
        float ku = kr * (1.f + (aval - 1.f) * kawv);
        kupd[off] = ku;
        Di[t][n] = wd[off];
        Ah[t][n] = -kkv;
        Bh[t][n] = kkv * aval;
        Kh[t][n] = ku;
        Rh[t][n] = r[off];
        Vt[t][n] = v[off];
    }
    __syncthreads();
    if (tid < 64) {
        float d = 1.f;
        for (int t = 0; t < LCH; ++t) { d *= Di[t][tid]; Di[t][tid] = d; }
    }
    __syncthreads();
#pragma unroll
    for (int e = 0; e < 8; ++e) {
        int t = tq * 8 + e;
        float di = Di[t][n];
        float dp = (t == 0) ? 1.f : Di[t - 1][n];
        float inv = 1.f / di;
        Ah[t][n] *= dp;
        Bh[t][n] *= inv;
        Kh[t][n] *= inv;
        Rh[t][n] *= di;
    }
    __syncthreads();
    // ---- G phase: 2x2 (t,s) tiles ----
    {
        int tp = tid >> 4, sp = tid & 15;
        int t0 = 2 * tp, s0 = 2 * sp;
        float gba00 = 0.f, gba01 = 0.f, gba10 = 0.f, gba11 = 0.f;
        float gka00 = 0.f, gka01 = 0.f, gka10 = 0.f, gka11 = 0.f;
        float grb00 = 0.f, grb01 = 0.f, grb10 = 0.f, grb11 = 0.f;
        float grk00 = 0.f, grk01 = 0.f, grk10 = 0.f, grk11 = 0.f;
#pragma unroll 4
        for (int j = 0; j < 64; ++j) {
            float a0 = Ah[t0][j], a1 = Ah[t0 + 1][j];
            float r0 = Rh[t0][j], r1 = Rh[t0 + 1][j];
            float b0 = Bh[s0][j], b1 = Bh[s0 + 1][j];
            float k0 = Kh[s0][j], k1 = Kh[s0 + 1][j];
            gba00 = fmaf(a0, b0, gba00); gba01 = fmaf(a0, b1, gba01);
            gba10 = fmaf(a1, b0, gba10); gba11 = fmaf(a1, b1, gba11);
            gka00 = fmaf(a0, k0, gka00); gka01 = fmaf(a0, k1, gka01);
            gka10 = fmaf(a1, k0, gka10); gka11 = fmaf(a1, k1, gka11);
            grb00 = fmaf(r0, b0, grb00); grb01 = fmaf(r0, b1, grb01);
            grb10 = fmaf(r1, b0, grb10); grb11 = fmaf(r1, b1, grb11);
            grk00 = fmaf(r0, k0, grk00); grk01 = fmaf(r0, k1, grk01);
            grk10 = fmaf(r1, k0, grk10); grk11 = fmaf(r1, k1, grk11);
        }
#pragma unroll
        for (int dt = 0; dt < 2; ++dt) {
            int t = t0 + dt;
#pragma unroll
            for (int ds = 0; ds < 2; ++ds) {
                int s = s0 + ds;
                float vba = dt ? (ds ? gba11 : gba10) : (ds ? gba01 : gba00);
                float vka = dt ? (ds ? gka11 : gka10) : (ds ? gka01 : gka00);
                float vrb = dt ? (ds ? grb11 : grb10) : (ds ? grb01 : grb00);
                float vrk = dt ? (ds ? grk11 : grk10) : (ds ? grk01 : grk00);
                Gba[t][s] = (s < t)  ? vba : 0.f;
                Gka[t][s] = (s < t)  ? vka : 0.f;
                Grb[t][s] = (s <= t) ? vrb : 0.f;
                Grk[t][s] = (s <= t) ? vrk : 0.f;
            }
        }
    }
    __syncthreads();
    // ---- Qm = Gka V (s-outer) ----
    {
        float acc[8];
#pragma unroll
        for (int e = 0; e < 8; ++e) acc[e] = 0.f;
        for (int s = 0; s < LCH; ++s) {
            float vs = Vt[s][n];
#pragma unroll
            for (int e = 0; e < 8; ++e)
                acc[e] = fmaf(Gka[tq * 8 + e][s], vs, acc[e]);
        }
#pragma unroll
        for (int e = 0; e < 8; ++e) Qm[tq * 8 + e][n] = acc[e];
    }
    __syncthreads();
    // ---- forward substitution ----
    if (tq == 0) {
        for (int t = 1; t < LCH; ++t) {
            float acc = Ah[t][n];
            for (int s = 0; s < t; ++s) acc = fmaf(Gba[t][s], Ah[s][n], acc);
            Ah[t][n] = acc;
        }
    } else if (tq == 1) {
        for (int t = 1; t < LCH; ++t) {
            float acc = Qm[t][n];
            for (int s = 0; s < t; ++s) acc = fmaf(Gba[t][s], Qm[s][n], acc);
            Qm[t][n] = acc;
        }
    }
    __syncthreads();
    size_t obase = ((size_t)(bh * NC + c)) * LCH * 64;
    // ---- yintra / zr (s-outer) ----
    {
        float accY[8], accZ[8];
#pragma unroll
        for (int e = 0; e < 8; ++e) { accY[e] = 0.f; accZ[e] = Rh[tq * 8 + e][n]; }
        for (int s = 0; s < LCH; ++s) {
            float vs = Vt[s][n], qs = Qm[s][n], us = Ah[s][n];
#pragma unroll
            for (int e = 0; e < 8; ++e) {
                int t = tq * 8 + e;
                float grk_ = Grk[t][s], grb_ = Grb[t][s];
                accY[e] = fmaf(grk_, vs, fmaf(grb_, qs, accY[e]));
                accZ[e] = fmaf(grb_, us, accZ[e]);
            }
        }
#pragma unroll
        for (int e = 0; e < 8; ++e) {
            int t = tq * 8 + e;
            yintra[obase + t * 64 + n] = accY[e];
            zrO[obase + t * 64 + n] = accZ[e];
        }
    }
    // ---- M / Zc (4x4 tiles, s-outer); M stored transposed as bf16 hi/lo pair ----
    {
        int pi = tid >> 4, ni = tid & 15;
        float accM[4][4], accZc[4][4];
#pragma unroll
        for (int dp = 0; dp < 4; ++dp)
#pragma unroll
            for (int dn = 0; dn < 4; ++dn) { accM[dp][dn] = 0.f; accZc[dp][dn] = 0.f; }
        for (int s = 0; s < LCH; ++s) {
            float aa[4], vv[4], qq[4], bb[4], kk[4];
#pragma unroll
            for (int d = 0; d < 4; ++d) {
                aa[d] = Ah[s][4 * pi + d];
                vv[d] = Vt[s][4 * pi + d];
                qq[d] = Qm[s][4 * pi + d];
                bb[d] = Bh[s][4 * ni + d];
                kk[d] = Kh[s][4 * ni + d];
            }
#pragma unroll
            for (int dp = 0; dp < 4; ++dp)
#pragma unroll
                for (int dn = 0; dn < 4; ++dn) {
                    accM[dp][dn]  = fmaf(aa[dp], bb[dn], accM[dp][dn]);
                    accZc[dp][dn] = fmaf(vv[dp], kk[dn], fmaf(qq[dp], bb[dn], accZc[dp][dn]));
                }
        }
        size_t mbase = ((size_t)(bh * NC + c)) * 4096;
        float dl[4];
#pragma unroll
        for (int dn = 0; dn < 4; ++dn) dl[dn] = Di[LCH - 1][4 * ni + dn];
#pragma unroll
        for (int dp = 0; dp < 4; ++dp) {
            int p = 4 * pi + dp;
            f32x4 z4;
#pragma unroll
            for (int dn = 0; dn < 4; ++dn) z4[dn] = dl[dn] * accZc[dp][dn];
            *(f32x4*)(zcO + mbase + p * 64 + 4 * ni) = z4;
        }
#pragma unroll
        for (int dn = 0; dn < 4; ++dn) {
            int nn = 4 * ni + dn;
            float dlv = dl[dn];
            bf16x4 h4, l4;
#pragma unroll
            for (int dp = 0; dp < 4; ++dp) {
                int p = 4 * pi + dp;
                float mm = (accM[dp][dn] + ((p == nn) ? 1.f : 0.f)) * dlv;
                __bf16 hb = f2bb(mm);
                h4[dp] = hb;
                l4[dp] = f2bb(mm - bb2f(hb));
            }
            *(bf16x4*)(mtHi + mbase + (size_t)nn * 64 + 4 * pi) = h4;
            *(bf16x4*)(mtLo + mbase + (size_t)nn * 64 + 4 * pi) = l4;
        }
    }
}

// ---------------- phase B1: sequential state chain via split-precision MFMA ----------------
// FULLY UNROLLED chunk loop so the double-buffer index cb is compile-time (rule #20).

__global__ __launch_bounds__(256) void chunkB1_kernel(
    const float* __restrict__ zc,
    const __bf16* __restrict__ mtHi,
    const __bf16* __restrict__ mtLo,
    float* __restrict__ schk) {
    int bh = blockIdx.x;
    int tid = threadIdx.x;
    int lane = tid & 63, w = tid >> 6;
    int r0 = lane & 15, u = lane >> 4;
    __shared__ __align__(16) float S[64][68];
    for (int i = tid; i < 64 * 68; i += 256) (&S[0][0])[i] = 0.f;
    const float* zbase = zc + (size_t)bh * NC * 4096;
    const __bf16* hbase = mtHi + (size_t)bh * NC * 4096;
    const __bf16* lbase = mtLo + (size_t)bh * NC * 4096;
    float* sbase = schk + (size_t)bh * NC * 4096;
    int arow = w * 16 + r0;

    bf16x8 mh[2][4][2], ml[2][4][2];
    f32x4 zf[2][4];
#pragma unroll
    for (int ct = 0; ct < 4; ++ct) {
#pragma unroll
        for (int ks = 0; ks < 2; ++ks) {
            size_t mo = (size_t)(ct * 16 + r0) * 64 + ks * 32 + u * 8;
            mh[0][ct][ks] = *(const bf16x8*)(hbase + mo);
            ml[0][ct][ks] = *(const bf16x8*)(lbase + mo);
        }
#pragma unroll
        for (int q = 0; q < 4; ++q)
            zf[0][ct][q] = zbase[(size_t)(w * 16 + u * 4 + q) * 64 + ct * 16 + r0];
    }
    __syncthreads();
#pragma unroll
    for (int c = 0; c < NC - 1; ++c) {
        const int cb = c & 1;          // compile-time after full unroll
        if (c + 1 < NC - 1) {
            const __bf16* hn = hbase + (size_t)(c + 1) * 4096;
            const __bf16* ln = lbase + (size_t)(c + 1) * 4096;
            const float* zn = zbase + (size_t)(c + 1) * 4096;
#pragma unroll
            for (int ct = 0; ct < 4; ++ct) {
#pragma unroll
                for (int ks = 0; ks < 2; ++ks) {
                    size_t mo = (size_t)(ct * 16 + r0) * 64 + ks * 32 + u * 8;
                    mh[cb ^ 1][ct][ks] = *(const bf16x8*)(hn + mo);
                    ml[cb ^ 1][ct][ks] = *(const bf16x8*)(ln + mo);
                }
#pragma unroll
                for (int q = 0; q < 4; ++q)
                    zf[cb ^ 1][ct][q] = zn[(size_t)(w * 16 + u * 4 + q) * 64 + ct * 16 + r0];
            }
        }
        bf16x8 ah[2], al[2];
#pragma unroll
        for (int ks = 0; ks < 2; ++ks) {
            f32x4 s0 = *(const f32x4*)&S[arow][ks * 32 + u * 8];
            f32x4 s1 = *(const f32x4*)&S[arow][ks * 32 + u * 8 + 4];
#pragma unroll
            for (int e = 0; e < 4; ++e) {
                __bf16 h0 = f2bb(s0[e]);
                ah[ks][e] = h0;
                al[ks][e] = f2bb(s0[e] - bb2f(h0));
                __bf16 h1 = f2bb(s1[e]);
                ah[ks][4 + e] = h1;
                al[ks][4 + e] = f2bb(s1[e] - bb2f(h1));
            }
        }
        f32x4 acc[4];
#pragma unroll
        for (int ct = 0; ct < 4; ++ct) {
            acc[ct] = zf[cb][ct];
#pragma unroll
            for (int ks = 0; ks < 2; ++ks) {
                acc[ct] = __builtin_amdgcn_mfma_f32_16x16x32_bf16(ah[ks], mh[cb][ct][ks], acc[ct], 0, 0, 0);
                acc[ct] = __builtin_amdgcn_mfma_f32_16x16x32_bf16(ah[ks], ml[cb][ct][ks], acc[ct], 0, 0, 0);
                acc[ct] = __builtin_amdgcn_mfma_f32_16x16x32_bf16(al[ks], mh[cb][ct][ks], acc[ct], 0, 0, 0);
            }
        }
        __syncthreads();   // all S reads complete
        float* cp = sbase + (size_t)(c + 1) * 4096;
#pragma unroll
        for (int ct = 0; ct < 4; ++ct) {
#pragma unroll
            for (int q = 0; q < 4; ++q) {
                int row = w * 16 + u * 4 + q;
                int col = ct * 16 + r0;
                S[row][col] = acc[ct][q];
                cp[(size_t)row * 64 + col] = acc[ct][q];
            }
        }
        __syncthreads();   // S_new visible before next chunk
    }
}

// ---------------- phase Y (unchanged) ----------------

__global__ __launch_bounds__(256) void chunkY_kernel(
    const float* __restrict__ yintra, const float* __restrict__ zrI,
    const float* __restrict__ schk,
    const float* __restrict__ r, const float* __restrict__ kupd,
    const float* __restrict__ v, const float* __restrict__ g,
    const float* __restrict__ rk, const float* __restrict__ lw,
    const float* __restrict__ lb, bf16* __restrict__ out) {
    int c = blockIdx.x, bh = blockIdx.y;
    int b = bh / HH, h = bh % HH;
    __shared__ float Y[LCH][SPAD];
    __shared__ float Zr[LCH][SPAD];
    __shared__ float Sh[64][SPAD];
    int tid = threadIdx.x;
    int n = tid & 63, tq = tid >> 6;
    size_t obase = ((size_t)(bh * NC + c)) * LCH * 64;
#pragma unroll
    for (int e = 0; e < 8; ++e) {
        int idx = tid + e * 256;
        int row = idx >> 6, col = idx & 63;
        Y[row][col] = yintra[obase + idx];
        Zr[row][col] = zrI[obase + idx];
    }
    if (c > 0) {
        size_t sbase = ((size_t)(bh * NC + c)) * 4096;
#pragma unroll
        for (int e = 0; e < 16; ++e) {
            int idx = tid + e * 256;
            Sh[idx >> 6][idx & 63] = schk[sbase + idx];
        }
    }
    __syncthreads();
    if (c > 0) {
        float acc[8];
#pragma unroll
        for (int e = 0; e < 8; ++e) acc[e] = 0.f;
        for (int p = 0; p < 64; ++p) {
            float sv = Sh[n][p];
#pragma unroll
            for (int e = 0; e < 8; ++e)
                acc[e] = fmaf(Zr[tq * 8 + e][p], sv, acc[e]);
        }
#pragma unroll
        for (int e = 0; e < 8; ++e) Y[tq * 8 + e][n] += acc[e];
    }
    size_t rowbase = ((size_t)(b * TT + c * LCH)) * CC + h * 64 + n;
    float rkv = rk[h * 64 + n];
    float lwv = lw[h * 64 + n], lbv = lb[h * 64 + n];
#pragma unroll
    for (int e = 0; e < 8; ++e) {
        int t = tq * 8 + e;
        size_t off = rowbase + (size_t)t * CC;
        float yv = Y[t][n];
        float rv = r[off], kv = kupd[off], vv = v[off];
        float s1 = yv, s2 = yv * yv, s3 = rv * kv * rkv;
        for (int m = 1; m < 64; m <<= 1) {
            s1 += __shfl_xor(s1, m);
            s2 += __shfl_xor(s2, m);
            s3 += __shfl_xor(s3, m);
        }
        float mean = s1 * (1.f / 64.f);
        float var  = s2 * (1.f / 64.f) - mean * mean;
        float inv  = rsqrtf(var + 64e-5f);
        float val  = (yv - mean) * inv * lwv + lbv + s3 * vv;
        out[off] = f2b(val * g[off]);
    }
}

// ---------------- host ----------------

extern "C" void kernel_launch(void* const* d_in, const int* in_sizes, int n_in,
                              void* d_out, int out_size, void* d_ws, size_t ws_size,
                              hipStream_t stream) {
    (void)in_sizes; (void)n_in; (void)out_size;
    const float* x    = (const float*)d_in[0];
    const float* x_r  = (const float*)d_in[1];
    const float* x_w  = (const float*)d_in[2];
    const float* x_k  = (const float*)d_in[3];
    const float* x_v  = (const float*)d_in[4];
    const float* x_a  = (const float*)d_in[5];
    const float* x_g  = (const float*)d_in[6];
    const float* w0   = (const float*)d_in[7];
    const float* w1   = (const float*)d_in[8];
    const float* w2   = (const float*)d_in[9];
    const float* a0   = (const float*)d_in[10];
    const float* a1   = (const float*)d_in[11];
    const float* a2   = (const float*)d_in[12];
    const float* v0   = (const float*)d_in[13];
    const float* v1   = (const float*)d_in[14];
    const float* v2   = (const float*)d_in[15];
    const float* g1   = (const float*)d_in[16];
    const float* g2   = (const float*)d_in[17];
    const float* k_k  = (const float*)d_in[18];
    const float* k_a  = (const float*)d_in[19];
    const float* r_k  = (const float*)d_in[20];
    const float* W_r  = (const float*)d_in[21];
    const float* W_k  = (const float*)d_in[22];
    const float* W_v  = (const float*)d_in[23];
    const float* W_o  = (const float*)d_in[24];
    const float* ln_x_w = (const float*)d_in[25];
    const float* ln_x_b = (const float*)d_in[26];
    const float* ln1_w  = (const float*)d_in[27];
    const float* ln1_b  = (const float*)d_in[28];
    const float* ln2_w  = (const float*)d_in[29];
    const float* ln2_b  = (const float*)d_in[30];
    const float* c_x_k  = (const float*)d_in[31];
    const float* W_ck   = (const float*)d_in[32];
    const float* W_cv   = (const float*)d_in[33];

    const size_t MC = (size_t)MT * CC;
    char* wsb = (char*)d_ws;
    size_t woff = 0;
    auto alloc = [&](size_t bytes) -> void* {
        void* p = wsb + woff;
        woff += (bytes + 255) & ~(size_t)255;
        return p;
    };
    const size_t S_Bcat = (size_t)2624 * 1536;
    const size_t S_Bck  = (size_t)3072 * 1536;
    const size_t S_w2t  = (size_t)768 * 64;
    const size_t S_a2t  = (size_t)768 * 64;
    const size_t S_v2t  = (size_t)768 * 64;   // padded to K=64
    const size_t S_g2t  = (size_t)768 * 128;
    const size_t S_Wo   = (size_t)768 * 768;
    const size_t S_Wcv  = (size_t)768 * 3072;
    bf16* BcatA = (bf16*)alloc(S_Bcat * LAYERS * 2);
    bf16* BckA  = (bf16*)alloc(S_Bck  * LAYERS * 2);
    bf16* w2tA  = (bf16*)alloc(S_w2t  * LAYERS * 2);
    bf16* a2tA  = (bf16*)alloc(S_a2t  * LAYERS * 2);
    bf16* v2tA  = (bf16*)alloc(S_v2t  * LAYERS * 2);
    bf16* g2tA  = (bf16*)alloc(S_g2t  * LAYERS * 2);
    bf16* WoA   = (bf16*)alloc(S_Wo   * LAYERS * 2);
    bf16* WcvA  = (bf16*)alloc(S_Wcv  * LAYERS * 2);
    bf16* A1    = (bf16*)alloc((size_t)MT * 1536 * 2);
    float* rbuf  = (float*)alloc(MC * 4);
    float* kraw  = (float*)alloc(MC * 4);
    float* kupd  = (float*)alloc(MC * 4);
    float* vbuf  = (float*)alloc(MC * 4);
    float* vfirst= (float*)alloc(MC * 4);
    float* abuf  = (float*)alloc(MC * 4);
    float* dbuf  = (float*)alloc(MC * 4);
    float* gbuf  = (float*)alloc(MC * 4);
    bf16* w1o   = (bf16*)alloc((size_t)MT * 64 * 2);
    bf16* a1o   = (bf16*)alloc((size_t)MT * 64 * 2);
    bf16* v1o   = (bf16*)alloc((size_t)MT * 64 * 2);   // widened to 64 cols
    bf16* g1o   = (bf16*)alloc((size_t)MT * 128 * 2);
    bf16* hbuf  = (bf16*)alloc((size_t)MT * FF * 2);
    bf16* ghout = (bf16*)alloc(MC * 2);
    float* yintraW = (float*)alloc((size_t)BH * NC * LCH * 64 * 4);
    float* zrW     = (float*)alloc((size_t)BH * NC * LCH * 64 * 4);
    __bf16* mtHiW  = (__bf16*)alloc((size_t)BH * NC * 4096 * 2);
    __bf16* mtLoW  = (__bf16*)alloc((size_t)BH * NC * 4096 * 2);
    float* zcW     = (float*)alloc((size_t)BH * NC * 4096 * 4);
    float* schkW   = (float*)alloc((size_t)BH * NC * 4096 * 4);
    if (woff > ws_size) return;

    float* xcur = (float*)d_out;
    copy_f<<<MC / 256, 256, 0, stream>>>(xcur, x);

    // ---- convert ALL layers' weights in one launch (vectorized 64x32 tiles) ----
    CArgs ca;
    ca.e[0]  = {W_r,  x_r,  BcatA,                    768, 768, 768, 1536, 0, 589824, (int)S_Bcat};
    ca.e[1]  = {W_k,  x_k,  BcatA + (size_t)768  * 1536, 768, 768, 768, 1536, 0, 589824, (int)S_Bcat};
    ca.e[2]  = {W_v,  x_v,  BcatA + (size_t)1536 * 1536, 768, 768, 768, 1536, 0, 589824, (int)S_Bcat};
    ca.e[3]  = {w1,   x_w,  BcatA + (size_t)2304 * 1536, 768, 64, 64, 1536, 0, 49152, (int)S_Bcat};
    ca.e[4]  = {a1,   x_a,  BcatA + (size_t)2368 * 1536, 768, 64, 64, 1536, 0, 49152, (int)S_Bcat};
    ca.e[5]  = {g1,   x_g,  BcatA + (size_t)2432 * 1536, 768, 128, 128, 1536, 0, 98304, (int)S_Bcat};
    ca.e[6]  = {v1,   x_v,  BcatA + (size_t)2560 * 1536, 768, 32, 64, 1536, 0, 24576, (int)S_Bcat};
    ca.e[7]  = {W_ck, c_x_k, BckA, 768, 3072, 3072, 1536, 0, 2359296, (int)S_Bck};
    ca.e[8]  = {w2,   nullptr, w2tA,   64, 768, 768, 64, 0, 49152, (int)S_w2t};
    ca.e[9]  = {a2,   nullptr, a2tA,   64, 768, 768, 64, 0, 49152, (int)S_a2t};
    ca.e[10] = {v2,   nullptr, v2tA,   32, 768, 768, 64, 0, 24576, (int)S_v2t};
    ca.e[11] = {g2,   nullptr, g2tA,  128, 768, 768, 128, 0, 98304, (int)S_g2t};
    ca.e[12] = {W_o,  nullptr, WoA,  768, 768, 768, 768, 0, 589824, (int)S_Wo};
    ca.e[13] = {W_cv, nullptr, WcvA, 3072, 768, 768, 3072, 0, 2359296, (int)S_Wcv};
    int btot = 0;
    for (int i = 0; i < 14; ++i) {
        ca.e[i].bstart = btot;
        btot += (ca.e[i].Npad >> 5) * (ca.e[i].Kdst >> 6);
    }
    convert_weights<<<dim3(btot, LAYERS), 256, 0, stream>>>(ca);

    for (int l = 0; l < LAYERS; ++l) {
        size_t oC = (size_t)l * CC;
        float* vptr = (l == 0) ? vfirst : vbuf;
        const __bf16* Bcat  = (const __bf16*)(BcatA + (size_t)l * S_Bcat);
        const __bf16* Bck   = (const __bf16*)(BckA  + (size_t)l * S_Bck);
        const __bf16* w2t   = (const __bf16*)(w2tA  + (size_t)l * S_w2t);
        const __bf16* a2t   = (const __bf16*)(a2tA  + (size_t)l * S_a2t);
        const __bf16* v2t   = (const __bf16*)(v2tA  + (size_t)l * S_v2t);
        const __bf16* g2t   = (const __bf16*)(g2tA  + (size_t)l * S_g2t);
        const __bf16* Wo_t  = (const __bf16*)(WoA   + (size_t)l * S_Wo);
        const __bf16* Wcv_t = (const __bf16*)(WcvA  + (size_t)l * S_Wcv);

        // ---- time mix ----
        ln_shift_kernel<<<MT, 256, 0, stream>>>(xcur, ln1_w + oC, ln1_b + oC, A1);

        EpiArgs e1;
        e1.g[0] = {rbuf,  nullptr, nullptr, nullptr, 0, 768, 768};
        e1.g[1] = {kraw,  nullptr, nullptr, nullptr, 0, 768, 768};
        e1.g[2] = {vptr,  nullptr, nullptr, nullptr, 0, 768, 768};
        e1.g[3] = {nullptr, w1o, nullptr, nullptr, 2, 64, 64};
        e1.g[4] = {nullptr, a1o, nullptr, nullptr, 1, 64, 64};
        e1.g[5] = {nullptr, g1o, nullptr, nullptr, 3, 128, 128};
        e1.g[6] = {nullptr, v1o, nullptr, nullptr, 1, 64, 64};
        int nb1[8] = {0, 768, 1536, 2304, 2368, 2432, 2560, 2624};
        for (int i = 0; i < 8; ++i) e1.nb[i] = nb1[i];
        gemm_multi<64, 64><<<dim3(41, 16), 256, 0, stream>>>((const __bf16*)A1, Bcat, 1536, e1);

        G2Args g2a;
        g2a.g[0] = {(const __bf16*)w1o, w2t, dbuf, w0 + oC, nullptr, 64, 6};
        g2a.g[1] = {(const __bf16*)a1o, a2t, abuf, a0 + oC, nullptr, 64, 7};
        g2a.g[2] = {(const __bf16*)g1o, g2t, gbuf, nullptr, nullptr, 128, 0};
        g2a.g[3] = {(const __bf16*)v1o, v2t, vbuf, v0 + oC, vfirst, 64, 8};
        gemm_g2<128, 64><<<dim3(12, 8, (l == 0) ? 3 : 4), 256, 0, stream>>>(g2a);

        // ---- chunked scan ----
        chunkA_kernel<<<dim3(NC, BH), 256, 0, stream>>>(rbuf, dbuf, kraw, abuf, vptr,
                                                        k_k + oC, k_a + oC, kupd,
                                                        yintraW, zrW, mtHiW, mtLoW, zcW);
        chunkB1_kernel<<<BH, 256, 0, stream>>>(zcW, mtHiW, mtLoW, schkW);
        chunkY_kernel<<<dim3(NC, BH), 256, 0, stream>>>(yintraW, zrW, schkW,
                                                        rbuf, kupd, vptr, gbuf,
                                                        r_k + (size_t)l * 768,
                                                        ln_x_w + oC, ln_x_b + oC, ghout);

        EpiArgs eo;
        eo.g[0] = {xcur, nullptr, nullptr, nullptr, 5, 768, 768};
        eo.nb[0] = 0; for (int i = 1; i < 8; ++i) eo.nb[i] = 1 << 30;
        eo.nb[1] = 768;
        gemm_multi<64, 64><<<dim3(12, 16), 256, 0, stream>>>((const __bf16*)ghout, Wo_t, 768, eo);

        // ---- channel mix ----
        ln_shift_kernel<<<MT, 256, 0, stream>>>(xcur, ln2_w + oC, ln2_b + oC, A1);

        EpiArgs ec;
        ec.g[0] = {nullptr, hbuf, nullptr, nullptr, 4, 3072, 3072};
        ec.nb[0] = 0; for (int i = 1; i < 8; ++i) ec.nb[i] = 1 << 30;
        ec.nb[1] = 3072;
        gemm_multi<64, 64><<<dim3(48, 16), 256, 0, stream>>>((const __bf16*)A1, Bck, 1536, ec);

        EpiArgs ev;
        ev.g[0] = {xcur, nullptr, nullptr, nullptr, 5, 768, 768};
        ev.nb[0] = 0; for (int i = 1; i < 8; ++i) ev.nb[i] = 1 << 30;
        ev.nb[1] = 768;
        gemm_multi<64, 64><<<dim3(12, 16), 256, 0, stream>>>((const __bf16*)hbuf, Wcv_t, 3072, ev);
    }
}

// Round 13
// 1288.339 us; speedup vs baseline: 1.3536x; 1.0490x over previous
//
#include <hip/hip_runtime.h>
#include <hip/hip_bf16.h>
#include <math.h>

#define LAYERS 6
#define BBATCH 2
#define TT 512
#define CC 768
#define HH 12
#define MT (BBATCH*TT)      // 1024 tokens
#define FF (4*CC)           // 3072
#define LCH 32
#define NC (TT/LCH)         // 16 chunks
#define BH (BBATCH*HH)      // 24
#define SPAD 65

typedef __hip_bfloat16 bf16;
typedef __bf16 bf16x8 __attribute__((ext_vector_type(8)));
typedef __bf16 bf16x4 __attribute__((ext_vector_type(4)));
typedef float f32x4 __attribute__((ext_vector_type(4)));

__device__ inline bf16 f2b(float f) { return __float2bfloat16(f); }
__device__ inline __bf16 f2bb(float f) {
    __hip_bfloat16 h = __float2bfloat16(f);
    return __builtin_bit_cast(__bf16, h);
}
__device__ inline float bb2f(__bf16 h) {
    return __bfloat162float(__builtin_bit_cast(__hip_bfloat16, h));
}

// ---------------- utility ----------------

__global__ __launch_bounds__(256) void copy_f(float* __restrict__ dst, const float* __restrict__ src) {
    size_t i = (size_t)blockIdx.x * 256 + threadIdx.x;
    dst[i] = src[i];
}

// ---------------- fused layernorm + token-shift-diff, bf16 concat output ----------------

__global__ __launch_bounds__(256) void ln_shift_kernel(const float* __restrict__ x,
                                                       const float* __restrict__ w,
                                                       const float* __restrict__ b,
                                                       bf16* __restrict__ out) {
    int row = blockIdx.x;
    int t = row % TT;
    const float* xr = x + (size_t)row * CC;
    const float* xp = xr - CC;
    int tid = threadIdx.x;
    float c0 = xr[tid], c1 = xr[tid + 256], c2 = xr[tid + 512];
    float p0 = 0.f, p1 = 0.f, p2 = 0.f;
    if (t > 0) { p0 = xp[tid]; p1 = xp[tid + 256]; p2 = xp[tid + 512]; }
    float s  = c0 + c1 + c2, q  = c0 * c0 + c1 * c1 + c2 * c2;
    float sp = p0 + p1 + p2, qp = p0 * p0 + p1 * p1 + p2 * p2;
    for (int m = 1; m < 64; m <<= 1) {
        s += __shfl_xor(s, m); q += __shfl_xor(q, m);
        sp += __shfl_xor(sp, m); qp += __shfl_xor(qp, m);
    }
    __shared__ float rs[4], rq[4], rsp[4], rqp[4];
    int wid = tid >> 6;
    if ((tid & 63) == 0) { rs[wid] = s; rq[wid] = q; rsp[wid] = sp; rqp[wid] = qp; }
    __syncthreads();
    s  = rs[0] + rs[1] + rs[2] + rs[3];   q  = rq[0] + rq[1] + rq[2] + rq[3];
    sp = rsp[0] + rsp[1] + rsp[2] + rsp[3]; qp = rqp[0] + rqp[1] + rqp[2] + rqp[3];
    float meanC = s * (1.f / CC);
    float invC  = rsqrtf(q * (1.f / CC) - meanC * meanC + 1e-5f);
    float meanP = sp * (1.f / CC);
    float invP  = rsqrtf(qp * (1.f / CC) - meanP * meanP + 1e-5f);
    bf16* orow = out + (size_t)row * 1536;
    float cv[3] = {c0, c1, c2};
    float pv[3] = {p0, p1, p2};
#pragma unroll
    for (int j = 0; j < 3; ++j) {
        int cc = tid + j * 256;
        float lnc = (cv[j] - meanC) * invC * w[cc] + b[cc];
        float lnp = (t > 0) ? (pv[j] - meanP) * invP * w[cc] + b[cc] : 0.f;
        orow[cc] = f2b(lnc);
        orow[768 + cc] = f2b(lnp - lnc);
    }
}

// ---------------- weight convert: ALL LAYERS, float4 loads, dual-half writes ----------------
// Block covers 64 SOURCE k-rows x 32 n-cols. Mix entries write BOTH K-halves
// (plain + x mix) from one source read. Plain entries with Kdst > Ksrc zero-pad.

struct CEntry { const float* W; const float* mix; bf16* dst;
                int Ksrc, Nsrc, Npad, Kdst, bstart, wstr, dstr; };
struct CArgs { CEntry e[14]; };

__global__ __launch_bounds__(256) void convert_weights(CArgs ca) {
    int bid = blockIdx.x;
    int l = blockIdx.y;
    int idx = 0;
#pragma unroll
    for (int i = 1; i < 14; ++i) if (bid >= ca.e[i].bstart) idx = i;
    CEntry E = ca.e[idx];
    const float* Wsrc = E.W + (size_t)l * E.wstr;
    __bf16* d = (__bf16*)(E.dst + (size_t)l * E.dstr);
    int t = bid - E.bstart;
    int ntN = E.Npad >> 5;
    int tn = (t % ntN) * 32;
    int tk = (t / ntN) * 64;
    __shared__ float tile[64][33];
    int tid = threadIdx.x;
    const float* mixl = E.mix ? (E.mix + (size_t)l * CC) : nullptr;
#pragma unroll
    for (int i = 0; i < 2; ++i) {
        int r = (tid >> 3) + 32 * i;
        int c4 = (tid & 7) * 4;
        int kk = tk + r;
        f32x4 v = (f32x4){0.f, 0.f, 0.f, 0.f};
        if (kk < E.Ksrc && tn + c4 < E.Nsrc)
            v = *(const f32x4*)(Wsrc + (size_t)kk * E.Nsrc + tn + c4);
        tile[r][c4 + 0] = v[0];
        tile[r][c4 + 1] = v[1];
        tile[r][c4 + 2] = v[2];
        tile[r][c4 + 3] = v[3];
    }
    __syncthreads();
    int n2 = tid >> 3, slot = tid & 7;
    bf16x8 h8;
#pragma unroll
    for (int e = 0; e < 8; ++e) h8[e] = f2bb(tile[slot * 8 + e][n2]);
    *(bf16x8*)(d + (size_t)(tn + n2) * E.Kdst + tk + slot * 8) = h8;
    if (mixl) {
        bf16x8 h8m;
#pragma unroll
        for (int e = 0; e < 8; ++e)
            h8m[e] = f2bb(tile[slot * 8 + e][n2] * mixl[tk + slot * 8 + e]);
        *(bf16x8*)(d + (size_t)(tn + n2) * E.Kdst + E.Ksrc + tk + slot * 8) = h8m;
    }
}

// ---------------- epilogues ----------------

struct EpiG {
    float* outF; bf16* outH;
    const float* p1; const float* p2;
    int epi, ld, ntrue;
};
struct EpiArgs { EpiG g[7]; int nb[8]; };

__device__ inline void epi_store(const EpiG& E, size_t idx, int lc, float v) {
    switch (E.epi) {
        case 0: E.outF[idx] = v; break;
        case 1: E.outH[idx] = f2b(v); break;
        case 2: E.outH[idx] = f2b(tanhf(v)); break;
        case 3: E.outH[idx] = f2b(1.f / (1.f + expf(-v))); break;
        case 4: { float t = fmaxf(v, 0.f); E.outH[idx] = f2b(t * t); } break;
        case 5: E.outF[idx] += v; break;
        case 6: { float z = E.p1[lc] + v; float nz = -z;
                  float sp = (nz > 20.f) ? nz : log1pf(expf(nz));
                  E.outF[idx] = expf(-expf(-sp - 0.5f)); } break;
        case 7: E.outF[idx] = 1.f / (1.f + expf(-(E.p1[lc] + v))); break;
        case 8: { float vv = E.outF[idx];
                  float s = 1.f / (1.f + expf(-(E.p1[lc] + v)));
                  E.outF[idx] = vv + (E.p2[idx] - vv) * s; } break;
    }
}

// ---------------- bf16 MFMA GEMM, BK=64, XCD-swizzled, grouped-column epilogue ----------------

template<int BM, int BN>
__global__ __launch_bounds__(256) void gemm_multi(const __bf16* __restrict__ A,
                                                  const __bf16* __restrict__ Bt,
                                                  int K, EpiArgs ea) {
    constexpr int FM = BM / 32, FN = BN / 32;
    constexpr int ABYTES = BM * 128;
    constexpr int TOT = (BM + BN) * 128;
    constexpr int NCHUNK = TOT / 4096;
    __shared__ __align__(16) char smem[2][TOT];
    int tid = threadIdx.x;
    int lane = tid & 63, wid = tid >> 6;
    int nwg = gridDim.x * gridDim.y;
    int orig = blockIdx.y * gridDim.x + blockIdx.x;
    int qq = nwg >> 3, rr = nwg & 7, xc = orig & 7, oo = orig >> 3;
    int swz = (xc < rr ? xc * (qq + 1) : rr * (qq + 1) + (xc - rr) * qq) + oo;
    int bn = (swz % gridDim.x) * BN, bm = (swz / gridDim.x) * BM;
    int wm = (wid >> 1) * (BM / 2), wn = (wid & 1) * (BN / 2);
    f32x4 acc[FM][FN];
#pragma unroll
    for (int i = 0; i < FM; ++i)
#pragma unroll
        for (int j = 0; j < FN; ++j) acc[i][j] = (f32x4){0.f, 0.f, 0.f, 0.f};

    int nk = K >> 6;
    auto stage = [&](int buf, int k0) {
        char* sb = &smem[buf][0];
#pragma unroll
        for (int c = 0; c < NCHUNK; ++c) {
            int d = c * 4096 + tid * 16;
            int isB = d >= ABYTES;
            int dd = isB ? d - ABYTES : d;
            int row = dd >> 7;
            int slot = (dd >> 4) & 7;
            int su = slot ^ (row & 7);
            const __bf16* src = isB ? (Bt + (size_t)(bn + row) * K + k0 + su * 8)
                                    : (A  + (size_t)(bm + row) * K + k0 + su * 8);
            char* ldst = sb + c * 4096 + (tid & 192) * 16;
            __builtin_amdgcn_global_load_lds(
                (const __attribute__((address_space(1))) unsigned int*)src,
                (__attribute__((address_space(3))) unsigned int*)ldst, 16, 0, 0);
        }
    };

    stage(0, 0);
    __syncthreads();
    for (int t = 0; t < nk; ++t) {
        if (t + 1 < nk) stage((t + 1) & 1, (t + 1) * 64);
        const char* sA = &smem[t & 1][0];
        const char* sB = &smem[t & 1][ABYTES];
        int u = lane >> 4, r0 = lane & 15;
        bf16x8 af[2][FM], bfr[2][FN];
#pragma unroll
        for (int ks = 0; ks < 2; ++ks) {
#pragma unroll
            for (int i = 0; i < FM; ++i) {
                int row = wm + i * 16 + r0;
                int slot = (ks * 4 + u) ^ (row & 7);
                af[ks][i] = *(const bf16x8*)(sA + row * 128 + slot * 16);
            }
#pragma unroll
            for (int j = 0; j < FN; ++j) {
                int row = wn + j * 16 + r0;
                int slot = (ks * 4 + u) ^ (row & 7);
                bfr[ks][j] = *(const bf16x8*)(sB + row * 128 + slot * 16);
            }
        }
#pragma unroll
        for (int ks = 0; ks < 2; ++ks)
#pragma unroll
            for (int i = 0; i < FM; ++i)
#pragma unroll
                for (int j = 0; j < FN; ++j)
                    acc[i][j] = __builtin_amdgcn_mfma_f32_16x16x32_bf16(af[ks][i], bfr[ks][j], acc[i][j], 0, 0, 0);
        __syncthreads();
    }

    int gid = 0;
#pragma unroll 1
    while (bn >= ea.nb[gid + 1]) ++gid;
    EpiG E = ea.g[gid];
    int colBase = ea.nb[gid];
#pragma unroll
    for (int i = 0; i < FM; ++i) {
#pragma unroll
        for (int j = 0; j < FN; ++j) {
#pragma unroll
            for (int q = 0; q < 4; ++q) {
                int gm = bm + wm + i * 16 + (lane >> 4) * 4 + q;
                int lc = bn + wn + j * 16 + (lane & 15) - colBase;
                if (lc < E.ntrue)
                    epi_store(E, (size_t)gm * E.ld + lc, lc, acc[i][j][q]);
            }
        }
    }
}

// ---------------- grouped low-rank GEMM (BK=32; 2-way swizzle) ----------------

struct G2G { const __bf16* A; const __bf16* Bt; float* outF; const float* p1; const float* p2; int K; int epi; };
struct G2Args { G2G g[4]; };

template<int BM, int BN>
__global__ __launch_bounds__(256) void gemm_g2(G2Args ga) {
    G2G G = ga.g[blockIdx.z];
    const __bf16* A = G.A;
    const __bf16* Bt = G.Bt;
    int K = G.K;
    constexpr int FM = BM / 32, FN = BN / 32;
    constexpr int ABYTES = BM * 64;
    constexpr int TOT = (BM + BN) * 64;
    constexpr int NCHUNK = TOT / 4096;
    __shared__ __align__(16) char smem[2][TOT];
    int tid = threadIdx.x;
    int lane = tid & 63, wid = tid >> 6;
    int bm = blockIdx.y * BM, bn = blockIdx.x * BN;
    int wm = (wid >> 1) * (BM / 2), wn = (wid & 1) * (BN / 2);
    f32x4 acc[FM][FN];
#pragma unroll
    for (int i = 0; i < FM; ++i)
#pragma unroll
        for (int j = 0; j < FN; ++j) acc[i][j] = (f32x4){0.f, 0.f, 0.f, 0.f};

    int nk = K >> 5;
    auto stage = [&](int buf, int k0) {
        char* sb = &smem[buf][0];
#pragma unroll
        for (int c = 0; c < NCHUNK; ++c) {
            int d = c * 4096 + tid * 16;
            int isB = d >= ABYTES;
            int dd = isB ? d - ABYTES : d;
            int row = dd >> 6;
            int u = (dd >> 4) & 3;
            int su = u ^ ((row >> 1) & 3);
            const __bf16* src = isB ? (Bt + (size_t)(bn + row) * K + k0 + su * 8)
                                    : (A  + (size_t)(bm + row) * K + k0 + su * 8);
            char* ldst = sb + c * 4096 + (tid & 192) * 16;
            __builtin_amdgcn_global_load_lds(
                (const __attribute__((address_space(1))) unsigned int*)src,
                (__attribute__((address_space(3))) unsigned int*)ldst, 16, 0, 0);
        }
    };

    stage(0, 0);
    __syncthreads();
    for (int t = 0; t < nk; ++t) {
        if (t + 1 < nk) stage((t + 1) & 1, (t + 1) * 32);
        const char* sA = &smem[t & 1][0];
        const char* sB = &smem[t & 1][ABYTES];
        int u = lane >> 4, r0 = lane & 15;
        bf16x8 af[FM], bfr[FN];
#pragma unroll
        for (int i = 0; i < FM; ++i) {
            int row = wm + i * 16 + r0;
            int su = u ^ ((row >> 1) & 3);
            af[i] = *(const bf16x8*)(sA + row * 64 + su * 16);
        }
#pragma unroll
        for (int j = 0; j < FN; ++j) {
            int row = wn + j * 16 + r0;
            int su = u ^ ((row >> 1) & 3);
            bfr[j] = *(const bf16x8*)(sB + row * 64 + su * 16);
        }
#pragma unroll
        for (int i = 0; i < FM; ++i)
#pragma unroll
            for (int j = 0; j < FN; ++j)
                acc[i][j] = __builtin_amdgcn_mfma_f32_16x16x32_bf16(af[i], bfr[j], acc[i][j], 0, 0, 0);
        __syncthreads();
    }

    EpiG E;
    E.outF = G.outF; E.outH = nullptr; E.p1 = G.p1; E.p2 = G.p2;
    E.epi = G.epi; E.ld = 768; E.ntrue = 768;
#pragma unroll
    for (int i = 0; i < FM; ++i) {
#pragma unroll
        for (int j = 0; j < FN; ++j) {
#pragma unroll
            for (int q = 0; q < 4; ++q) {
                int gm = bm + wm + i * 16 + (lane >> 4) * 4 + q;
                int lc = bn + wn + j * 16 + (lane & 15);
                epi_store(E, (size_t)gm * 768 + lc, lc, acc[i][j][q]);
            }
        }
    }
}

// ---------------- chunked WKV7, phase A (register-tiled; M out as transposed bf16 pair) ----------------

__global__ __launch_bounds__(256) void chunkA_kernel(
    const float* __restrict__ r, const float* __restrict__ wd,
    const float* __restrict__ kraw, const float* __restrict__ av_,
    const float* __restrict__ v,
    const float* __restrict__ kkw, const float* __restrict__ kaw,
    float* __restrict__ kupd,
    float* __restrict__ yintra, float* __restrict__ zrO,
    __bf16* __restrict__ mtHi, __bf16* __restrict__ mtLo,
    float* __restrict__ zcO) {
    int c = blockIdx.x, bh = blockIdx.y;
    int b = bh / HH, h = bh % HH;
    __shared__ float Di[LCH][SPAD];
    __shared__ float Ah[LCH][SPAD];
    __shared__ float Bh[LCH][SPAD];
    __shared__ float Kh[LCH][SPAD];
    __shared__ float Rh[LCH][SPAD];
    __shared__ float Vt[LCH][SPAD];
    __shared__ float Qm[LCH][SPAD];
    __shared__ float Gba[LCH][LCH], Gka[LCH][LCH], Grb[LCH][LCH], Grk[LCH][LCH];
    int tid = threadIdx.x;
    int n = tid & 63, tq = tid >> 6;
    size_t base = ((size_t)(b * TT + c * LCH)) * CC + h * 64 + n;
    int cvec = h * 64 + n;
    float kkwv = kkw[cvec], kawv = kaw[cvec];
#pragma unroll
    for (int e = 0; e < 8; ++e) {
        int t = tq * 8 + e;
        size_t off = base + (size_t)t * CC;
        float kr = kraw[off];
        float aval = av_[off];
        float kk0 = kr * kkwv;
        float ss = kk0 * kk0;
        for (int m = 1; m < 64; m <<= 1) ss += __shfl_xor(ss, m);
        float rinv = 1.f / fmaxf(sqrtf(ss), 1e-12f);
        float kkv = kk0 * rinv;
        float ku = kr * (1.f + (aval - 1.f) * kawv);
        kupd[off] = ku;
        Di[t][n] = wd[off];
        Ah[t][n] = -kkv;
        Bh[t][n] = kkv * aval;
        Kh[t][n] = ku;
        Rh[t][n] = r[off];
        Vt[t][n] = v[off];
    }
    __syncthreads();
    if (tid < 64) {
        float d = 1.f;
        for (int t = 0; t < LCH; ++t) { d *= Di[t][tid]; Di[t][tid] = d; }
    }
    __syncthreads();
#pragma unroll
    for (int e = 0; e < 8; ++e) {
        int t = tq * 8 + e;
        float di = Di[t][n];
        float dp = (t == 0) ? 1.f : Di[t - 1][n];
        float inv = 1.f / di;
        Ah[t][n] *= dp;
        Bh[t][n] *= inv;
        Kh[t][n] *= inv;
        Rh[t][n] *= di;
    }
    __syncthreads();
    // ---- G phase: 2x2 (t,s) tiles ----
    {
        int tp = tid >> 4, sp = tid & 15;
        int t0 = 2 * tp, s0 = 2 * sp;
        float gba00 = 0.f, gba01 = 0.f, gba10 = 0.f, gba11 = 0.f;
        float gka00 = 0.f, gka01 = 0.f, gka10 = 0.f, gka11 = 0.f;
        float grb00 = 0.f, grb01 = 0.f, grb10 = 0.f, grb11 = 0.f;
        float grk00 = 0.f, grk01 = 0.f, grk10 = 0.f, grk11 = 0.f;
#pragma unroll 4
        for (int j = 0; j < 64; ++j) {
            float a0 = Ah[t0][j], a1 = Ah[t0 + 1][j];
            float r0 = Rh[t0][j], r1 = Rh[t0 + 1][j];
            float b0 = Bh[s0][j], b1 = Bh[s0 + 1][j];
            float k0 = Kh[s0][j], k1 = Kh[s0 + 1][j];
            gba00 = fmaf(a0, b0, gba00); gba01 = fmaf(a0, b1, gba01);
            gba10 = fmaf(a1, b0, gba10); gba11 = fmaf(a1, b1, gba11);
            gka00 = fmaf(a0, k0, gka00); gka01 = fmaf(a0, k1, gka01);
            gka10 = fmaf(a1, k0, gka10); gka11 = fmaf(a1, k1, gka11);
            grb00 = fmaf(r0, b0, grb00); grb01 = fmaf(r0, b1, grb01);
            grb10 = fmaf(r1, b0, grb10); grb11 = fmaf(r1, b1, grb11);
            grk00 = fmaf(r0, k0, grk00); grk01 = fmaf(r0, k1, grk01);
            grk10 = fmaf(r1, k0, grk10); grk11 = fmaf(r1, k1, grk11);
        }
#pragma unroll
        for (int dt = 0; dt < 2; ++dt) {
            int t = t0 + dt;
#pragma unroll
            for (int ds = 0; ds < 2; ++ds) {
                int s = s0 + ds;
                float vba = dt ? (ds ? gba11 : gba10) : (ds ? gba01 : gba00);
                float vka = dt ? (ds ? gka11 : gka10) : (ds ? gka01 : gka00);
                float vrb = dt ? (ds ? grb11 : grb10) : (ds ? grb01 : grb00);
                float vrk = dt ? (ds ? grk11 : grk10) : (ds ? grk01 : grk00);
                Gba[t][s] = (s < t)  ? vba : 0.f;
                Gka[t][s] = (s < t)  ? vka : 0.f;
                Grb[t][s] = (s <= t) ? vrb : 0.f;
                Grk[t][s] = (s <= t) ? vrk : 0.f;
            }
        }
    }
    __syncthreads();
    // ---- Qm = Gka V (s-outer) ----
    {
        float acc[8];
#pragma unroll
        for (int e = 0; e < 8; ++e) acc[e] = 0.f;
        for (int s = 0; s < LCH; ++s) {
            float vs = Vt[s][n];
#pragma unroll
            for (int e = 0; e < 8; ++e)
                acc[e] = fmaf(Gka[tq * 8 + e][s], vs, acc[e]);
        }
#pragma unroll
        for (int e = 0; e < 8; ++e) Qm[tq * 8 + e][n] = acc[e];
    }
    __syncthreads();
    // ---- forward substitution ----
    if (tq == 0) {
        for (int t = 1; t < LCH; ++t) {
            float acc = Ah[t][n];
            for (int s = 0; s < t; ++s) acc = fmaf(Gba[t][s], Ah[s][n], acc);
            Ah[t][n] = acc;
        }
    } else if (tq == 1) {
        for (int t = 1; t < LCH; ++t) {
            float acc = Qm[t][n];
            for (int s = 0; s < t; ++s) acc = fmaf(Gba[t][s], Qm[s][n], acc);
            Qm[t][n] = acc;
        }
    }
    __syncthreads();
    size_t obase = ((size_t)(bh * NC + c)) * LCH * 64;
    // ---- yintra / zr (s-outer) ----
    {
        float accY[8], accZ[8];
#pragma unroll
        for (int e = 0; e < 8; ++e) { accY[e] = 0.f; accZ[e] = Rh[tq * 8 + e][n]; }
        for (int s = 0; s < LCH; ++s) {
            float vs = Vt[s][n], qs = Qm[s][n], us = Ah[s][n];
#pragma unroll
            for (int e = 0; e < 8; ++e) {
                int t = tq * 8 + e;
                float grk_ = Grk[t][s], grb_ = Grb[t][s];
                accY[e] = fmaf(grk_, vs, fmaf(grb_, qs, accY[e]));
                accZ[e] = fmaf(grb_, us, accZ[e]);
            }
        }
#pragma unroll
        for (int e = 0; e < 8; ++e) {
            int t = tq * 8 + e;
            yintra[obase + t * 64 + n] = accY[e];
            zrO[obase + t * 64 + n] = accZ[e];
        }
    }
    // ---- M / Zc (4x4 tiles, s-outer); M stored transposed as bf16 hi/lo pair ----
    {
        int pi = tid >> 4, ni = tid & 15;
        float accM[4][4], accZc[4][4];
#pragma unroll
        for (int dp = 0; dp < 4; ++dp)
#pragma unroll
            for (int dn = 0; dn < 4; ++dn) { accM[dp][dn] = 0.f; accZc[dp][dn] = 0.f; }
        for (int s = 0; s < LCH; ++s) {
            float aa[4], vv[4], qq[4], bb[4], kk[4];
#pragma unroll
            for (int d = 0; d < 4; ++d) {
                aa[d] = Ah[s][4 * pi + d];
                vv[d] = Vt[s][4 * pi + d];
                qq[d] = Qm[s][4 * pi + d];
                bb[d] = Bh[s][4 * ni + d];
                kk[d] = Kh[s][4 * ni + d];
            }
#pragma unroll
            for (int dp = 0; dp < 4; ++dp)
#pragma unroll
                for (int dn = 0; dn < 4; ++dn) {
                    accM[dp][dn]  = fmaf(aa[dp], bb[dn], accM[dp][dn]);
                    accZc[dp][dn] = fmaf(vv[dp], kk[dn], fmaf(qq[dp], bb[dn], accZc[dp][dn]));
                }
        }
        size_t mbase = ((size_t)(bh * NC + c)) * 4096;
        float dl[4];
#pragma unroll
        for (int dn = 0; dn < 4; ++dn) dl[dn] = Di[LCH - 1][4 * ni + dn];
#pragma unroll
        for (int dp = 0; dp < 4; ++dp) {
            int p = 4 * pi + dp;
            f32x4 z4;
#pragma unroll
            for (int dn = 0; dn < 4; ++dn) z4[dn] = dl[dn] * accZc[dp][dn];
            *(f32x4*)(zcO + mbase + p * 64 + 4 * ni) = z4;
        }
#pragma unroll
        for (int dn = 0; dn < 4; ++dn) {
            int nn = 4 * ni + dn;
            float dlv = dl[dn];
            bf16x4 h4, l4;
#pragma unroll
            for (int dp = 0; dp < 4; ++dp) {
                int p = 4 * pi + dp;
                float mm = (accM[dp][dn] + ((p == nn) ? 1.f : 0.f)) * dlv;
                __bf16 hb = f2bb(mm);
                h4[dp] = hb;
                l4[dp] = f2bb(mm - bb2f(hb));
            }
            *(bf16x4*)(mtHi + mbase + (size_t)nn * 64 + 4 * pi) = h4;
            *(bf16x4*)(mtLo + mbase + (size_t)nn * 64 + 4 * pi) = l4;
        }
    }
}

// ---------------- phase B1: sequential state chain via split-precision MFMA ----------------
// FULLY UNROLLED chunk loop so the double-buffer index cb is compile-time (rule #20).

__global__ __launch_bounds__(256) void chunkB1_kernel(
    const float* __restrict__ zc,
    const __bf16* __restrict__ mtHi,
    const __bf16* __restrict__ mtLo,
    float* __restrict__ schk) {
    int bh = blockIdx.x;
    int tid = threadIdx.x;
    int lane = tid & 63, w = tid >> 6;
    int r0 = lane & 15, u = lane >> 4;
    __shared__ __align__(16) float S[64][68];
    for (int i = tid; i < 64 * 68; i += 256) (&S[0][0])[i] = 0.f;
    const float* zbase = zc + (size_t)bh * NC * 4096;
    const __bf16* hbase = mtHi + (size_t)bh * NC * 4096;
    const __bf16* lbase = mtLo + (size_t)bh * NC * 4096;
    float* sbase = schk + (size_t)bh * NC * 4096;
    int arow = w * 16 + r0;

    bf16x8 mh[2][4][2], ml[2][4][2];
    f32x4 zf[2][4];
#pragma unroll
    for (int ct = 0; ct < 4; ++ct) {
#pragma unroll
        for (int ks = 0; ks < 2; ++ks) {
            size_t mo = (size_t)(ct * 16 + r0) * 64 + ks * 32 + u * 8;
            mh[0][ct][ks] = *(const bf16x8*)(hbase + mo);
            ml[0][ct][ks] = *(const bf16x8*)(lbase + mo);
        }
#pragma unroll
        for (int q = 0; q < 4; ++q)
            zf[0][ct][q] = zbase[(size_t)(w * 16 + u * 4 + q) * 64 + ct * 16 + r0];
    }
    __syncthreads();
#pragma unroll
    for (int c = 0; c < NC - 1; ++c) {
        const int cb = c & 1;          // compile-time after full unroll
        if (c + 1 < NC - 1) {
            const __bf16* hn = hbase + (size_t)(c + 1) * 4096;
            const __bf16* ln = lbase + (size_t)(c + 1) * 4096;
            const float* zn = zbase + (size_t)(c + 1) * 4096;
#pragma unroll
            for (int ct = 0; ct < 4; ++ct) {
#pragma unroll
                for (int ks = 0; ks < 2; ++ks) {
                    size_t mo = (size_t)(ct * 16 + r0) * 64 + ks * 32 + u * 8;
                    mh[cb ^ 1][ct][ks] = *(const bf16x8*)(hn + mo);
                    ml[cb ^ 1][ct][ks] = *(const bf16x8*)(ln + mo);
                }
#pragma unroll
                for (int q = 0; q < 4; ++q)
                    zf[cb ^ 1][ct][q] = zn[(size_t)(w * 16 + u * 4 + q) * 64 + ct * 16 + r0];
            }
        }
        bf16x8 ah[2], al[2];
#pragma unroll
        for (int ks = 0; ks < 2; ++ks) {
            f32x4 s0 = *(const f32x4*)&S[arow][ks * 32 + u * 8];
            f32x4 s1 = *(const f32x4*)&S[arow][ks * 32 + u * 8 + 4];
#pragma unroll
            for (int e = 0; e < 4; ++e) {
                __bf16 h0 = f2bb(s0[e]);
                ah[ks][e] = h0;
                al[ks][e] = f2bb(s0[e] - bb2f(h0));
                __bf16 h1 = f2bb(s1[e]);
                ah[ks][4 + e] = h1;
                al[ks][4 + e] = f2bb(s1[e] - bb2f(h1));
            }
        }
        f32x4 acc[4];
#pragma unroll
        for (int ct = 0; ct < 4; ++ct) {
            acc[ct] = zf[cb][ct];
#pragma unroll
            for (int ks = 0; ks < 2; ++ks) {
                acc[ct] = __builtin_amdgcn_mfma_f32_16x16x32_bf16(ah[ks], mh[cb][ct][ks], acc[ct], 0, 0, 0);
                acc[ct] = __builtin_amdgcn_mfma_f32_16x16x32_bf16(ah[ks], ml[cb][ct][ks], acc[ct], 0, 0, 0);
                acc[ct] = __builtin_amdgcn_mfma_f32_16x16x32_bf16(al[ks], mh[cb][ct][ks], acc[ct], 0, 0, 0);
            }
        }
        __syncthreads();   // all S reads complete
        float* cp = sbase + (size_t)(c + 1) * 4096;
#pragma unroll
        for (int ct = 0; ct < 4; ++ct) {
#pragma unroll
            for (int q = 0; q < 4; ++q) {
                int row = w * 16 + u * 4 + q;
                int col = ct * 16 + r0;
                S[row][col] = acc[ct][q];
                cp[(size_t)row * 64 + col] = acc[ct][q];
            }
        }
        __syncthreads();   // S_new visible before next chunk
    }
}

// ---------------- phase Y (unchanged) ----------------

__global__ __launch_bounds__(256) void chunkY_kernel(
    const float* __restrict__ yintra, const float* __restrict__ zrI,
    const float* __restrict__ schk,
    const float* __restrict__ r, const float* __restrict__ kupd,
    const float* __restrict__ v, const float* __restrict__ g,
    const float* __restrict__ rk, const float* __restrict__ lw,
    const float* __restrict__ lb, bf16* __restrict__ out) {
    int c = blockIdx.x, bh = blockIdx.y;
    int b = bh / HH, h = bh % HH;
    __shared__ float Y[LCH][SPAD];
    __shared__ float Zr[LCH][SPAD];
    __shared__ float Sh[64][SPAD];
    int tid = threadIdx.x;
    int n = tid & 63, tq = tid >> 6;
    size_t obase = ((size_t)(bh * NC + c)) * LCH * 64;
#pragma unroll
    for (int e = 0; e < 8; ++e) {
        int idx = tid + e * 256;
        int row = idx >> 6, col = idx & 63;
        Y[row][col] = yintra[obase + idx];
        Zr[row][col] = zrI[obase + idx];
    }
    if (c > 0) {
        size_t sbase = ((size_t)(bh * NC + c)) * 4096;
#pragma unroll
        for (int e = 0; e < 16; ++e) {
            int idx = tid + e * 256;
            Sh[idx >> 6][idx & 63] = schk[sbase + idx];
        }
    }
    __syncthreads();
    if (c > 0) {
        float acc[8];
#pragma unroll
        for (int e = 0; e < 8; ++e) acc[e] = 0.f;
        for (int p = 0; p < 64; ++p) {
            float sv = Sh[n][p];
#pragma unroll
            for (int e = 0; e < 8; ++e)
                acc[e] = fmaf(Zr[tq * 8 + e][p], sv, acc[e]);
        }
#pragma unroll
        for (int e = 0; e < 8; ++e) Y[tq * 8 + e][n] += acc[e];
    }
    size_t rowbase = ((size_t)(b * TT + c * LCH)) * CC + h * 64 + n;
    float rkv = rk[h * 64 + n];
    float lwv = lw[h * 64 + n], lbv = lb[h * 64 + n];
#pragma unroll
    for (int e = 0; e < 8; ++e) {
        int t = tq * 8 + e;
        size_t off = rowbase + (size_t)t * CC;
        float yv = Y[t][n];
        float rv = r[off], kv = kupd[off], vv = v[off];
        float s1 = yv, s2 = yv * yv, s3 = rv * kv * rkv;
        for (int m = 1; m < 64; m <<= 1) {
            s1 += __shfl_xor(s1, m);
            s2 += __shfl_xor(s2, m);
            s3 += __shfl_xor(s3, m);
        }
        float mean = s1 * (1.f / 64.f);
        float var  = s2 * (1.f / 64.f) - mean * mean;
        float inv  = rsqrtf(var + 64e-5f);
        float val  = (yv - mean) * inv * lwv + lbv + s3 * vv;
        out[off] = f2b(val * g[off]);
    }
}

// ---------------- host ----------------

extern "C" void kernel_launch(void* const* d_in, const int* in_sizes, int n_in,
                              void* d_out, int out_size, void* d_ws, size_t ws_size,
                              hipStream_t stream) {
    (void)in_sizes; (void)n_in; (void)out_size;
    const float* x    = (const float*)d_in[0];
    const float* x_r  = (const float*)d_in[1];
    const float* x_w  = (const float*)d_in[2];
    const float* x_k  = (const float*)d_in[3];
    const float* x_v  = (const float*)d_in[4];
    const float* x_a  = (const float*)d_in[5];
    const float* x_g  = (const float*)d_in[6];
    const float* w0   = (const float*)d_in[7];
    const float* w1   = (const float*)d_in[8];
    const float* w2   = (const float*)d_in[9];
    const float* a0   = (const float*)d_in[10];
    const float* a1   = (const float*)d_in[11];
    const float* a2   = (const float*)d_in[12];
    const float* v0   = (const float*)d_in[13];
    const float* v1   = (const float*)d_in[14];
    const float* v2   = (const float*)d_in[15];
    const float* g1   = (const float*)d_in[16];
    const float* g2   = (const float*)d_in[17];
    const float* k_k  = (const float*)d_in[18];
    const float* k_a  = (const float*)d_in[19];
    const float* r_k  = (const float*)d_in[20];
    const float* W_r  = (const float*)d_in[21];
    const float* W_k  = (const float*)d_in[22];
    const float* W_v  = (const float*)d_in[23];
    const float* W_o  = (const float*)d_in[24];
    const float* ln_x_w = (const float*)d_in[25];
    const float* ln_x_b = (const float*)d_in[26];
    const float* ln1_w  = (const float*)d_in[27];
    const float* ln1_b  = (const float*)d_in[28];
    const float* ln2_w  = (const float*)d_in[29];
    const float* ln2_b  = (const float*)d_in[30];
    const float* c_x_k  = (const float*)d_in[31];
    const float* W_ck   = (const float*)d_in[32];
    const float* W_cv   = (const float*)d_in[33];

    const size_t MC = (size_t)MT * CC;
    char* wsb = (char*)d_ws;
    size_t woff = 0;
    auto alloc = [&](size_t bytes) -> void* {
        void* p = wsb + woff;
        woff += (bytes + 255) & ~(size_t)255;
        return p;
    };
    const size_t S_Bcat = (size_t)2624 * 1536;
    const size_t S_Bck  = (size_t)3072 * 1536;
    const size_t S_w2t  = (size_t)768 * 64;
    const size_t S_a2t  = (size_t)768 * 64;
    const size_t S_v2t  = (size_t)768 * 64;   // padded to K=64
    const size_t S_g2t  = (size_t)768 * 128;
    const size_t S_Wo   = (size_t)768 * 768;
    const size_t S_Wcv  = (size_t)768 * 3072;
    bf16* BcatA = (bf16*)alloc(S_Bcat * LAYERS * 2);
    bf16* BckA  = (bf16*)alloc(S_Bck  * LAYERS * 2);
    bf16* w2tA  = (bf16*)alloc(S_w2t  * LAYERS * 2);
    bf16* a2tA  = (bf16*)alloc(S_a2t  * LAYERS * 2);
    bf16* v2tA  = (bf16*)alloc(S_v2t  * LAYERS * 2);
    bf16* g2tA  = (bf16*)alloc(S_g2t  * LAYERS * 2);
    bf16* WoA   = (bf16*)alloc(S_Wo   * LAYERS * 2);
    bf16* WcvA  = (bf16*)alloc(S_Wcv  * LAYERS * 2);
    bf16* A1    = (bf16*)alloc((size_t)MT * 1536 * 2);
    float* rbuf  = (float*)alloc(MC * 4);
    float* kraw  = (float*)alloc(MC * 4);
    float* kupd  = (float*)alloc(MC * 4);
    float* vbuf  = (float*)alloc(MC * 4);
    float* vfirst= (float*)alloc(MC * 4);
    float* abuf  = (float*)alloc(MC * 4);
    float* dbuf  = (float*)alloc(MC * 4);
    float* gbuf  = (float*)alloc(MC * 4);
    bf16* w1o   = (bf16*)alloc((size_t)MT * 64 * 2);
    bf16* a1o   = (bf16*)alloc((size_t)MT * 64 * 2);
    bf16* v1o   = (bf16*)alloc((size_t)MT * 64 * 2);
    bf16* g1o   = (bf16*)alloc((size_t)MT * 128 * 2);
    bf16* hbuf  = (bf16*)alloc((size_t)MT * FF * 2);
    bf16* ghout = (bf16*)alloc(MC * 2);
    float* yintraW = (float*)alloc((size_t)BH * NC * LCH * 64 * 4);
    float* zrW     = (float*)alloc((size_t)BH * NC * LCH * 64 * 4);
    __bf16* mtHiW  = (__bf16*)alloc((size_t)BH * NC * 4096 * 2);
    __bf16* mtLoW  = (__bf16*)alloc((size_t)BH * NC * 4096 * 2);
    float* zcW     = (float*)alloc((size_t)BH * NC * 4096 * 4);
    float* schkW   = (float*)alloc((size_t)BH * NC * 4096 * 4);
    if (woff > ws_size) return;

    float* xcur = (float*)d_out;
    copy_f<<<MC / 256, 256, 0, stream>>>(xcur, x);

    // ---- convert ALL layers' weights in one launch (float4 loads, dual-half writes) ----
    CArgs ca;
    ca.e[0]  = {W_r,  x_r,  BcatA,                    768, 768, 768, 1536, 0, 589824, (int)S_Bcat};
    ca.e[1]  = {W_k,  x_k,  BcatA + (size_t)768  * 1536, 768, 768, 768, 1536, 0, 589824, (int)S_Bcat};
    ca.e[2]  = {W_v,  x_v,  BcatA + (size_t)1536 * 1536, 768, 768, 768, 1536, 0, 589824, (int)S_Bcat};
    ca.e[3]  = {w1,   x_w,  BcatA + (size_t)2304 * 1536, 768, 64, 64, 1536, 0, 49152, (int)S_Bcat};
    ca.e[4]  = {a1,   x_a,  BcatA + (size_t)2368 * 1536, 768, 64, 64, 1536, 0, 49152, (int)S_Bcat};
    ca.e[5]  = {g1,   x_g,  BcatA + (size_t)2432 * 1536, 768, 128, 128, 1536, 0, 98304, (int)S_Bcat};
    ca.e[6]  = {v1,   x_v,  BcatA + (size_t)2560 * 1536, 768, 32, 64, 1536, 0, 24576, (int)S_Bcat};
    ca.e[7]  = {W_ck, c_x_k, BckA, 768, 3072, 3072, 1536, 0, 2359296, (int)S_Bck};
    ca.e[8]  = {w2,   nullptr, w2tA,   64, 768, 768, 64, 0, 49152, (int)S_w2t};
    ca.e[9]  = {a2,   nullptr, a2tA,   64, 768, 768, 64, 0, 49152, (int)S_a2t};
    ca.e[10] = {v2,   nullptr, v2tA,   32, 768, 768, 64, 0, 24576, (int)S_v2t};
    ca.e[11] = {g2,   nullptr, g2tA,  128, 768, 768, 128, 0, 98304, (int)S_g2t};
    ca.e[12] = {W_o,  nullptr, WoA,  768, 768, 768, 768, 0, 589824, (int)S_Wo};
    ca.e[13] = {W_cv, nullptr, WcvA, 3072, 768, 768, 3072, 0, 2359296, (int)S_Wcv};
    int btot = 0;
    for (int i = 0; i < 14; ++i) {
        ca.e[i].bstart = btot;
        int kblocks = ((ca.e[i].mix ? ca.e[i].Ksrc : ca.e[i].Kdst) + 63) >> 6;
        btot += (ca.e[i].Npad >> 5) * kblocks;
    }
    convert_weights<<<dim3(btot, LAYERS), 256, 0, stream>>>(ca);

    for (int l = 0; l < LAYERS; ++l) {
        size_t oC = (size_t)l * CC;
        float* vptr = (l == 0) ? vfirst : vbuf;
        const __bf16* Bcat  = (const __bf16*)(BcatA + (size_t)l * S_Bcat);
        const __bf16* Bck   = (const __bf16*)(BckA  + (size_t)l * S_Bck);
        const __bf16* w2t   = (const __bf16*)(w2tA  + (size_t)l * S_w2t);
        const __bf16* a2t   = (const __bf16*)(a2tA  + (size_t)l * S_a2t);
        const __bf16* v2t   = (const __bf16*)(v2tA  + (size_t)l * S_v2t);
        const __bf16* g2t   = (const __bf16*)(g2tA  + (size_t)l * S_g2t);
        const __bf16* Wo_t  = (const __bf16*)(WoA   + (size_t)l * S_Wo);
        const __bf16* Wcv_t = (const __bf16*)(WcvA  + (size_t)l * S_Wcv);

        // ---- time mix ----
        ln_shift_kernel<<<MT, 256, 0, stream>>>(xcur, ln1_w + oC, ln1_b + oC, A1);

        EpiArgs e1;
        e1.g[0] = {rbuf,  nullptr, nullptr, nullptr, 0, 768, 768};
        e1.g[1] = {kraw,  nullptr, nullptr, nullptr, 0, 768, 768};
        e1.g[2] = {vptr,  nullptr, nullptr, nullptr, 0, 768, 768};
        e1.g[3] = {nullptr, w1o, nullptr, nullptr, 2, 64, 64};
        e1.g[4] = {nullptr, a1o, nullptr, nullptr, 1, 64, 64};
        e1.g[5] = {nullptr, g1o, nullptr, nullptr, 3, 128, 128};
        e1.g[6] = {nullptr, v1o, nullptr, nullptr, 1, 64, 64};
        int nb1[8] = {0, 768, 1536, 2304, 2368, 2432, 2560, 2624};
        for (int i = 0; i < 8; ++i) e1.nb[i] = nb1[i];
        gemm_multi<64, 64><<<dim3(41, 16), 256, 0, stream>>>((const __bf16*)A1, Bcat, 1536, e1);

        G2Args g2a;
        g2a.g[0] = {(const __bf16*)w1o, w2t, dbuf, w0 + oC, nullptr, 64, 6};
        g2a.g[1] = {(const __bf16*)a1o, a2t, abuf, a0 + oC, nullptr, 64, 7};
        g2a.g[2] = {(const __bf16*)g1o, g2t, gbuf, nullptr, nullptr, 128, 0};
        g2a.g[3] = {(const __bf16*)v1o, v2t, vbuf, v0 + oC, vfirst, 64, 8};
        gemm_g2<128, 64><<<dim3(12, 8, (l == 0) ? 3 : 4), 256, 0, stream>>>(g2a);

        // ---- chunked scan ----
        chunkA_kernel<<<dim3(NC, BH), 256, 0, stream>>>(rbuf, dbuf, kraw, abuf, vptr,
                                                        k_k + oC, k_a + oC, kupd,
                                                        yintraW, zrW, mtHiW, mtLoW, zcW);
        chunkB1_kernel<<<BH, 256, 0, stream>>>(zcW, mtHiW, mtLoW, schkW);
        chunkY_kernel<<<dim3(NC, BH), 256, 0, stream>>>(yintraW, zrW, schkW,
                                                        rbuf, kupd, vptr, gbuf,
                                                        r_k + (size_t)l * 768,
                                                        ln_x_w + oC, ln_x_b + oC, ghout);

        EpiArgs eo;
        eo.g[0] = {xcur, nullptr, nullptr, nullptr, 5, 768, 768};
        eo.nb[0] = 0; for (int i = 1; i < 8; ++i) eo.nb[i] = 1 << 30;
        eo.nb[1] = 768;
        gemm_multi<64, 64><<<dim3(12, 16), 256, 0, stream>>>((const __bf16*)ghout, Wo_t, 768, eo);

        // ---- channel mix ----
        ln_shift_kernel<<<MT, 256, 0, stream>>>(xcur, ln2_w + oC, ln2_b + oC, A1);

        EpiArgs ec;
        ec.g[0] = {nullptr, hbuf, nullptr, nullptr, 4, 3072, 3072};
        ec.nb[0] = 0; for (int i = 1; i < 8; ++i) ec.nb[i] = 1 << 30;
        ec.nb[1] = 3072;
        gemm_multi<64, 64><<<dim3(48, 16), 256, 0, stream>>>((const __bf16*)A1, Bck, 1536, ec);

        EpiArgs ev;
        ev.g[0] = {xcur, nullptr, nullptr, nullptr, 5, 768, 768};
        ev.nb[0] = 0; for (int i = 1; i < 8; ++i) ev.nb[i] = 1 << 30;
        ev.nb[1] = 768;
        gemm_multi<64, 64><<<dim3(12, 16), 256, 0, stream>>>((const __bf16*)hbuf, Wcv_t, 3072, ev);
    }
}

// Round 14
// 1283.532 us; speedup vs baseline: 1.3587x; 1.0037x over previous
//
#include <hip/hip_runtime.h>
#include <hip/hip_bf16.h>
#include <math.h>

#define LAYERS 6
#define BBATCH 2
#define TT 512
#define CC 768
#define HH 12
#define MT (BBATCH*TT)      // 1024 tokens
#define FF (4*CC)           // 3072
#define LCH 32
#define NC (TT/LCH)         // 16 chunks
#define BH (BBATCH*HH)      // 24
#define SPAD 65

typedef __hip_bfloat16 bf16;
typedef __bf16 bf16x8 __attribute__((ext_vector_type(8)));
typedef __bf16 bf16x4 __attribute__((ext_vector_type(4)));
typedef float f32x4 __attribute__((ext_vector_type(4)));

__device__ inline bf16 f2b(float f) { return __float2bfloat16(f); }
__device__ inline __bf16 f2bb(float f) {
    __hip_bfloat16 h = __float2bfloat16(f);
    return __builtin_bit_cast(__bf16, h);
}
__device__ inline float bb2f(__bf16 h) {
    return __bfloat162float(__builtin_bit_cast(__hip_bfloat16, h));
}

// ---------------- utility ----------------

__global__ __launch_bounds__(256) void copy_f(float* __restrict__ dst, const float* __restrict__ src) {
    size_t i = (size_t)blockIdx.x * 256 + threadIdx.x;
    dst[i] = src[i];
}

// ---------------- fused layernorm + token-shift-diff, bf16 concat output ----------------

__global__ __launch_bounds__(256) void ln_shift_kernel(const float* __restrict__ x,
                                                       const float* __restrict__ w,
                                                       const float* __restrict__ b,
                                                       bf16* __restrict__ out) {
    int row = blockIdx.x;
    int t = row % TT;
    const float* xr = x + (size_t)row * CC;
    const float* xp = xr - CC;
    int tid = threadIdx.x;
    float c0 = xr[tid], c1 = xr[tid + 256], c2 = xr[tid + 512];
    float p0 = 0.f, p1 = 0.f, p2 = 0.f;
    if (t > 0) { p0 = xp[tid]; p1 = xp[tid + 256]; p2 = xp[tid + 512]; }
    float s  = c0 + c1 + c2, q  = c0 * c0 + c1 * c1 + c2 * c2;
    float sp = p0 + p1 + p2, qp = p0 * p0 + p1 * p1 + p2 * p2;
    for (int m = 1; m < 64; m <<= 1) {
        s += __shfl_xor(s, m); q += __shfl_xor(q, m);
        sp += __shfl_xor(sp, m); qp += __shfl_xor(qp, m);
    }
    __shared__ float rs[4], rq[4], rsp[4], rqp[4];
    int wid = tid >> 6;
    if ((tid & 63) == 0) { rs[wid] = s; rq[wid] = q; rsp[wid] = sp; rqp[wid] = qp; }
    __syncthreads();
    s  = rs[0] + rs[1] + rs[2] + rs[3];   q  = rq[0] + rq[1] + rq[2] + rq[3];
    sp = rsp[0] + rsp[1] + rsp[2] + rsp[3]; qp = rqp[0] + rqp[1] + rqp[2] + rqp[3];
    float meanC = s * (1.f / CC);
    float invC  = rsqrtf(q * (1.f / CC) - meanC * meanC + 1e-5f);
    float meanP = sp * (1.f / CC);
    float invP  = rsqrtf(qp * (1.f / CC) - meanP * meanP + 1e-5f);
    bf16* orow = out + (size_t)row * 1536;
    float cv[3] = {c0, c1, c2};
    float pv[3] = {p0, p1, p2};
#pragma unroll
    for (int j = 0; j < 3; ++j) {
        int cc = tid + j * 256;
        float lnc = (cv[j] - meanC) * invC * w[cc] + b[cc];
        float lnp = (t > 0) ? (pv[j] - meanP) * invP * w[cc] + b[cc] : 0.f;
        orow[cc] = f2b(lnc);
        orow[768 + cc] = f2b(lnp - lnc);
    }
}

// ---------------- weight convert: ALL LAYERS, float4 loads, dual-half writes ----------------

struct CEntry { const float* W; const float* mix; bf16* dst;
                int Ksrc, Nsrc, Npad, Kdst, bstart, wstr, dstr; };
struct CArgs { CEntry e[14]; };

__global__ __launch_bounds__(256) void convert_weights(CArgs ca) {
    int bid = blockIdx.x;
    int l = blockIdx.y;
    int idx = 0;
#pragma unroll
    for (int i = 1; i < 14; ++i) if (bid >= ca.e[i].bstart) idx = i;
    CEntry E = ca.e[idx];
    const float* Wsrc = E.W + (size_t)l * E.wstr;
    __bf16* d = (__bf16*)(E.dst + (size_t)l * E.dstr);
    int t = bid - E.bstart;
    int ntN = E.Npad >> 5;
    int tn = (t % ntN) * 32;
    int tk = (t / ntN) * 64;
    __shared__ float tile[64][33];
    int tid = threadIdx.x;
    const float* mixl = E.mix ? (E.mix + (size_t)l * CC) : nullptr;
#pragma unroll
    for (int i = 0; i < 2; ++i) {
        int r = (tid >> 3) + 32 * i;
        int c4 = (tid & 7) * 4;
        int kk = tk + r;
        f32x4 v = (f32x4){0.f, 0.f, 0.f, 0.f};
        if (kk < E.Ksrc && tn + c4 < E.Nsrc)
            v = *(const f32x4*)(Wsrc + (size_t)kk * E.Nsrc + tn + c4);
        tile[r][c4 + 0] = v[0];
        tile[r][c4 + 1] = v[1];
        tile[r][c4 + 2] = v[2];
        tile[r][c4 + 3] = v[3];
    }
    __syncthreads();
    int n2 = tid >> 3, slot = tid & 7;
    bf16x8 h8;
#pragma unroll
    for (int e = 0; e < 8; ++e) h8[e] = f2bb(tile[slot * 8 + e][n2]);
    *(bf16x8*)(d + (size_t)(tn + n2) * E.Kdst + tk + slot * 8) = h8;
    if (mixl) {
        bf16x8 h8m;
#pragma unroll
        for (int e = 0; e < 8; ++e)
            h8m[e] = f2bb(tile[slot * 8 + e][n2] * mixl[tk + slot * 8 + e]);
        *(bf16x8*)(d + (size_t)(tn + n2) * E.Kdst + E.Ksrc + tk + slot * 8) = h8m;
    }
}

// ---------------- epilogues ----------------

struct EpiG {
    float* outF; bf16* outH;
    const float* p1; const float* p2;
    int epi, ld, ntrue;
};
struct EpiArgs { EpiG g[7]; int nb[8]; };

__device__ inline void epi_store(const EpiG& E, size_t idx, int lc, float v) {
    switch (E.epi) {
        case 0: E.outF[idx] = v; break;
        case 1: E.outH[idx] = f2b(v); break;
        case 2: E.outH[idx] = f2b(tanhf(v)); break;
        case 3: E.outH[idx] = f2b(1.f / (1.f + expf(-v))); break;
        case 4: { float t = fmaxf(v, 0.f); E.outH[idx] = f2b(t * t); } break;
        case 5: E.outF[idx] += v; break;
        case 6: { float z = E.p1[lc] + v; float nz = -z;
                  float sp = (nz > 20.f) ? nz : log1pf(expf(nz));
                  E.outF[idx] = expf(-expf(-sp - 0.5f)); } break;
        case 7: E.outF[idx] = 1.f / (1.f + expf(-(E.p1[lc] + v))); break;
        case 8: { float vv = E.outF[idx];
                  float s = 1.f / (1.f + expf(-(E.p1[lc] + v)));
                  E.outF[idx] = vv + (E.p2[idx] - vv) * s; } break;
    }
}

// ---------------- bf16 MFMA GEMM, BK=64, XCD-swizzled, grouped-column epilogue ----------------

template<int BM, int BN>
__global__ __launch_bounds__(256) void gemm_multi(const __bf16* __restrict__ A,
                                                  const __bf16* __restrict__ Bt,
                                                  int K, EpiArgs ea) {
    constexpr int FM = (BM + 31) / 32, FN = BN / 32;
    constexpr int ABYTES = BM * 128;
    constexpr int TOT = (BM + BN) * 128;
    constexpr int NCHUNK = TOT / 4096;
    __shared__ __align__(16) char smem[2][TOT];
    int tid = threadIdx.x;
    int lane = tid & 63, wid = tid >> 6;
    int nwg = gridDim.x * gridDim.y;
    int orig = blockIdx.y * gridDim.x + blockIdx.x;
    int qq = nwg >> 3, rr = nwg & 7, xc = orig & 7, oo = orig >> 3;
    int swz = (xc < rr ? xc * (qq + 1) : rr * (qq + 1) + (xc - rr) * qq) + oo;
    int bn = (swz % gridDim.x) * BN, bm = (swz / gridDim.x) * BM;
    int wm = (wid >> 1) * (BM / 2), wn = (wid & 1) * (BN / 2);
    f32x4 acc[FM][FN];
#pragma unroll
    for (int i = 0; i < FM; ++i)
#pragma unroll
        for (int j = 0; j < FN; ++j) acc[i][j] = (f32x4){0.f, 0.f, 0.f, 0.f};

    int nk = K >> 6;
    auto stage = [&](int buf, int k0) {
        char* sb = &smem[buf][0];
#pragma unroll
        for (int c = 0; c < NCHUNK; ++c) {
            int d = c * 4096 + tid * 16;
            int isB = d >= ABYTES;
            int dd = isB ? d - ABYTES : d;
            int row = dd >> 7;
            int slot = (dd >> 4) & 7;
            int su = slot ^ (row & 7);
            const __bf16* src = isB ? (Bt + (size_t)(bn + row) * K + k0 + su * 8)
                                    : (A  + (size_t)(bm + row) * K + k0 + su * 8);
            char* ldst = sb + c * 4096 + (tid & 192) * 16;
            __builtin_amdgcn_global_load_lds(
                (const __attribute__((address_space(1))) unsigned int*)src,
                (__attribute__((address_space(3))) unsigned int*)ldst, 16, 0, 0);
        }
    };

    stage(0, 0);
    __syncthreads();
    for (int t = 0; t < nk; ++t) {
        if (t + 1 < nk) stage((t + 1) & 1, (t + 1) * 64);
        const char* sA = &smem[t & 1][0];
        const char* sB = &smem[t & 1][ABYTES];
        int u = lane >> 4, r0 = lane & 15;
        bf16x8 af[2][FM], bfr[2][FN];
#pragma unroll
        for (int ks = 0; ks < 2; ++ks) {
#pragma unroll
            for (int i = 0; i < FM; ++i) {
                int row = wm + i * 16 + r0;
                int slot = (ks * 4 + u) ^ (row & 7);
                af[ks][i] = *(const bf16x8*)(sA + row * 128 + slot * 16);
            }
#pragma unroll
            for (int j = 0; j < FN; ++j) {
                int row = wn + j * 16 + r0;
                int slot = (ks * 4 + u) ^ (row & 7);
                bfr[ks][j] = *(const bf16x8*)(sB + row * 128 + slot * 16);
            }
        }
#pragma unroll
        for (int ks = 0; ks < 2; ++ks)
#pragma unroll
            for (int i = 0; i < FM; ++i)
#pragma unroll
                for (int j = 0; j < FN; ++j)
                    acc[i][j] = __builtin_amdgcn_mfma_f32_16x16x32_bf16(af[ks][i], bfr[ks][j], acc[i][j], 0, 0, 0);
        __syncthreads();
    }

    int gid = 0;
#pragma unroll 1
    while (bn >= ea.nb[gid + 1]) ++gid;
    EpiG E = ea.g[gid];
    int colBase = ea.nb[gid];
#pragma unroll
    for (int i = 0; i < FM; ++i) {
#pragma unroll
        for (int j = 0; j < FN; ++j) {
#pragma unroll
            for (int q = 0; q < 4; ++q) {
                int gm = bm + wm + i * 16 + (lane >> 4) * 4 + q;
                int lc = bn + wn + j * 16 + (lane & 15) - colBase;
                if (lc < E.ntrue)
                    epi_store(E, (size_t)gm * E.ld + lc, lc, acc[i][j][q]);
            }
        }
    }
}

// ---------------- grouped low-rank GEMM (BK=32; 2-way swizzle) ----------------

struct G2G { const __bf16* A; const __bf16* Bt; float* outF; const float* p1; const float* p2; int K; int epi; };
struct G2Args { G2G g[4]; };

template<int BM, int BN>
__global__ __launch_bounds__(256) void gemm_g2(G2Args ga) {
    G2G G = ga.g[blockIdx.z];
    const __bf16* A = G.A;
    const __bf16* Bt = G.Bt;
    int K = G.K;
    constexpr int FM = BM / 32, FN = BN / 32;
    constexpr int ABYTES = BM * 64;
    constexpr int TOT = (BM + BN) * 64;
    constexpr int NCHUNK = TOT / 4096;
    __shared__ __align__(16) char smem[2][TOT];
    int tid = threadIdx.x;
    int lane = tid & 63, wid = tid >> 6;
    int bm = blockIdx.y * BM, bn = blockIdx.x * BN;
    int wm = (wid >> 1) * (BM / 2), wn = (wid & 1) * (BN / 2);
    f32x4 acc[FM][FN];
#pragma unroll
    for (int i = 0; i < FM; ++i)
#pragma unroll
        for (int j = 0; j < FN; ++j) acc[i][j] = (f32x4){0.f, 0.f, 0.f, 0.f};

    int nk = K >> 5;
    auto stage = [&](int buf, int k0) {
        char* sb = &smem[buf][0];
#pragma unroll
        for (int c = 0; c < NCHUNK; ++c) {
            int d = c * 4096 + tid * 16;
            int isB = d >= ABYTES;
            int dd = isB ? d - ABYTES : d;
            int row = dd >> 6;
            int u = (dd >> 4) & 3;
            int su = u ^ ((row >> 1) & 3);
            const __bf16* src = isB ? (Bt + (size_t)(bn + row) * K + k0 + su * 8)
                                    : (A  + (size_t)(bm + row) * K + k0 + su * 8);
            char* ldst = sb + c * 4096 + (tid & 192) * 16;
            __builtin_amdgcn_global_load_lds(
                (const __attribute__((address_space(1))) unsigned int*)src,
                (__attribute__((address_space(3))) unsigned int*)ldst, 16, 0, 0);
        }
    };

    stage(0, 0);
    __syncthreads();
    for (int t = 0; t < nk; ++t) {
        if (t + 1 < nk) stage((t + 1) & 1, (t + 1) * 32);
        const char* sA = &smem[t & 1][0];
        const char* sB = &smem[t & 1][ABYTES];
        int u = lane >> 4, r0 = lane & 15;
        bf16x8 af[FM], bfr[FN];
#pragma unroll
        for (int i = 0; i < FM; ++i) {
            int row = wm + i * 16 + r0;
            int su = u ^ ((row >> 1) & 3);
            af[i] = *(const bf16x8*)(sA + row * 64 + su * 16);
        }
#pragma unroll
        for (int j = 0; j < FN; ++j) {
            int row = wn + j * 16 + r0;
            int su = u ^ ((row >> 1) & 3);
            bfr[j] = *(const bf16x8*)(sB + row * 64 + su * 16);
        }
#pragma unroll
        for (int i = 0; i < FM; ++i)
#pragma unroll
            for (int j = 0; j < FN; ++j)
                acc[i][j] = __builtin_amdgcn_mfma_f32_16x16x32_bf16(af[i], bfr[j], acc[i][j], 0, 0, 0);
        __syncthreads();
    }

    EpiG E;
    E.outF = G.outF; E.outH = nullptr; E.p1 = G.p1; E.p2 = G.p2;
    E.epi = G.epi; E.ld = 768; E.ntrue = 768;
#pragma unroll
    for (int i = 0; i < FM; ++i) {
#pragma unroll
        for (int j = 0; j < FN; ++j) {
#pragma unroll
            for (int q = 0; q < 4; ++q) {
                int gm = bm + wm + i * 16 + (lane >> 4) * 4 + q;
                int lc = bn + wn + j * 16 + (lane & 15);
                epi_store(E, (size_t)gm * 768 + lc, lc, acc[i][j][q]);
            }
        }
    }
}

// ---------------- chunked WKV7, phase A (register-tiled; M out as transposed bf16 pair) ----------------

__global__ __launch_bounds__(256) void chunkA_kernel(
    const float* __restrict__ r, const float* __restrict__ wd,
    const float* __restrict__ kraw, const float* __restrict__ av_,
    const float* __restrict__ v,
    const float* __restrict__ kkw, const float* __restrict__ kaw,
    float* __restrict__ kupd,
    float* __restrict__ yintra, float* __restrict__ zrO,
    __bf16* __restrict__ mtHi, __bf16* __restrict__ mtLo,
    float* __restrict__ zcO) {
    int c = blockIdx.x, bh = blockIdx.y;
    int b = bh / HH, h = bh % HH;
    __shared__ float Di[LCH][SPAD];
    __shared__ float Ah[LCH][SPAD];
    __shared__ float Bh[LCH][SPAD];
    __shared__ float Kh[LCH][SPAD];
    __shared__ float Rh[LCH][SPAD];
    __shared__ float Vt[LCH][SPAD];
    __shared__ float Qm[LCH][SPAD];
    __shared__ float Gba[LCH][LCH], Gka[LCH][LCH], Grb[LCH][LCH], Grk[LCH][LCH];
    int tid = threadIdx.x;
    int n = tid & 63, tq = tid >> 6;
    size_t base = ((size_t)(b * TT + c * LCH)) * CC + h * 64 + n;
    int cvec = h * 64 + n;
    float kkwv = kkw[cvec], kawv = kaw[cvec];
#pragma unroll
    for (int e = 0; e < 8; ++e) {
        int t = tq * 8 + e;
        size_t off = base + (size_t)t * CC;
        float kr = kraw[off];
        float aval = av_[off];
        float kk0 = kr * kkwv;
        float ss = kk0 * kk0;
        for (int m = 1; m < 64; m <<= 1) ss += __shfl_xor(ss, m);
        float rinv = 1.f / fmaxf(sqrtf(ss), 1e-12f);
        float kkv = kk0 * rinv;
        float ku = kr * (1.f + (aval - 1.f) * kawv);
        kupd[off] = ku;
        Di[t][n] = wd[off];
        Ah[t][n] = -kkv;
        Bh[t][n] = kkv * aval;
        Kh[t][n] = ku;
        Rh[t][n] = r[off];
        Vt[t][n] = v[off];
    }
    __syncthreads();
    if (tid < 64) {
        float d = 1.f;
        for (int t = 0; t < LCH; ++t) { d *= Di[t][tid]; Di[t][tid] = d; }
    }
    __syncthreads();
#pragma unroll
    for (int e = 0; e < 8; ++e) {
        int t = tq * 8 + e;
        float di = Di[t][n];
        float dp = (t == 0) ? 1.f : Di[t - 1][n];
        float inv = 1.f / di;
        Ah[t][n] *= dp;
        Bh[t][n] *= inv;
        Kh[t][n] *= inv;
        Rh[t][n] *= di;
    }
    __syncthreads();
    // ---- G phase: 2x2 (t,s) tiles ----
    {
        int tp = tid >> 4, sp = tid & 15;
        int t0 = 2 * tp, s0 = 2 * sp;
        float gba00 = 0.f, gba01 = 0.f, gba10 = 0.f, gba11 = 0.f;
        float gka00 = 0.f, gka01 = 0.f, gka10 = 0.f, gka11 = 0.f;
        float grb00 = 0.f, grb01 = 0.f, grb10 = 0.f, grb11 = 0.f;
        float grk00 = 0.f, grk01 = 0.f, grk10 = 0.f, grk11 = 0.f;
#pragma unroll 4
        for (int j = 0; j < 64; ++j) {
            float a0 = Ah[t0][j], a1 = Ah[t0 + 1][j];
            float r0 = Rh[t0][j], r1 = Rh[t0 + 1][j];
            float b0 = Bh[s0][j], b1 = Bh[s0 + 1][j];
            float k0 = Kh[s0][j], k1 = Kh[s0 + 1][j];
            gba00 = fmaf(a0, b0, gba00); gba01 = fmaf(a0, b1, gba01);
            gba10 = fmaf(a1, b0, gba10); gba11 = fmaf(a1, b1, gba11);
            gka00 = fmaf(a0, k0, gka00); gka01 = fmaf(a0, k1, gka01);
            gka10 = fmaf(a1, k0, gka10); gka11 = fmaf(a1, k1, gka11);
            grb00 = fmaf(r0, b0, grb00); grb01 = fmaf(r0, b1, grb01);
            grb10 = fmaf(r1, b0, grb10); grb11 = fmaf(r1, b1, grb11);
            grk00 = fmaf(r0, k0, grk00); grk01 = fmaf(r0, k1, grk01);
            grk10 = fmaf(r1, k0, grk10); grk11 = fmaf(r1, k1, grk11);
        }
#pragma unroll
        for (int dt = 0; dt < 2; ++dt) {
            int t = t0 + dt;
#pragma unroll
            for (int ds = 0; ds < 2; ++ds) {
                int s = s0 + ds;
                float vba = dt ? (ds ? gba11 : gba10) : (ds ? gba01 : gba00);
                float vka = dt ? (ds ? gka11 : gka10) : (ds ? gka01 : gka00);
                float vrb = dt ? (ds ? grb11 : grb10) : (ds ? grb01 : grb00);
                float vrk = dt ? (ds ? grk11 : grk10) : (ds ? grk01 : grk00);
                Gba[t][s] = (s < t)  ? vba : 0.f;
                Gka[t][s] = (s < t)  ? vka : 0.f;
                Grb[t][s] = (s <= t) ? vrb : 0.f;
                Grk[t][s] = (s <= t) ? vrk : 0.f;
            }
        }
    }
    __syncthreads();
    // ---- Qm = Gka V (s-outer) ----
    {
        float acc[8];
#pragma unroll
        for (int e = 0; e < 8; ++e) acc[e] = 0.f;
        for (int s = 0; s < LCH; ++s) {
            float vs = Vt[s][n];
#pragma unroll
            for (int e = 0; e < 8; ++e)
                acc[e] = fmaf(Gka[tq * 8 + e][s], vs, acc[e]);
        }
#pragma unroll
        for (int e = 0; e < 8; ++e) Qm[tq * 8 + e][n] = acc[e];
    }
    __syncthreads();
    // ---- forward substitution ----
    if (tq == 0) {
        for (int t = 1; t < LCH; ++t) {
            float acc = Ah[t][n];
            for (int s = 0; s < t; ++s) acc = fmaf(Gba[t][s], Ah[s][n], acc);
            Ah[t][n] = acc;
        }
    } else if (tq == 1) {
        for (int t = 1; t < LCH; ++t) {
            float acc = Qm[t][n];
            for (int s = 0; s < t; ++s) acc = fmaf(Gba[t][s], Qm[s][n], acc);
            Qm[t][n] = acc;
        }
    }
    __syncthreads();
    size_t obase = ((size_t)(bh * NC + c)) * LCH * 64;
    // ---- yintra / zr (s-outer) ----
    {
        float accY[8], accZ[8];
#pragma unroll
        for (int e = 0; e < 8; ++e) { accY[e] = 0.f; accZ[e] = Rh[tq * 8 + e][n]; }
        for (int s = 0; s < LCH; ++s) {
            float vs = Vt[s][n], qs = Qm[s][n], us = Ah[s][n];
#pragma unroll
            for (int e = 0; e < 8; ++e) {
                int t = tq * 8 + e;
                float grk_ = Grk[t][s], grb_ = Grb[t][s];
                accY[e] = fmaf(grk_, vs, fmaf(grb_, qs, accY[e]));
                accZ[e] = fmaf(grb_, us, accZ[e]);
            }
        }
#pragma unroll
        for (int e = 0; e < 8; ++e) {
            int t = tq * 8 + e;
            yintra[obase + t * 64 + n] = accY[e];
            zrO[obase + t * 64 + n] = accZ[e];
        }
    }
    // ---- M / Zc (4x4 tiles, s-outer); M stored transposed as bf16 hi/lo pair ----
    {
        int pi = tid >> 4, ni = tid & 15;
        float accM[4][4], accZc[4][4];
#pragma unroll
        for (int dp = 0; dp < 4; ++dp)
#pragma unroll
            for (int dn = 0; dn < 4; ++dn) { accM[dp][dn] = 0.f; accZc[dp][dn] = 0.f; }
        for (int s = 0; s < LCH; ++s) {
            float aa[4], vv[4], qq[4], bb[4], kk[4];
#pragma unroll
            for (int d = 0; d < 4; ++d) {
                aa[d] = Ah[s][4 * pi + d];
                vv[d] = Vt[s][4 * pi + d];
                qq[d] = Qm[s][4 * pi + d];
                bb[d] = Bh[s][4 * ni + d];
                kk[d] = Kh[s][4 * ni + d];
            }
#pragma unroll
            for (int dp = 0; dp < 4; ++dp)
#pragma unroll
                for (int dn = 0; dn < 4; ++dn) {
                    accM[dp][dn]  = fmaf(aa[dp], bb[dn], accM[dp][dn]);
                    accZc[dp][dn] = fmaf(vv[dp], kk[dn], fmaf(qq[dp], bb[dn], accZc[dp][dn]));
                }
        }
        size_t mbase = ((size_t)(bh * NC + c)) * 4096;
        float dl[4];
#pragma unroll
        for (int dn = 0; dn < 4; ++dn) dl[dn] = Di[LCH - 1][4 * ni + dn];
#pragma unroll
        for (int dp = 0; dp < 4; ++dp) {
            int p = 4 * pi + dp;
            f32x4 z4;
#pragma unroll
            for (int dn = 0; dn < 4; ++dn) z4[dn] = dl[dn] * accZc[dp][dn];
            *(f32x4*)(zcO + mbase + p * 64 + 4 * ni) = z4;
        }
#pragma unroll
        for (int dn = 0; dn < 4; ++dn) {
            int nn = 4 * ni + dn;
            float dlv = dl[dn];
            bf16x4 h4, l4;
#pragma unroll
            for (int dp = 0; dp < 4; ++dp) {
                int p = 4 * pi + dp;
                float mm = (accM[dp][dn] + ((p == nn) ? 1.f : 0.f)) * dlv;
                __bf16 hb = f2bb(mm);
                h4[dp] = hb;
                l4[dp] = f2bb(mm - bb2f(hb));
            }
            *(bf16x4*)(mtHi + mbase + (size_t)nn * 64 + 4 * pi) = h4;
            *(bf16x4*)(mtLo + mbase + (size_t)nn * 64 + 4 * pi) = l4;
        }
    }
}

// ---------------- phase B1: sequential state chain via split-precision MFMA ----------------

__global__ __launch_bounds__(256) void chunkB1_kernel(
    const float* __restrict__ zc,
    const __bf16* __restrict__ mtHi,
    const __bf16* __restrict__ mtLo,
    float* __restrict__ schk) {
    int bh = blockIdx.x;
    int tid = threadIdx.x;
    int lane = tid & 63, w = tid >> 6;
    int r0 = lane & 15, u = lane >> 4;
    __shared__ __align__(16) float S[64][68];
    for (int i = tid; i < 64 * 68; i += 256) (&S[0][0])[i] = 0.f;
    const float* zbase = zc + (size_t)bh * NC * 4096;
    const __bf16* hbase = mtHi + (size_t)bh * NC * 4096;
    const __bf16* lbase = mtLo + (size_t)bh * NC * 4096;
    float* sbase = schk + (size_t)bh * NC * 4096;
    int arow = w * 16 + r0;

    bf16x8 mh[2][4][2], ml[2][4][2];
    f32x4 zf[2][4];
#pragma unroll
    for (int ct = 0; ct < 4; ++ct) {
#pragma unroll
        for (int ks = 0; ks < 2; ++ks) {
            size_t mo = (size_t)(ct * 16 + r0) * 64 + ks * 32 + u * 8;
            mh[0][ct][ks] = *(const bf16x8*)(hbase + mo);
            ml[0][ct][ks] = *(const bf16x8*)(lbase + mo);
        }
#pragma unroll
        for (int q = 0; q < 4; ++q)
            zf[0][ct][q] = zbase[(size_t)(w * 16 + u * 4 + q) * 64 + ct * 16 + r0];
    }
    __syncthreads();
#pragma unroll
    for (int c = 0; c < NC - 1; ++c) {
        const int cb = c & 1;          // compile-time after full unroll
        if (c + 1 < NC - 1) {
            const __bf16* hn = hbase + (size_t)(c + 1) * 4096;
            const __bf16* ln = lbase + (size_t)(c + 1) * 4096;
            const float* zn = zbase + (size_t)(c + 1) * 4096;
#pragma unroll
            for (int ct = 0; ct < 4; ++ct) {
#pragma unroll
                for (int ks = 0; ks < 2; ++ks) {
                    size_t mo = (size_t)(ct * 16 + r0) * 64 + ks * 32 + u * 8;
                    mh[cb ^ 1][ct][ks] = *(const bf16x8*)(hn + mo);
                    ml[cb ^ 1][ct][ks] = *(const bf16x8*)(ln + mo);
                }
#pragma unroll
                for (int q = 0; q < 4; ++q)
                    zf[cb ^ 1][ct][q] = zn[(size_t)(w * 16 + u * 4 + q) * 64 + ct * 16 + r0];
            }
        }
        bf16x8 ah[2], al[2];
#pragma unroll
        for (int ks = 0; ks < 2; ++ks) {
            f32x4 s0 = *(const f32x4*)&S[arow][ks * 32 + u * 8];
            f32x4 s1 = *(const f32x4*)&S[arow][ks * 32 + u * 8 + 4];
#pragma unroll
            for (int e = 0; e < 4; ++e) {
                __bf16 h0 = f2bb(s0[e]);
                ah[ks][e] = h0;
                al[ks][e] = f2bb(s0[e] - bb2f(h0));
                __bf16 h1 = f2bb(s1[e]);
                ah[ks][4 + e] = h1;
                al[ks][4 + e] = f2bb(s1[e] - bb2f(h1));
            }
        }
        f32x4 acc[4];
#pragma unroll
        for (int ct = 0; ct < 4; ++ct) {
            acc[ct] = zf[cb][ct];
#pragma unroll
            for (int ks = 0; ks < 2; ++ks) {
                acc[ct] = __builtin_amdgcn_mfma_f32_16x16x32_bf16(ah[ks], mh[cb][ct][ks], acc[ct], 0, 0, 0);
                acc[ct] = __builtin_amdgcn_mfma_f32_16x16x32_bf16(ah[ks], ml[cb][ct][ks], acc[ct], 0, 0, 0);
                acc[ct] = __builtin_amdgcn_mfma_f32_16x16x32_bf16(al[ks], mh[cb][ct][ks], acc[ct], 0, 0, 0);
            }
        }
        __syncthreads();   // all S reads complete
        float* cp = sbase + (size_t)(c + 1) * 4096;
#pragma unroll
        for (int ct = 0; ct < 4; ++ct) {
#pragma unroll
            for (int q = 0; q < 4; ++q) {
                int row = w * 16 + u * 4 + q;
                int col = ct * 16 + r0;
                S[row][col] = acc[ct][q];
                cp[(size_t)row * 64 + col] = acc[ct][q];
            }
        }
        __syncthreads();   // S_new visible before next chunk
    }
}

// ---------------- phase Y (unchanged) ----------------

__global__ __launch_bounds__(256) void chunkY_kernel(
    const float* __restrict__ yintra, const float* __restrict__ zrI,
    const float* __restrict__ schk,
    const float* __restrict__ r, const float* __restrict__ kupd,
    const float* __restrict__ v, const float* __restrict__ g,
    const float* __restrict__ rk, const float* __restrict__ lw,
    const float* __restrict__ lb, bf16* __restrict__ out) {
    int c = blockIdx.x, bh = blockIdx.y;
    int b = bh / HH, h = bh % HH;
    __shared__ float Y[LCH][SPAD];
    __shared__ float Zr[LCH][SPAD];
    __shared__ float Sh[64][SPAD];
    int tid = threadIdx.x;
    int n = tid & 63, tq = tid >> 6;
    size_t obase = ((size_t)(bh * NC + c)) * LCH * 64;
#pragma unroll
    for (int e = 0; e < 8; ++e) {
        int idx = tid + e * 256;
        int row = idx >> 6, col = idx & 63;
        Y[row][col] = yintra[obase + idx];
        Zr[row][col] = zrI[obase + idx];
    }
    if (c > 0) {
        size_t sbase = ((size_t)(bh * NC + c)) * 4096;
#pragma unroll
        for (int e = 0; e < 16; ++e) {
            int idx = tid + e * 256;
            Sh[idx >> 6][idx & 63] = schk[sbase + idx];
        }
    }
    __syncthreads();
    if (c > 0) {
        float acc[8];
#pragma unroll
        for (int e = 0; e < 8; ++e) acc[e] = 0.f;
        for (int p = 0; p < 64; ++p) {
            float sv = Sh[n][p];
#pragma unroll
            for (int e = 0; e < 8; ++e)
                acc[e] = fmaf(Zr[tq * 8 + e][p], sv, acc[e]);
        }
#pragma unroll
        for (int e = 0; e < 8; ++e) Y[tq * 8 + e][n] += acc[e];
    }
    size_t rowbase = ((size_t)(b * TT + c * LCH)) * CC + h * 64 + n;
    float rkv = rk[h * 64 + n];
    float lwv = lw[h * 64 + n], lbv = lb[h * 64 + n];
#pragma unroll
    for (int e = 0; e < 8; ++e) {
        int t = tq * 8 + e;
        size_t off = rowbase + (size_t)t * CC;
        float yv = Y[t][n];
        float rv = r[off], kv = kupd[off], vv = v[off];
        float s1 = yv, s2 = yv * yv, s3 = rv * kv * rkv;
        for (int m = 1; m < 64; m <<= 1) {
            s1 += __shfl_xor(s1, m);
            s2 += __shfl_xor(s2, m);
            s3 += __shfl_xor(s3, m);
        }
        float mean = s1 * (1.f / 64.f);
        float var  = s2 * (1.f / 64.f) - mean * mean;
        float inv  = rsqrtf(var + 64e-5f);
        float val  = (yv - mean) * inv * lwv + lbv + s3 * vv;
        out[off] = f2b(val * g[off]);
    }
}

// ---------------- host ----------------

extern "C" void kernel_launch(void* const* d_in, const int* in_sizes, int n_in,
                              void* d_out, int out_size, void* d_ws, size_t ws_size,
                              hipStream_t stream) {
    (void)in_sizes; (void)n_in; (void)out_size;
    const float* x    = (const float*)d_in[0];
    const float* x_r  = (const float*)d_in[1];
    const float* x_w  = (const float*)d_in[2];
    const float* x_k  = (const float*)d_in[3];
    const float* x_v  = (const float*)d_in[4];
    const float* x_a  = (const float*)d_in[5];
    const float* x_g  = (const float*)d_in[6];
    const float* w0   = (const float*)d_in[7];
    const float* w1   = (const float*)d_in[8];
    const float* w2   = (const float*)d_in[9];
    const float* a0   = (const float*)d_in[10];
    const float* a1   = (const float*)d_in[11];
    const float* a2   = (const float*)d_in[12];
    const float* v0   = (const float*)d_in[13];
    const float* v1   = (const float*)d_in[14];
    const float* v2   = (const float*)d_in[15];
    const float* g1   = (const float*)d_in[16];
    const float* g2   = (const float*)d_in[17];
    const float* k_k  = (const float*)d_in[18];
    const float* k_a  = (const float*)d_in[19];
    const float* r_k  = (const float*)d_in[20];
    const float* W_r  = (const float*)d_in[21];
    const float* W_k  = (const float*)d_in[22];
    const float* W_v  = (const float*)d_in[23];
    const float* W_o  = (const float*)d_in[24];
    const float* ln_x_w = (const float*)d_in[25];
    const float* ln_x_b = (const float*)d_in[26];
    const float* ln1_w  = (const float*)d_in[27];
    const float* ln1_b  = (const float*)d_in[28];
    const float* ln2_w  = (const float*)d_in[29];
    const float* ln2_b  = (const float*)d_in[30];
    const float* c_x_k  = (const float*)d_in[31];
    const float* W_ck   = (const float*)d_in[32];
    const float* W_cv   = (const float*)d_in[33];

    const size_t MC = (size_t)MT * CC;
    char* wsb = (char*)d_ws;
    size_t woff = 0;
    auto alloc = [&](size_t bytes) -> void* {
        void* p = wsb + woff;
        woff += (bytes + 255) & ~(size_t)255;
        return p;
    };
    const size_t S_Bcat = (size_t)2624 * 1536;
    const size_t S_Bck  = (size_t)3072 * 1536;
    const size_t S_w2t  = (size_t)768 * 64;
    const size_t S_a2t  = (size_t)768 * 64;
    const size_t S_v2t  = (size_t)768 * 64;   // padded to K=64
    const size_t S_g2t  = (size_t)768 * 128;
    const size_t S_Wo   = (size_t)768 * 768;
    const size_t S_Wcv  = (size_t)768 * 3072;
    bf16* BcatA = (bf16*)alloc(S_Bcat * LAYERS * 2);
    bf16* BckA  = (bf16*)alloc(S_Bck  * LAYERS * 2);
    bf16* w2tA  = (bf16*)alloc(S_w2t  * LAYERS * 2);
    bf16* a2tA  = (bf16*)alloc(S_a2t  * LAYERS * 2);
    bf16* v2tA  = (bf16*)alloc(S_v2t  * LAYERS * 2);
    bf16* g2tA  = (bf16*)alloc(S_g2t  * LAYERS * 2);
    bf16* WoA   = (bf16*)alloc(S_Wo   * LAYERS * 2);
    bf16* WcvA  = (bf16*)alloc(S_Wcv  * LAYERS * 2);
    bf16* A1    = (bf16*)alloc((size_t)MT * 1536 * 2);
    float* rbuf  = (float*)alloc(MC * 4);
    float* kraw  = (float*)alloc(MC * 4);
    float* kupd  = (float*)alloc(MC * 4);
    float* vbuf  = (float*)alloc(MC * 4);
    float* vfirst= (float*)alloc(MC * 4);
    float* abuf  = (float*)alloc(MC * 4);
    float* dbuf  = (float*)alloc(MC * 4);
    float* gbuf  = (float*)alloc(MC * 4);
    bf16* w1o   = (bf16*)alloc((size_t)MT * 64 * 2);
    bf16* a1o   = (bf16*)alloc((size_t)MT * 64 * 2);
    bf16* v1o   = (bf16*)alloc((size_t)MT * 64 * 2);
    bf16* g1o   = (bf16*)alloc((size_t)MT * 128 * 2);
    bf16* hbuf  = (bf16*)alloc((size_t)MT * FF * 2);
    bf16* ghout = (bf16*)alloc(MC * 2);
    float* yintraW = (float*)alloc((size_t)BH * NC * LCH * 64 * 4);
    float* zrW     = (float*)alloc((size_t)BH * NC * LCH * 64 * 4);
    __bf16* mtHiW  = (__bf16*)alloc((size_t)BH * NC * 4096 * 2);
    __bf16* mtLoW  = (__bf16*)alloc((size_t)BH * NC * 4096 * 2);
    float* zcW     = (float*)alloc((size_t)BH * NC * 4096 * 4);
    float* schkW   = (float*)alloc((size_t)BH * NC * 4096 * 4);
    if (woff > ws_size) return;

    float* xcur = (float*)d_out;
    copy_f<<<MC / 256, 256, 0, stream>>>(xcur, x);

    // ---- convert ALL layers' weights in one launch ----
    CArgs ca;
    ca.e[0]  = {W_r,  x_r,  BcatA,                    768, 768, 768, 1536, 0, 589824, (int)S_Bcat};
    ca.e[1]  = {W_k,  x_k,  BcatA + (size_t)768  * 1536, 768, 768, 768, 1536, 0, 589824, (int)S_Bcat};
    ca.e[2]  = {W_v,  x_v,  BcatA + (size_t)1536 * 1536, 768, 768, 768, 1536, 0, 589824, (int)S_Bcat};
    ca.e[3]  = {w1,   x_w,  BcatA + (size_t)2304 * 1536, 768, 64, 64, 1536, 0, 49152, (int)S_Bcat};
    ca.e[4]  = {a1,   x_a,  BcatA + (size_t)2368 * 1536, 768, 64, 64, 1536, 0, 49152, (int)S_Bcat};
    ca.e[5]  = {g1,   x_g,  BcatA + (size_t)2432 * 1536, 768, 128, 128, 1536, 0, 98304, (int)S_Bcat};
    ca.e[6]  = {v1,   x_v,  BcatA + (size_t)2560 * 1536, 768, 32, 64, 1536, 0, 24576, (int)S_Bcat};
    ca.e[7]  = {W_ck, c_x_k, BckA, 768, 3072, 3072, 1536, 0, 2359296, (int)S_Bck};
    ca.e[8]  = {w2,   nullptr, w2tA,   64, 768, 768, 64, 0, 49152, (int)S_w2t};
    ca.e[9]  = {a2,   nullptr, a2tA,   64, 768, 768, 64, 0, 49152, (int)S_a2t};
    ca.e[10] = {v2,   nullptr, v2tA,   32, 768, 768, 64, 0, 24576, (int)S_v2t};
    ca.e[11] = {g2,   nullptr, g2tA,  128, 768, 768, 128, 0, 98304, (int)S_g2t};
    ca.e[12] = {W_o,  nullptr, WoA,  768, 768, 768, 768, 0, 589824, (int)S_Wo};
    ca.e[13] = {W_cv, nullptr, WcvA, 3072, 768, 768, 3072, 0, 2359296, (int)S_Wcv};
    int btot = 0;
    for (int i = 0; i < 14; ++i) {
        ca.e[i].bstart = btot;
        int kblocks = ((ca.e[i].mix ? ca.e[i].Ksrc : ca.e[i].Kdst) + 63) >> 6;
        btot += (ca.e[i].Npad >> 5) * kblocks;
    }
    convert_weights<<<dim3(btot, LAYERS), 256, 0, stream>>>(ca);

    for (int l = 0; l < LAYERS; ++l) {
        size_t oC = (size_t)l * CC;
        float* vptr = (l == 0) ? vfirst : vbuf;
        const __bf16* Bcat  = (const __bf16*)(BcatA + (size_t)l * S_Bcat);
        const __bf16* Bck   = (const __bf16*)(BckA  + (size_t)l * S_Bck);
        const __bf16* w2t   = (const __bf16*)(w2tA  + (size_t)l * S_w2t);
        const __bf16* a2t   = (const __bf16*)(a2tA  + (size_t)l * S_a2t);
        const __bf16* v2t   = (const __bf16*)(v2tA  + (size_t)l * S_v2t);
        const __bf16* g2t   = (const __bf16*)(g2tA  + (size_t)l * S_g2t);
        const __bf16* Wo_t  = (const __bf16*)(WoA   + (size_t)l * S_Wo);
        const __bf16* Wcv_t = (const __bf16*)(WcvA  + (size_t)l * S_Wcv);

        // ---- time mix ----
        ln_shift_kernel<<<MT, 256, 0, stream>>>(xcur, ln1_w + oC, ln1_b + oC, A1);

        EpiArgs e1;
        e1.g[0] = {rbuf,  nullptr, nullptr, nullptr, 0, 768, 768};
        e1.g[1] = {kraw,  nullptr, nullptr, nullptr, 0, 768, 768};
        e1.g[2] = {vptr,  nullptr, nullptr, nullptr, 0, 768, 768};
        e1.g[3] = {nullptr, w1o, nullptr, nullptr, 2, 64, 64};
        e1.g[4] = {nullptr, a1o, nullptr, nullptr, 1, 64, 64};
        e1.g[5] = {nullptr, g1o, nullptr, nullptr, 3, 128, 128};
        e1.g[6] = {nullptr, v1o, nullptr, nullptr, 1, 64, 64};
        int nb1[8] = {0, 768, 1536, 2304, 2368, 2432, 2560, 2624};
        for (int i = 0; i < 8; ++i) e1.nb[i] = nb1[i];
        gemm_multi<32, 64><<<dim3(41, 32), 256, 0, stream>>>((const __bf16*)A1, Bcat, 1536, e1);

        G2Args g2a;
        g2a.g[0] = {(const __bf16*)w1o, w2t, dbuf, w0 + oC, nullptr, 64, 6};
        g2a.g[1] = {(const __bf16*)a1o, a2t, abuf, a0 + oC, nullptr, 64, 7};
        g2a.g[2] = {(const __bf16*)g1o, g2t, gbuf, nullptr, nullptr, 128, 0};
        g2a.g[3] = {(const __bf16*)v1o, v2t, vbuf, v0 + oC, vfirst, 64, 8};
        gemm_g2<128, 64><<<dim3(12, 8, (l == 0) ? 3 : 4), 256, 0, stream>>>(g2a);

        // ---- chunked scan ----
        chunkA_kernel<<<dim3(NC, BH), 256, 0, stream>>>(rbuf, dbuf, kraw, abuf, vptr,
                                                        k_k + oC, k_a + oC, kupd,
                                                        yintraW, zrW, mtHiW, mtLoW, zcW);
        chunkB1_kernel<<<BH, 256, 0, stream>>>(zcW, mtHiW, mtLoW, schkW);
        chunkY_kernel<<<dim3(NC, BH), 256, 0, stream>>>(yintraW, zrW, schkW,
                                                        rbuf, kupd, vptr, gbuf,
                                                        r_k + (size_t)l * 768,
                                                        ln_x_w + oC, ln_x_b + oC, ghout);

        EpiArgs eo;
        eo.g[0] = {xcur, nullptr, nullptr, nullptr, 5, 768, 768};
        eo.nb[0] = 0; for (int i = 1; i < 8; ++i) eo.nb[i] = 1 << 30;
        eo.nb[1] = 768;
        gemm_multi<32, 64><<<dim3(12, 32), 256, 0, stream>>>((const __bf16*)ghout, Wo_t, 768, eo);

        // ---- channel mix ----
        ln_shift_kernel<<<MT, 256, 0, stream>>>(xcur, ln2_w + oC, ln2_b + oC, A1);

        EpiArgs ec;
        ec.g[0] = {nullptr, hbuf, nullptr, nullptr, 4, 3072, 3072};
        ec.nb[0] = 0; for (int i = 1; i < 8; ++i) ec.nb[i] = 1 << 30;
        ec.nb[1] = 3072;
        gemm_multi<32, 64><<<dim3(48, 32), 256, 0, stream>>>((const __bf16*)A1, Bck, 1536, ec);

        EpiArgs ev;
        ev.g[0] = {xcur, nullptr, nullptr, nullptr, 5, 768, 768};
        ev.nb[0] = 0; for (int i = 1; i < 8; ++i) ev.nb[i] = 1 << 30;
        ev.nb[1] = 768;
        gemm_multi<32, 64><<<dim3(12, 32), 256, 0, stream>>>((const __bf16*)hbuf, Wcv_t, 3072, ev);
    }
}